// Round 1
// 708.900 us; speedup vs baseline: 1.0451x; 1.0451x over previous
//
#include <hip/hip_runtime.h>
#include <hip/hip_bf16.h>

typedef __bf16 bf16x8 __attribute__((ext_vector_type(8)));
typedef float f32x4 __attribute__((ext_vector_type(4)));
typedef unsigned short u16x8 __attribute__((ext_vector_type(8)));

#define DEV __device__ __forceinline__

static constexpr int N_SENTC = 256, BB = 512, SS = 128, DD = 1024;
static constexpr int LL = 10331, LATENT = 101;
static constexpr int LPAD = 10368;  // 162*64 = 81*128, row-padded L
static constexpr int LATPAD = 128;  // padded latent

DEV float bf2f(unsigned short u) {
  unsigned v = (unsigned)u << 16;
  return __builtin_bit_cast(float, v);
}
DEV unsigned short f2bf(float f) {
  unsigned u = __builtin_bit_cast(unsigned, f);
  unsigned lsb = (u >> 16) & 1u;
  u += 0x7fffu + lsb;
  return (unsigned short)(u >> 16);
}

DEV void stage8(unsigned short* dst, const float* src) {
  float4 a = *(const float4*)src;
  float4 b = *(const float4*)(src + 4);
  unsigned short t[8];
  t[0] = f2bf(a.x); t[1] = f2bf(a.y); t[2] = f2bf(a.z); t[3] = f2bf(a.w);
  t[4] = f2bf(b.x); t[5] = f2bf(b.y); t[6] = f2bf(b.z); t[7] = f2bf(b.w);
  *(uint4*)dst = *(uint4*)t;
}

// async global->LDS, 16B per lane; lds base wave-uniform (HW adds lane*16)
DEV void gl_lds16(const unsigned short* g, unsigned short* l) {
  __builtin_amdgcn_global_load_lds(
      (const __attribute__((address_space(1))) unsigned int*)g,
      (__attribute__((address_space(3))) unsigned int*)l, 16, 0, 0);
}

// ---------------------------------------------------------------------------
// f32 -> bf16 bulk convert (n4 = count/4)
// ---------------------------------------------------------------------------
__global__ __launch_bounds__(256) void k_cvt(
    const float* __restrict__ src, unsigned short* __restrict__ dst, int n4) {
  for (int i = blockIdx.x * 256 + threadIdx.x; i < n4; i += gridDim.x * 256) {
    float4 v = ((const float4*)src)[i];
    unsigned short t[4] = {f2bf(v.x), f2bf(v.y), f2bf(v.z), f2bf(v.w)};
    ((uint2*)dst)[i] = *(const uint2*)t;
  }
}

// f32 [srcR,srcC] -> bf16 [dstR,dstC] zero-padded
__global__ __launch_bounds__(256) void k_cvt_pad(
    const float* __restrict__ src, unsigned short* __restrict__ dst,
    int srcR, int srcC, int dstC, int total) {
  for (int i = blockIdx.x * 256 + threadIdx.x; i < total; i += gridDim.x * 256) {
    int r = i / dstC, c = i - r * dstC;
    dst[i] = (r < srcR && c < srcC) ? f2bf(src[(size_t)r * srcC + c]) : (unsigned short)0;
  }
}

// ---------------------------------------------------------------------------
// Fused men-score + ctx-hidden GEMM, 256x256-tile 8-phase schedule
// (T2 st_16x32 swizzle + T3/T4 counted vmcnt + T5 setprio).
//
// C[32768, 2048] = Xb[32768,1024] . [Wmb|Wcb]^T, K=1024 = 16 K-tiles of 64.
// 512 threads = 8 waves (2M x 4N), strided wave map:
//   row = mf*32 + wr*16 + lm  (mf 0..7)   col = nf*64 + wc*16 + lm (nf 0..3)
// LDS 128KB: [buf2][A/B][half2][8192]u16; half = [ks2][128 rows][32 bf16],
// swizzle byte ^= ((byte>>9)&1)<<5 (linear DMA dest + inverse-swizzled global
// source + swizzled ds_read -- rule "both sides or neither").
// Per K-tile 4 phases (one C-quadrant x K=64 each, 16 MFMA); stage order:
//   ph1: B-h1(kt+1)->buf^1   ph2: A-h0(kt+2)->buf
//   ph3: B-h0(kt+2)->buf     ph4: A-h1(kt+2)->buf, vmcnt(6), barrier
// Each LDS region overwritten only >=1 barrier after its last read.
// grid = 1024 (XCD-bijective swizzle; 1024%8==0), colTile 0-3 men / 4-7 ctx.
// ---------------------------------------------------------------------------
__global__ __launch_bounds__(512) void k_mc_gemm8(
    const unsigned short* __restrict__ Xb, const unsigned short* __restrict__ Wmb,
    const unsigned short* __restrict__ Wcb, const float* __restrict__ wo,
    float* __restrict__ score, unsigned short* __restrict__ Hc) {
  __shared__ __align__(16) unsigned short lds[2][2][2][8192];
  const int bid = blockIdx.x;
  const int lbid = (bid & 7) * 128 + (bid >> 3);   // bijective XCD swizzle
  const int colTile = lbid & 7, rowTile = lbid >> 3;
  const int rowBase = rowTile * 256;
  const bool isMen = colTile < 4;
  const unsigned short* __restrict__ Bsrc = isMen ? Wmb : Wcb;
  const int bcolBase = (colTile & 3) * 256;
  const int tid = threadIdx.x, w = tid >> 6, lane = tid & 63;
  const int lm = lane & 15, lq = lane >> 4;
  const int wr = w >> 2, wc = w & 3;
  // staging coords: wave w stages rows [w*16, w*16+16) of each half-tile;
  // source column pre-swapped for lanes>=32 (inverse of LDS read swizzle).
  const int stRow = w * 16 + (lane >> 2);
  const int stCol = ((lane & 3) * 8) ^ ((lane >> 5) << 4);
  const unsigned short* aSrc = Xb + (size_t)(rowBase + stRow) * 1024 + stCol;
  const unsigned short* bSrc = Bsrc + (size_t)(bcolBase + stRow) * 1024 + stCol;
  // read coords: byte col within 64B row, bit5 XOR'd with row-bit-3 (= lane&8)
  const int rdCol = (lq * 16) ^ ((lane & 8) ? 32 : 0);
  const int aoff = (wr * 16 + lm) * 64 + rdCol;
  const int boff = (wc * 16 + lm) * 64 + rdCol;
  f32x4 acc[8][4] = {};

  auto ST = [&](int op, int h, int kt, int buf) {
    const unsigned short* s = (op ? bSrc : aSrc) + (size_t)h * 131072 + kt * 64;
    unsigned short* d = &lds[buf][op][h][w * 512];
    gl_lds16(s, d);             // ks=0 block of this half
    gl_lds16(s + 32, d + 4096); // ks=1 block
  };

  // prologue: kt0 complete (4 halves) + kt1 A-h0,B-h0,A-h1 (B-h1 comes in g0/ph1)
  ST(0, 0, 0, 0); ST(1, 0, 0, 0); ST(0, 1, 0, 0); ST(1, 1, 0, 0);
  ST(0, 0, 1, 1); ST(1, 0, 1, 1); ST(0, 1, 1, 1);
  asm volatile("s_waitcnt vmcnt(6)" ::: "memory");  // kt0's 8 loads landed
  __builtin_amdgcn_s_barrier();

  bf16x8 af[4][2], bfr[4][2];
  for (int kt = 0; kt < 16; ++kt) {
    const int buf = kt & 1;
    const char* A0 = (const char*)&lds[buf][0][0][0];
    const char* A1 = (const char*)&lds[buf][0][1][0];
    const char* B0 = (const char*)&lds[buf][1][0][0];
    const char* B1 = (const char*)&lds[buf][1][1][0];
    // ---- phase 1: Q(0,0)  reads A-h0, B-h0
#pragma unroll
    for (int m = 0; m < 4; ++m)
#pragma unroll
      for (int ks = 0; ks < 2; ++ks)
        af[m][ks] = *(const bf16x8*)(A0 + aoff + m * 2048 + ks * 8192);
#pragma unroll
    for (int n = 0; n < 2; ++n)
#pragma unroll
      for (int ks = 0; ks < 2; ++ks)
        bfr[n][ks] = *(const bf16x8*)(B0 + boff + n * 4096 + ks * 8192);
    if (kt + 1 < 16) ST(1, 1, kt + 1, buf ^ 1);
    __builtin_amdgcn_s_barrier();
    __builtin_amdgcn_s_setprio(1);
#pragma unroll
    for (int m = 0; m < 4; ++m)
#pragma unroll
      for (int n = 0; n < 2; ++n)
#pragma unroll
        for (int ks = 0; ks < 2; ++ks)
          acc[m][n] = __builtin_amdgcn_mfma_f32_16x16x32_bf16(af[m][ks], bfr[n][ks], acc[m][n], 0, 0, 0);
    __builtin_amdgcn_s_setprio(0);
    __builtin_amdgcn_s_barrier();
    // ---- phase 2: Q(0,1)  reads B-h1
#pragma unroll
    for (int n = 0; n < 2; ++n)
#pragma unroll
      for (int ks = 0; ks < 2; ++ks)
        bfr[2 + n][ks] = *(const bf16x8*)(B1 + boff + n * 4096 + ks * 8192);
    if (kt + 2 < 16) ST(0, 0, kt + 2, buf);
    __builtin_amdgcn_s_barrier();
    __builtin_amdgcn_s_setprio(1);
#pragma unroll
    for (int m = 0; m < 4; ++m)
#pragma unroll
      for (int n = 0; n < 2; ++n)
#pragma unroll
        for (int ks = 0; ks < 2; ++ks)
          acc[m][2 + n] = __builtin_amdgcn_mfma_f32_16x16x32_bf16(af[m][ks], bfr[2 + n][ks], acc[m][2 + n], 0, 0, 0);
    __builtin_amdgcn_s_setprio(0);
    __builtin_amdgcn_s_barrier();
    // ---- phase 3: Q(1,0)  reads A-h1 (mf 4..7)
#pragma unroll
    for (int m = 0; m < 4; ++m)
#pragma unroll
      for (int ks = 0; ks < 2; ++ks)
        af[m][ks] = *(const bf16x8*)(A1 + aoff + m * 2048 + ks * 8192);
    if (kt + 2 < 16) ST(1, 0, kt + 2, buf);
    __builtin_amdgcn_s_barrier();
    __builtin_amdgcn_s_setprio(1);
#pragma unroll
    for (int m = 0; m < 4; ++m)
#pragma unroll
      for (int n = 0; n < 2; ++n)
#pragma unroll
        for (int ks = 0; ks < 2; ++ks)
          acc[4 + m][n] = __builtin_amdgcn_mfma_f32_16x16x32_bf16(af[m][ks], bfr[n][ks], acc[4 + m][n], 0, 0, 0);
    __builtin_amdgcn_s_setprio(0);
    __builtin_amdgcn_s_barrier();
    // ---- phase 4: Q(1,1)  no reads
    if (kt + 2 < 16) ST(0, 1, kt + 2, buf);
    __builtin_amdgcn_s_barrier();
    __builtin_amdgcn_s_setprio(1);
#pragma unroll
    for (int m = 0; m < 4; ++m)
#pragma unroll
      for (int n = 0; n < 2; ++n)
#pragma unroll
        for (int ks = 0; ks < 2; ++ks)
          acc[4 + m][2 + n] = __builtin_amdgcn_mfma_f32_16x16x32_bf16(af[m][ks], bfr[2 + n][ks], acc[4 + m][2 + n], 0, 0, 0);
    __builtin_amdgcn_s_setprio(0);
    if (kt < 14) {
      asm volatile("s_waitcnt vmcnt(6)" ::: "memory");  // kt+1 fully landed
    } else {
      asm volatile("s_waitcnt vmcnt(0)" ::: "memory");  // tail drain
    }
    __builtin_amdgcn_s_barrier();
  }

  if (isMen) {
    float wov[4];
#pragma unroll
    for (int n = 0; n < 4; ++n) wov[n] = wo[bcolBase + n * 64 + wc * 16 + lm];
    float rsum[8][4];
#pragma unroll
    for (int m = 0; m < 8; ++m)
#pragma unroll
      for (int r = 0; r < 4; ++r) {
        float s = 0.f;
#pragma unroll
        for (int n = 0; n < 4; ++n) s += tanhf(acc[m][n][r]) * wov[n];
        rsum[m][r] = s;
      }
#pragma unroll
    for (int msk = 1; msk <= 8; msk <<= 1)
#pragma unroll
      for (int m = 0; m < 8; ++m)
#pragma unroll
        for (int r = 0; r < 4; ++r) rsum[m][r] += __shfl_xor(rsum[m][r], msk, 64);
    if (lm == 0) {
#pragma unroll
      for (int m = 0; m < 8; ++m)
#pragma unroll
        for (int r = 0; r < 4; ++r)
          atomicAdd(&score[rowBase + m * 32 + wr * 16 + lq * 4 + r], rsum[m][r]);
    }
  } else {
    const int cb0 = (colTile - 4) * 256 + wc * 16 + lm;
#pragma unroll
    for (int m = 0; m < 8; ++m) {
      const int row = rowBase + m * 32 + wr * 16 + lq * 4;
#pragma unroll
      for (int n = 0; n < 4; ++n) {
        const int col = cb0 + n * 64;
#pragma unroll
        for (int r = 0; r < 4; ++r)
          Hc[(size_t)(row + r) * 1024 + col] = f2bf(acc[m][n][r]);
      }
    }
  }
}

// ---------------------------------------------------------------------------
// ctx score from deduped hidden (proven)
// ---------------------------------------------------------------------------
__global__ __launch_bounds__(256) void k_ctx_score(
    const unsigned short* __restrict__ Hc, const int* __restrict__ gathers,
    const float* __restrict__ cb, const float* __restrict__ wd,
    const float* __restrict__ wo, const float* __restrict__ dist,
    float* __restrict__ score) {
  const int b = blockIdx.x, tid = threadIdx.x, wave = tid >> 6, lane = tid & 63;
  const int n = gathers[b];
  __shared__ float cbl[1024], wdl[1024], wol[1024];
  for (int i = tid; i < 1024; i += 256) {
    cbl[i] = cb[b * 1024 + i];
    wdl[i] = wd[i];
    wol[i] = wo[i];
  }
  __syncthreads();
  for (int s = wave; s < 128; s += 4) {
    float d = dist[b * 128 + s];
    const unsigned short* hrow = &Hc[(size_t)(n * 128 + s) * 1024 + lane * 16];
    unsigned short hs[16];
    *(uint4*)hs = *(const uint4*)hrow;
    *(uint4*)(hs + 8) = *(const uint4*)(hrow + 8);
    float p = 0.f;
#pragma unroll
    for (int j = 0; j < 16; ++j) {
      int e = lane * 16 + j;
      p += tanhf(bf2f(hs[j]) + cbl[e] + d * wdl[e]) * wol[e];
    }
#pragma unroll
    for (int msk = 1; msk <= 32; msk <<= 1) p += __shfl_xor(p, msk, 64);
    if (lane == 0) score[b * 128 + s] = p;
  }
}

// ---------------------------------------------------------------------------
// softmax over S=128 + weighted sum from bf16 X -> bf16 final_repr half.
// ---------------------------------------------------------------------------
__global__ __launch_bounds__(256) void k_softb(
    const float* __restrict__ score_src, const float* __restrict__ mask,
    const unsigned short* __restrict__ Xb, const int* __restrict__ gathers,
    unsigned short* __restrict__ finalrb, int isCtx) {
  const int b = blockIdx.x, tid = threadIdx.x;
  const int n = gathers[b];
  __shared__ float attn[128];
  __shared__ float red[128 * 8];
  __shared__ float smax, ssum;
  if (tid < 128) {
    int srow = isCtx ? b : n;
    attn[tid] = score_src[srow * 128 + tid] + (1.0f - mask[b * 128 + tid]) * (-10000.0f);
  }
  __syncthreads();
  if (tid == 0) {
    float m = attn[0];
    for (int i = 1; i < 128; ++i) m = fmaxf(m, attn[i]);
    smax = m;
  }
  __syncthreads();
  if (tid < 128) attn[tid] = expf(attn[tid] - smax);
  __syncthreads();
  if (tid == 0) {
    float s = 0.f;
    for (int i = 0; i < 128; ++i) s += attn[i];
    ssum = 1.0f / s;
  }
  __syncthreads();
  if (tid < 128) attn[tid] *= ssum;
  __syncthreads();
  const unsigned short* xb = Xb + (size_t)n * 128 * 1024;
  const int c = tid & 127, h = tid >> 7;
  float acc[8] = {};
  for (int s = h; s < 128; s += 2) {
    float w = attn[s];
    u16x8 v = *(const u16x8*)&xb[(size_t)s * 1024 + c * 8];
#pragma unroll
    for (int j = 0; j < 8; ++j) acc[j] += w * bf2f(v[j]);
  }
  if (h == 1) {
#pragma unroll
    for (int j = 0; j < 8; ++j) red[c * 8 + j] = acc[j];
  }
  __syncthreads();
  if (h == 0) {
    unsigned short o[8];
#pragma unroll
    for (int j = 0; j < 8; ++j) o[j] = f2bf(acc[j] + red[c * 8 + j]);
    *(uint4*)&finalrb[(size_t)b * 2048 + (isCtx ? 1024 : 0) + c * 8] = *(uint4*)o;
  }
}

// ---------------------------------------------------------------------------
// cb GEMM (bf16 in): cb[b,e] = men_repr[b,:1024] . Wcm[e,:]; grid 128
// ---------------------------------------------------------------------------
__global__ __launch_bounds__(256) void k_cb_gemm_b(
    const unsigned short* __restrict__ finalrb, const unsigned short* __restrict__ Wcmb,
    float* __restrict__ cb) {
  __shared__ __align__(16) unsigned short As[64 * 32];
  __shared__ __align__(16) unsigned short Bs[64 * 32];
  const int bid = blockIdx.x;
  const int rowBase = (bid >> 4) * 64, colBase = (bid & 15) * 64;
  const int tid = threadIdx.x, wave = tid >> 6, lane = tid & 63;
  const int lm = lane & 15, lq = lane >> 4;
  const int sr = tid >> 2, sc = (tid & 3) * 8;
  f32x4 acc[4] = {};
  for (int k0 = 0; k0 < 1024; k0 += 32) {
    __syncthreads();
    *(uint4*)&As[sr * 32 + sc] = *(const uint4*)&finalrb[(size_t)(rowBase + sr) * 2048 + k0 + sc];
    *(uint4*)&Bs[sr * 32 + sc] = *(const uint4*)&Wcmb[(size_t)(colBase + sr) * 1024 + k0 + sc];
    __syncthreads();
    bf16x8 af = *(const bf16x8*)&As[(wave * 16 + lm) * 32 + lq * 8];
#pragma unroll
    for (int j = 0; j < 4; ++j) {
      bf16x8 bfr = *(const bf16x8*)&Bs[(j * 16 + lm) * 32 + lq * 8];
      acc[j] = __builtin_amdgcn_mfma_f32_16x16x32_bf16(af, bfr, acc[j], 0, 0, 0);
    }
  }
#pragma unroll
  for (int j = 0; j < 4; ++j) {
    int col = colBase + j * 16 + lm;
#pragma unroll
    for (int r = 0; r < 4; ++r) {
      int row = rowBase + wave * 16 + lq * 4 + r;
      cb[row * 1024 + col] = acc[j][r];
    }
  }
}

// ---------------------------------------------------------------------------
// latent GEMM (bf16): latb[b,0:128] = finalrb . Wf2lb^T; grid dim3(2,8)
// ---------------------------------------------------------------------------
__global__ __launch_bounds__(256) void k_lat_gemm_b(
    const unsigned short* __restrict__ finalrb, const unsigned short* __restrict__ Wf2lb,
    unsigned short* __restrict__ latb) {
  __shared__ __align__(16) unsigned short As[64 * 32];
  __shared__ __align__(16) unsigned short Bs[64 * 32];
  const int rowBase = blockIdx.y * 64, colBase = blockIdx.x * 64;
  const int tid = threadIdx.x, wave = tid >> 6, lane = tid & 63;
  const int lm = lane & 15, lq = lane >> 4;
  const int sr = tid >> 2, sc = (tid & 3) * 8;
  f32x4 acc[4] = {};
  for (int k0 = 0; k0 < 2048; k0 += 32) {
    __syncthreads();
    *(uint4*)&As[sr * 32 + sc] = *(const uint4*)&finalrb[(size_t)(rowBase + sr) * 2048 + k0 + sc];
    *(uint4*)&Bs[sr * 32 + sc] = *(const uint4*)&Wf2lb[(size_t)(colBase + sr) * 2048 + k0 + sc];
    __syncthreads();
    bf16x8 af = *(const bf16x8*)&As[(wave * 16 + lm) * 32 + lq * 8];
#pragma unroll
    for (int j = 0; j < 4; ++j) {
      bf16x8 bfr = *(const bf16x8*)&Bs[(j * 16 + lm) * 32 + lq * 8];
      acc[j] = __builtin_amdgcn_mfma_f32_16x16x32_bf16(af, bfr, acc[j], 0, 0, 0);
    }
  }
#pragma unroll
  for (int j = 0; j < 4; ++j) {
    int col = colBase + j * 16 + lm;
#pragma unroll
    for (int r = 0; r < 4; ++r) {
      int row = rowBase + wave * 16 + lq * 4 + r;
      latb[row * LATPAD + col] = f2bf(acc[j][r]);
    }
  }
}

// ---------------------------------------------------------------------------
// output GEMM, 128x128 async BK=64 structure:
//   acc  = finalrb[128,2048] . Woutb[128cols,2048]^T
//   acc2 = latb[128,128] . Wl2lb[128cols,128]^T
//   out = acc + scal*acc2 ; outLat = acc2. grid dim3(81, 4) - all co-resident
// ---------------------------------------------------------------------------
__global__ __launch_bounds__(256) void k_out_gemm_b(
    const unsigned short* __restrict__ finalrb, const unsigned short* __restrict__ Woutb,
    const unsigned short* __restrict__ latb, const unsigned short* __restrict__ Wl2lb,
    const float* __restrict__ lscale, float* __restrict__ out,
    float* __restrict__ outLat) {
  __shared__ __align__(16) unsigned short As[2 * 128 * 32];
  __shared__ __align__(16) unsigned short Bs[2 * 128 * 32];
  const int colBase = blockIdx.x * 128;
  const int rowBase = blockIdx.y * 128;
  const int tid = threadIdx.x, wave = tid >> 6, lane = tid & 63;
  const int lm = lane & 15, lq = lane >> 4;
  const int wr = (wave & 1) * 64, wc = (wave >> 1) * 64;
  const int srow = wave * 32 + (lane >> 2);
  const int scol = (lane & 3) * 8;
  const float scal = lscale[0];
  const unsigned short* aPtr = finalrb + (size_t)(rowBase + srow) * 2048 + scol;
  const unsigned short* bPtr = Woutb + (size_t)(colBase + srow) * 2048 + scol;
  f32x4 acc[4][4] = {};
  for (int k0 = 0; k0 < 2048; k0 += 64) {
    __syncthreads();
#pragma unroll
    for (int h = 0; h < 2; ++h) {
      gl_lds16(aPtr + k0 + h * 32, As + h * 4096 + wave * 1024);
      gl_lds16(aPtr + k0 + h * 32 + 16 * 2048, As + h * 4096 + wave * 1024 + 512);
      gl_lds16(bPtr + k0 + h * 32, Bs + h * 4096 + wave * 1024);
      gl_lds16(bPtr + k0 + h * 32 + 16 * 2048, Bs + h * 4096 + wave * 1024 + 512);
    }
    __syncthreads();
#pragma unroll
    for (int h = 0; h < 2; ++h) {
      bf16x8 af[4], bfr[4];
#pragma unroll
      for (int m = 0; m < 4; ++m)
        af[m] = *(const bf16x8*)&As[h * 4096 + (wr + m * 16 + lm) * 32 + lq * 8];
#pragma unroll
      for (int n = 0; n < 4; ++n)
        bfr[n] = *(const bf16x8*)&Bs[h * 4096 + (wc + n * 16 + lm) * 32 + lq * 8];
#pragma unroll
      for (int m = 0; m < 4; ++m)
#pragma unroll
        for (int n = 0; n < 4; ++n)
          acc[m][n] = __builtin_amdgcn_mfma_f32_16x16x32_bf16(af[m], bfr[n], acc[m][n], 0, 0, 0);
    }
  }
  // latent phase: K=128 (2 iters), separate accumulator
  const unsigned short* aPtr2 = latb + (size_t)(rowBase + srow) * LATPAD + scol;
  const unsigned short* bPtr2 = Wl2lb + (size_t)(colBase + srow) * LATPAD + scol;
  f32x4 acc2[4][4] = {};
  for (int k0 = 0; k0 < 128; k0 += 64) {
    __syncthreads();
#pragma unroll
    for (int h = 0; h < 2; ++h) {
      gl_lds16(aPtr2 + k0 + h * 32, As + h * 4096 + wave * 1024);
      gl_lds16(aPtr2 + k0 + h * 32 + 16 * LATPAD, As + h * 4096 + wave * 1024 + 512);
      gl_lds16(bPtr2 + k0 + h * 32, Bs + h * 4096 + wave * 1024);
      gl_lds16(bPtr2 + k0 + h * 32 + 16 * LATPAD, Bs + h * 4096 + wave * 1024 + 512);
    }
    __syncthreads();
#pragma unroll
    for (int h = 0; h < 2; ++h) {
      bf16x8 af[4], bfr[4];
#pragma unroll
      for (int m = 0; m < 4; ++m)
        af[m] = *(const bf16x8*)&As[h * 4096 + (wr + m * 16 + lm) * 32 + lq * 8];
#pragma unroll
      for (int n = 0; n < 4; ++n)
        bfr[n] = *(const bf16x8*)&Bs[h * 4096 + (wc + n * 16 + lm) * 32 + lq * 8];
#pragma unroll
      for (int m = 0; m < 4; ++m)
#pragma unroll
        for (int n = 0; n < 4; ++n)
          acc2[m][n] = __builtin_amdgcn_mfma_f32_16x16x32_bf16(af[m], bfr[n], acc2[m][n], 0, 0, 0);
    }
  }
#pragma unroll
  for (int m = 0; m < 4; ++m)
#pragma unroll
    for (int n = 0; n < 4; ++n) {
      int col = colBase + wc + n * 16 + lm;
      if (col < LL) {
#pragma unroll
        for (int r = 0; r < 4; ++r) {
          int row = rowBase + wr + m * 16 + lq * 4 + r;
          float lv = acc2[m][n][r];
          out[(size_t)row * LL + col] = acc[m][n][r] + scal * lv;
          outLat[(size_t)row * LL + col] = lv;
        }
      }
    }
}

// ======================= legacy fallback (round-3, proven) ==================
__global__ __launch_bounds__(256) void k_men_gemm(
    const float* __restrict__ X, const float* __restrict__ Wm,
    const float* __restrict__ wo, float* __restrict__ score) {
  __shared__ __align__(16) unsigned short As[64 * 32];
  __shared__ __align__(16) unsigned short Bs[64 * 32];
  const int bid = blockIdx.x;
  const int rowBase = (bid >> 4) * 64, colBase = (bid & 15) * 64;
  const int tid = threadIdx.x, wave = tid >> 6, lane = tid & 63;
  const int lm = lane & 15, lq = lane >> 4;
  const int sr = tid >> 2, sc = (tid & 3) * 8;
  f32x4 acc[4] = {};
  for (int k0 = 0; k0 < 1024; k0 += 32) {
    __syncthreads();
    stage8(&As[sr * 32 + sc], &X[(size_t)(rowBase + sr) * 1024 + k0 + sc]);
    stage8(&Bs[sr * 32 + sc], &Wm[(size_t)(colBase + sr) * 1024 + k0 + sc]);
    __syncthreads();
    bf16x8 af = *(const bf16x8*)&As[(wave * 16 + lm) * 32 + lq * 8];
#pragma unroll
    for (int j = 0; j < 4; ++j) {
      bf16x8 bfr = *(const bf16x8*)&Bs[(j * 16 + lm) * 32 + lq * 8];
      acc[j] = __builtin_amdgcn_mfma_f32_16x16x32_bf16(af, bfr, acc[j], 0, 0, 0);
    }
  }
  float rsum[4] = {0.f, 0.f, 0.f, 0.f};
#pragma unroll
  for (int j = 0; j < 4; ++j) {
    float w = wo[colBase + j * 16 + lm];
#pragma unroll
    for (int r = 0; r < 4; ++r) rsum[r] += tanhf(acc[j][r]) * w;
  }
#pragma unroll
  for (int m = 1; m <= 8; m <<= 1)
#pragma unroll
    for (int r = 0; r < 4; ++r) rsum[r] += __shfl_xor(rsum[r], m, 64);
  if (lm == 0) {
    int row0 = rowBase + wave * 16 + lq * 4;
#pragma unroll
    for (int r = 0; r < 4; ++r) atomicAdd(&score[row0 + r], rsum[r]);
  }
}

__global__ __launch_bounds__(256) void k_ctx_gemm(
    const float* __restrict__ X, const int* __restrict__ gathers,
    const float* __restrict__ Wc, const float* __restrict__ wd,
    const float* __restrict__ wo, const float* __restrict__ dist,
    const float* __restrict__ cb, float* __restrict__ score) {
  __shared__ __align__(16) unsigned short As[64 * 32];
  __shared__ __align__(16) unsigned short Bs[64 * 32];
  const int bid = blockIdx.x;
  const int rowBase = (bid >> 4) * 64, colBase = (bid & 15) * 64;
  const int tid = threadIdx.x, wave = tid >> 6, lane = tid & 63;
  const int lm = lane & 15, lq = lane >> 4;
  const int sr = tid >> 2, sc = (tid & 3) * 8;
  const int row_g = rowBase + sr;
  const int srcRow = (gathers[row_g >> 7] << 7) + (row_g & 127);
  f32x4 acc[4] = {};
  for (int k0 = 0; k0 < 1024; k0 += 32) {
    __syncthreads();
    stage8(&As[sr * 32 + sc], &X[(size_t)srcRow * 1024 + k0 + sc]);
    stage8(&Bs[sr * 32 + sc], &Wc[(size_t)(colBase + sr) * 1024 + k0 + sc]);
    __syncthreads();
    bf16x8 af = *(const bf16x8*)&As[(wave * 16 + lm) * 32 + lq * 8];
#pragma unroll
    for (int j = 0; j < 4; ++j) {
      bf16x8 bfr = *(const bf16x8*)&Bs[(j * 16 + lm) * 32 + lq * 8];
      acc[j] = __builtin_amdgcn_mfma_f32_16x16x32_bf16(af, bfr, acc[j], 0, 0, 0);
    }
  }
  float rsum[4] = {0.f, 0.f, 0.f, 0.f};
#pragma unroll
  for (int j = 0; j < 4; ++j) {
    int col = colBase + j * 16 + lm;
    float w = wo[col];
    float wdv = wd[col];
#pragma unroll
    for (int r = 0; r < 4; ++r) {
      int rg = rowBase + wave * 16 + lq * 4 + r;
      int b = rg >> 7, s = rg & 127;
      float v = acc[j][r] + cb[b * 1024 + col] + dist[b * 128 + s] * wdv;
      rsum[r] += tanhf(v) * w;
    }
  }
#pragma unroll
  for (int m = 1; m <= 8; m <<= 1)
#pragma unroll
    for (int r = 0; r < 4; ++r) rsum[r] += __shfl_xor(rsum[r], m, 64);
  if (lm == 0) {
    int row0 = rowBase + wave * 16 + lq * 4;
#pragma unroll
    for (int r = 0; r < 4; ++r) atomicAdd(&score[row0 + r], rsum[r]);
  }
}

__global__ __launch_bounds__(256) void k_soft(
    const float* __restrict__ score_src, const float* __restrict__ mask,
    const float* __restrict__ X, const int* __restrict__ gathers,
    float* __restrict__ finalr, int isCtx) {
  const int b = blockIdx.x, tid = threadIdx.x;
  const int n = gathers[b];
  __shared__ float attn[128];
  __shared__ float smax, ssum;
  if (tid < 128) {
    int srow = isCtx ? b : n;
    attn[tid] = score_src[srow * 128 + tid] + (1.0f - mask[b * 128 + tid]) * (-10000.0f);
  }
  __syncthreads();
  if (tid == 0) {
    float m = attn[0];
    for (int i = 1; i < 128; ++i) m = fmaxf(m, attn[i]);
    smax = m;
  }
  __syncthreads();
  if (tid < 128) attn[tid] = expf(attn[tid] - smax);
  __syncthreads();
  if (tid == 0) {
    float s = 0.f;
    for (int i = 0; i < 128; ++i) s += attn[i];
    ssum = 1.0f / s;
  }
  __syncthreads();
  if (tid < 128) attn[tid] *= ssum;
  __syncthreads();
  const float* xb = &X[(size_t)(n << 7) * 1024];
  const int off = isCtx ? 1024 : 0;
  for (int d = tid; d < 1024; d += 256) {
    float a = 0.f;
#pragma unroll 8
    for (int s = 0; s < 128; ++s) a += attn[s] * xb[s * 1024 + d];
    finalr[b * 2048 + off + d] = a;
  }
}

__global__ __launch_bounds__(256) void k_cb_gemm(
    const float* __restrict__ finalr, const float* __restrict__ Wcm,
    float* __restrict__ cb) {
  __shared__ __align__(16) unsigned short As[64 * 32];
  __shared__ __align__(16) unsigned short Bs[64 * 32];
  const int bid = blockIdx.x;
  const int rowBase = (bid >> 4) * 64, colBase = (bid & 15) * 64;
  const int tid = threadIdx.x, wave = tid >> 6, lane = tid & 63;
  const int lm = lane & 15, lq = lane >> 4;
  const int sr = tid >> 2, sc = (tid & 3) * 8;
  f32x4 acc[4] = {};
  for (int k0 = 0; k0 < 1024; k0 += 32) {
    __syncthreads();
    stage8(&As[sr * 32 + sc], &finalr[(size_t)(rowBase + sr) * 2048 + k0 + sc]);
    stage8(&Bs[sr * 32 + sc], &Wcm[(size_t)(colBase + sr) * 1024 + k0 + sc]);
    __syncthreads();
    bf16x8 af = *(const bf16x8*)&As[(wave * 16 + lm) * 32 + lq * 8];
#pragma unroll
    for (int j = 0; j < 4; ++j) {
      bf16x8 bfr = *(const bf16x8*)&Bs[(j * 16 + lm) * 32 + lq * 8];
      acc[j] = __builtin_amdgcn_mfma_f32_16x16x32_bf16(af, bfr, acc[j], 0, 0, 0);
    }
  }
#pragma unroll
  for (int j = 0; j < 4; ++j) {
    int col = colBase + j * 16 + lm;
#pragma unroll
    for (int r = 0; r < 4; ++r) {
      int row = rowBase + wave * 16 + lq * 4 + r;
      cb[row * 1024 + col] = acc[j][r];
    }
  }
}

__global__ __launch_bounds__(256) void k_lat_gemm(
    const float* __restrict__ finalr, const float* __restrict__ Wf2l,
    float* __restrict__ lat) {
  __shared__ __align__(16) unsigned short As[64 * 32];
  __shared__ __align__(16) unsigned short Bs[64 * 32];
  const int rowBase = blockIdx.y * 64, colBase = blockIdx.x * 64;
  const int tid = threadIdx.x, wave = tid >> 6, lane = tid & 63;
  const int lm = lane & 15, lq = lane >> 4;
  const int sr = tid >> 2, sc = (tid & 3) * 8;
  f32x4 acc[4] = {};
  for (int k0 = 0; k0 < 2048; k0 += 32) {
    __syncthreads();
    stage8(&As[sr * 32 + sc], &finalr[(size_t)(rowBase + sr) * 2048 + k0 + sc]);
    int l = colBase + sr;
    if (l < LATENT) {
      stage8(&Bs[sr * 32 + sc], &Wf2l[(size_t)l * 2048 + k0 + sc]);
    } else {
      uint4 z = {0, 0, 0, 0};
      *(uint4*)&Bs[sr * 32 + sc] = z;
    }
    __syncthreads();
    bf16x8 af = *(const bf16x8*)&As[(wave * 16 + lm) * 32 + lq * 8];
#pragma unroll
    for (int j = 0; j < 4; ++j) {
      bf16x8 bfr = *(const bf16x8*)&Bs[(j * 16 + lm) * 32 + lq * 8];
      acc[j] = __builtin_amdgcn_mfma_f32_16x16x32_bf16(af, bfr, acc[j], 0, 0, 0);
    }
  }
#pragma unroll
  for (int j = 0; j < 4; ++j) {
    int col = colBase + j * 16 + lm;
    if (col < LATENT) {
#pragma unroll
      for (int r = 0; r < 4; ++r) {
        int row = rowBase + wave * 16 + lq * 4 + r;
        lat[row * LATENT + col] = acc[j][r];
      }
    }
  }
}

__global__ __launch_bounds__(256) void k_out_gemm(
    const float* __restrict__ finalr, const float* __restrict__ Wout,
    const float* __restrict__ lat, const float* __restrict__ Wl2l,
    const float* __restrict__ lscale, float* __restrict__ out,
    float* __restrict__ outLat) {
  __shared__ __align__(16) unsigned short As[64 * 32];
  __shared__ __align__(16) unsigned short Bs[64 * 32];
  const int rowBase = blockIdx.y * 64, colBase = blockIdx.x * 64;
  const int tid = threadIdx.x, wave = tid >> 6, lane = tid & 63;
  const int lm = lane & 15, lq = lane >> 4;
  const int sr = tid >> 2, sc = (tid & 3) * 8;
  const float scal = lscale[0];
  const int lrow = colBase + sr;
  const bool lvalid = (lrow < LL);
  f32x4 acc[4] = {};
  for (int k0 = 0; k0 < 2048; k0 += 32) {
    __syncthreads();
    stage8(&As[sr * 32 + sc], &finalr[(size_t)(rowBase + sr) * 2048 + k0 + sc]);
    if (lvalid) {
      stage8(&Bs[sr * 32 + sc], &Wout[(size_t)lrow * 2048 + k0 + sc]);
    } else {
      uint4 z = {0, 0, 0, 0};
      *(uint4*)&Bs[sr * 32 + sc] = z;
    }
    __syncthreads();
    bf16x8 af = *(const bf16x8*)&As[(wave * 16 + lm) * 32 + lq * 8];
#pragma unroll
    for (int j = 0; j < 4; ++j) {
      bf16x8 bfr = *(const bf16x8*)&Bs[(j * 16 + lm) * 32 + lq * 8];
      acc[j] = __builtin_amdgcn_mfma_f32_16x16x32_bf16(af, bfr, acc[j], 0, 0, 0);
    }
  }
  f32x4 acc2[4] = {};
  for (int k2 = 0; k2 < 128; k2 += 32) {
    __syncthreads();
    const int brow = rowBase + sr;
#pragma unroll
    for (int jj = 0; jj < 8; ++jj) {
      int idx = k2 + sc + jj;
      As[sr * 32 + sc + jj] = (idx < LATENT) ? f2bf(lat[brow * LATENT + idx]) : (unsigned short)0;
      Bs[sr * 32 + sc + jj] = (lvalid && idx < LATENT) ? f2bf(Wl2l[lrow * LATENT + idx]) : (unsigned short)0;
    }
    __syncthreads();
    bf16x8 af = *(const bf16x8*)&As[(wave * 16 + lm) * 32 + lq * 8];
#pragma unroll
    for (int j = 0; j < 4; ++j) {
      bf16x8 bfr = *(const bf16x8*)&Bs[(j * 16 + lm) * 32 + lq * 8];
      acc2[j] = __builtin_amdgcn_mfma_f32_16x16x32_bf16(af, bfr, acc2[j], 0, 0, 0);
    }
  }
#pragma unroll
  for (int j = 0; j < 4; ++j) {
    int col = colBase + j * 16 + lm;
    if (col < LL) {
#pragma unroll
      for (int r = 0; r < 4; ++r) {
        int row = rowBase + wave * 16 + lq * 4 + r;
        float lv = acc2[j][r];
        out[(size_t)row * LL + col] = acc[j][r] + scal * lv;
        outLat[(size_t)row * LL + col] = lv;
      }
    }
  }
}

extern "C" void kernel_launch(void* const* d_in, const int* in_sizes, int n_in,
                              void* d_out, int out_size, void* d_ws, size_t ws_size,
                              hipStream_t stream) {
  const float* X = (const float*)d_in[0];
  const float* men_mask = (const float*)d_in[1];
  const float* ctx_mask = (const float*)d_in[2];
  const float* dist = (const float*)d_in[3];
  const int* gathers = (const int*)d_in[4];
  const float* W_men_m = (const float*)d_in[5];
  const float* W_men_o = (const float*)d_in[6];
  const float* W_ctx_c = (const float*)d_in[7];
  const float* W_ctx_m = (const float*)d_in[8];
  const float* w_ctx_d = (const float*)d_in[9];
  const float* W_ctx_o = (const float*)d_in[10];
  const float* W_out = (const float*)d_in[11];
  const float* W_f2l = (const float*)d_in[12];
  const float* W_l2l = (const float*)d_in[13];
  const float* lscale = (const float*)d_in[14];
  float* out = (float*)d_out;
  float* outLat = out + (size_t)BB * LL;

  size_t off = 0;
  auto carve = [&](size_t bytes) {
    void* p = (char*)d_ws + off;
    off = (off + bytes + 255) & ~(size_t)255;
    return p;
  };
  float* sent_score = (float*)carve(32768 * 4);
  float* ctx_score = (float*)carve(65536 * 4);
  float* finalr = (float*)carve((size_t)512 * 2048 * 4);        // legacy only
  float* cb = (float*)carve((size_t)512 * 1024 * 4);
  float* lat = (float*)carve((size_t)512 * LATENT * 4);         // legacy only
  unsigned short* Xb = (unsigned short*)carve((size_t)32768 * 1024 * 2);
  unsigned short* Wmb = (unsigned short*)carve((size_t)1024 * 1024 * 2);
  unsigned short* Wcb = (unsigned short*)carve((size_t)1024 * 1024 * 2);
  unsigned short* Wcmb = (unsigned short*)carve((size_t)1024 * 1024 * 2);
  unsigned short* Hc = (unsigned short*)carve((size_t)32768 * 1024 * 2);
  unsigned short* Wf2lb = (unsigned short*)carve((size_t)LATPAD * 2048 * 2);
  unsigned short* Wl2lb = (unsigned short*)carve((size_t)LPAD * LATPAD * 2);
  unsigned short* finalrb = (unsigned short*)carve((size_t)512 * 2048 * 2);
  unsigned short* latb = (unsigned short*)carve((size_t)512 * LATPAD * 2);
  const bool fits = off <= ws_size;
  // Woutb aliases Xb (Xb dead after ctx softmax; LPAD*2048*2 = 42.5 MB <= 67 MB)
  unsigned short* Woutb = Xb;

  if (fits) {
    hipMemsetAsync(sent_score, 0, 32768 * sizeof(float), stream);
    k_cvt<<<8192, 256, 0, stream>>>(X, Xb, 32768 * 1024 / 4);
    k_cvt<<<1024, 256, 0, stream>>>(W_men_m, Wmb, 1024 * 1024 / 4);
    k_cvt<<<1024, 256, 0, stream>>>(W_ctx_c, Wcb, 1024 * 1024 / 4);
    k_cvt<<<1024, 256, 0, stream>>>(W_ctx_m, Wcmb, 1024 * 1024 / 4);
    k_cvt_pad<<<512, 256, 0, stream>>>(W_f2l, Wf2lb, LATENT, 2048, 2048, LATPAD * 2048);
    k_cvt_pad<<<1024, 256, 0, stream>>>(W_l2l, Wl2lb, LL, LATENT, LATPAD, LPAD * LATPAD);
    k_mc_gemm8<<<1024, 512, 0, stream>>>(Xb, Wmb, Wcb, W_men_o, sent_score, Hc);
    k_softb<<<512, 256, 0, stream>>>(sent_score, men_mask, Xb, gathers, finalrb, 0);
    k_cb_gemm_b<<<128, 256, 0, stream>>>(finalrb, Wcmb, cb);
    k_ctx_score<<<512, 256, 0, stream>>>(Hc, gathers, cb, w_ctx_d, W_ctx_o, dist, ctx_score);
    k_softb<<<512, 256, 0, stream>>>(ctx_score, ctx_mask, Xb, gathers, finalrb, 1);
    k_lat_gemm_b<<<dim3(2, 8), 256, 0, stream>>>(finalrb, Wf2lb, latb);
    // Xb dead; convert W_out (zero-padded rows) into its space
    k_cvt_pad<<<8192, 256, 0, stream>>>(W_out, Woutb, LL, 2048, 2048, LPAD * 2048);
    k_out_gemm_b<<<dim3(81, 4), 256, 0, stream>>>(finalrb, Woutb, latb, Wl2lb,
                                                  lscale, out, outLat);
  } else {
    hipMemsetAsync(d_ws, 0, (32768 + 65536) * sizeof(float), stream);
    k_men_gemm<<<8192, 256, 0, stream>>>(X, W_men_m, W_men_o, sent_score);
    k_soft<<<512, 256, 0, stream>>>(sent_score, men_mask, X, gathers, finalr, 0);
    k_cb_gemm<<<128, 256, 0, stream>>>(finalr, W_ctx_m, cb);
    k_ctx_gemm<<<16384, 256, 0, stream>>>(X, gathers, W_ctx_c, w_ctx_d, W_ctx_o, dist, cb, ctx_score);
    k_soft<<<512, 256, 0, stream>>>(ctx_score, ctx_mask, X, gathers, finalr, 1);
    k_lat_gemm<<<dim3(2, 8), 256, 0, stream>>>(finalr, W_f2l, lat);
    k_out_gemm<<<dim3(162, 8), 256, 0, stream>>>(finalr, W_out, lat, W_l2l, lscale, out, outLat);
  }
}

// Round 2
// 662.574 us; speedup vs baseline: 1.1182x; 1.0699x over previous
//
#include <hip/hip_runtime.h>
#include <hip/hip_bf16.h>

typedef __bf16 bf16x8 __attribute__((ext_vector_type(8)));
typedef float f32x4 __attribute__((ext_vector_type(4)));
typedef unsigned short u16x8 __attribute__((ext_vector_type(8)));

#define DEV __device__ __forceinline__

static constexpr int N_SENTC = 256, BB = 512, SS = 128, DD = 1024;
static constexpr int LL = 10331, LATENT = 101;
static constexpr int LPAD = 10368;  // 162*64 = 81*128, row-padded L
static constexpr int LATPAD = 128;  // padded latent

DEV float bf2f(unsigned short u) {
  unsigned v = (unsigned)u << 16;
  return __builtin_bit_cast(float, v);
}
DEV unsigned short f2bf(float f) {
  unsigned u = __builtin_bit_cast(unsigned, f);
  unsigned lsb = (u >> 16) & 1u;
  u += 0x7fffu + lsb;
  return (unsigned short)(u >> 16);
}

// fast tanh: 1 - 2/(e^2x + 1); |err| ~1e-7 rel, saturates correctly at +-inf
DEV float fast_tanh(float x) {
  float e = __expf(2.0f * x);
  return 1.0f - 2.0f / (e + 1.0f);
}

DEV void stage8(unsigned short* dst, const float* src) {
  float4 a = *(const float4*)src;
  float4 b = *(const float4*)(src + 4);
  unsigned short t[8];
  t[0] = f2bf(a.x); t[1] = f2bf(a.y); t[2] = f2bf(a.z); t[3] = f2bf(a.w);
  t[4] = f2bf(b.x); t[5] = f2bf(b.y); t[6] = f2bf(b.z); t[7] = f2bf(b.w);
  *(uint4*)dst = *(uint4*)t;
}

// async global->LDS, 16B per lane; lds base wave-uniform (HW adds lane*16)
DEV void gl_lds16(const unsigned short* g, unsigned short* l) {
  __builtin_amdgcn_global_load_lds(
      (const __attribute__((address_space(1))) unsigned int*)g,
      (__attribute__((address_space(3))) unsigned int*)l, 16, 0, 0);
}

// ---------------------------------------------------------------------------
// f32 -> bf16 bulk convert (n4 = count/4)
// ---------------------------------------------------------------------------
__global__ __launch_bounds__(256) void k_cvt(
    const float* __restrict__ src, unsigned short* __restrict__ dst, int n4) {
  for (int i = blockIdx.x * 256 + threadIdx.x; i < n4; i += gridDim.x * 256) {
    float4 v = ((const float4*)src)[i];
    unsigned short t[4] = {f2bf(v.x), f2bf(v.y), f2bf(v.z), f2bf(v.w)};
    ((uint2*)dst)[i] = *(const uint2*)t;
  }
}

// f32 [srcR,srcC] -> bf16 [dstR,dstC] zero-padded
__global__ __launch_bounds__(256) void k_cvt_pad(
    const float* __restrict__ src, unsigned short* __restrict__ dst,
    int srcR, int srcC, int dstC, int total) {
  for (int i = blockIdx.x * 256 + threadIdx.x; i < total; i += gridDim.x * 256) {
    int r = i / dstC, c = i - r * dstC;
    dst[i] = (r < srcR && c < srcC) ? f2bf(src[(size_t)r * srcC + c]) : (unsigned short)0;
  }
}

// ---------------------------------------------------------------------------
// Fused men-score + ctx-hidden GEMM, 256x256-tile 8-phase schedule,
// PERSISTENT blocks (grid 256, 4 tiles each; colTile constant per block so
// the 512KB B-slice stays L2-hot) + fragment-register double-buffering
// (af0 for A-half0 phases 1-2, af1 for A-half1 phases 3-4: kills the WAR
// between phase-2 MFMAs and phase-3 ds_reads that serialized the pipeline).
//
// C[32768, 2048] = Xb[32768,1024] . [Wmb|Wcb]^T, K=1024 = 16 K-tiles of 64.
// 512 threads = 8 waves (2M x 4N), strided wave map:
//   row = mf*32 + wr*16 + lm  (mf 0..7)   col = nf*64 + wc*16 + lm (nf 0..3)
// LDS 128KB: [buf2][A/B][half2][8192]u16; half = [ks2][128 rows][32 bf16],
// st_16x32 swizzle: linear DMA dest + inverse-swizzled global source +
// swizzled ds_read (both-sides rule). Per K-tile 4 phases; stage order:
//   ph1: B-h1(kt+1)->buf^1   ph2: A-h0(kt+2)->buf
//   ph3: B-h0(kt+2)->buf     ph4: A-h1(kt+2)->buf, vmcnt(6), barrier
// vmcnt(6) = 3 half-tiles in flight, never 0 in steady state.
// ---------------------------------------------------------------------------
__global__ __launch_bounds__(512) void k_mc_gemm8(
    const unsigned short* __restrict__ Xb, const unsigned short* __restrict__ Wmb,
    const unsigned short* __restrict__ Wcb, const float* __restrict__ wo,
    float* __restrict__ score, unsigned short* __restrict__ Hc) {
  __shared__ __align__(16) unsigned short lds[2][2][2][8192];
  const int p = blockIdx.x;  // 256 persistent blocks
  const int tid = threadIdx.x, w = tid >> 6, lane = tid & 63;
  const int lm = lane & 15, lq = lane >> 4;
  const int wr = w >> 2, wc = w & 3;
  // staging coords: wave w stages rows [w*16, w*16+16) of each half-tile;
  // source column pre-swapped for lanes>=32 (inverse of LDS read swizzle).
  const int stRow = w * 16 + (lane >> 2);
  const int stCol = ((lane & 3) * 8) ^ ((lane >> 5) << 4);
  // read coords: byte col within 64B row, bit5 XOR'd with row-bit-3 (= lane&8)
  const int rdCol = (lq * 16) ^ ((lane & 8) ? 32 : 0);
  const int aoff = (wr * 16 + lm) * 64 + rdCol;
  const int boff = (wc * 16 + lm) * 64 + rdCol;

  // per-assignment tile state
  const unsigned short* aSrc;
  const unsigned short* bSrc;
  int rowBase, bcolBase;
  bool isMen;
  auto setTile = [&](int t) {
    const int vbid = p + 256 * t;
    const int lbid = (vbid & 7) * 128 + (vbid >> 3);  // bijective XCD swizzle
    const int colTile = lbid & 7, rowTile = lbid >> 3;
    rowBase = rowTile * 256;
    isMen = colTile < 4;
    bcolBase = (colTile & 3) * 256;
    aSrc = Xb + (size_t)(rowBase + stRow) * 1024 + stCol;
    bSrc = (isMen ? Wmb : Wcb) + (size_t)(bcolBase + stRow) * 1024 + stCol;
  };

  auto ST = [&](int op, int h, int kt, int buf) {
    const unsigned short* s = (op ? bSrc : aSrc) + (size_t)h * 131072 + kt * 64;
    unsigned short* d = &lds[buf][op][h][w * 512];
    gl_lds16(s, d);             // ks=0 block of this half
    gl_lds16(s + 32, d + 4096); // ks=1 block
  };
  auto PRO = [&]() {
    // kt0 complete (4 halves) + kt1 A-h0,B-h0,A-h1 (B-h1 comes in ph1 of kt0)
    ST(0, 0, 0, 0); ST(1, 0, 0, 0); ST(0, 1, 0, 0); ST(1, 1, 0, 0);
    ST(0, 0, 1, 1); ST(1, 0, 1, 1); ST(0, 1, 1, 1);
  };

  setTile(0);
  PRO();

  for (int t = 0; t < 4; ++t) {
    asm volatile("s_waitcnt vmcnt(6)" ::: "memory");  // kt0's 8 loads landed
    __builtin_amdgcn_s_barrier();

    f32x4 acc[8][4] = {};
    bf16x8 af0[4][2], af1[4][2], bfr[4][2];
    for (int kt = 0; kt < 16; ++kt) {
      const int buf = kt & 1;
      const char* A0 = (const char*)&lds[buf][0][0][0];
      const char* A1 = (const char*)&lds[buf][0][1][0];
      const char* B0 = (const char*)&lds[buf][1][0][0];
      const char* B1 = (const char*)&lds[buf][1][1][0];
      // ---- phase 1: Q(0,0)  reads A-h0 -> af0, B-h0 -> bfr[0..1]
#pragma unroll
      for (int m = 0; m < 4; ++m)
#pragma unroll
        for (int ks = 0; ks < 2; ++ks)
          af0[m][ks] = *(const bf16x8*)(A0 + aoff + m * 2048 + ks * 8192);
#pragma unroll
      for (int n = 0; n < 2; ++n)
#pragma unroll
        for (int ks = 0; ks < 2; ++ks)
          bfr[n][ks] = *(const bf16x8*)(B0 + boff + n * 4096 + ks * 8192);
      if (kt + 1 < 16) ST(1, 1, kt + 1, buf ^ 1);
      __builtin_amdgcn_s_barrier();
      __builtin_amdgcn_s_setprio(1);
#pragma unroll
      for (int m = 0; m < 4; ++m)
#pragma unroll
        for (int n = 0; n < 2; ++n)
#pragma unroll
          for (int ks = 0; ks < 2; ++ks)
            acc[m][n] = __builtin_amdgcn_mfma_f32_16x16x32_bf16(af0[m][ks], bfr[n][ks], acc[m][n], 0, 0, 0);
      __builtin_amdgcn_s_setprio(0);
      __builtin_amdgcn_s_barrier();
      // ---- phase 2: Q(0,1)  reads B-h1 -> bfr[2..3]
#pragma unroll
      for (int n = 0; n < 2; ++n)
#pragma unroll
        for (int ks = 0; ks < 2; ++ks)
          bfr[2 + n][ks] = *(const bf16x8*)(B1 + boff + n * 4096 + ks * 8192);
      if (kt + 2 < 16) ST(0, 0, kt + 2, buf);
      __builtin_amdgcn_s_barrier();
      __builtin_amdgcn_s_setprio(1);
#pragma unroll
      for (int m = 0; m < 4; ++m)
#pragma unroll
        for (int n = 0; n < 2; ++n)
#pragma unroll
          for (int ks = 0; ks < 2; ++ks)
            acc[m][2 + n] = __builtin_amdgcn_mfma_f32_16x16x32_bf16(af0[m][ks], bfr[2 + n][ks], acc[m][2 + n], 0, 0, 0);
      __builtin_amdgcn_s_setprio(0);
      __builtin_amdgcn_s_barrier();
      // ---- phase 3: Q(1,0)  reads A-h1 -> af1 (distinct regs: no WAR vs ph2)
#pragma unroll
      for (int m = 0; m < 4; ++m)
#pragma unroll
        for (int ks = 0; ks < 2; ++ks)
          af1[m][ks] = *(const bf16x8*)(A1 + aoff + m * 2048 + ks * 8192);
      if (kt + 2 < 16) ST(1, 0, kt + 2, buf);
      __builtin_amdgcn_s_barrier();
      __builtin_amdgcn_s_setprio(1);
#pragma unroll
      for (int m = 0; m < 4; ++m)
#pragma unroll
        for (int n = 0; n < 2; ++n)
#pragma unroll
          for (int ks = 0; ks < 2; ++ks)
            acc[4 + m][n] = __builtin_amdgcn_mfma_f32_16x16x32_bf16(af1[m][ks], bfr[n][ks], acc[4 + m][n], 0, 0, 0);
      __builtin_amdgcn_s_setprio(0);
      __builtin_amdgcn_s_barrier();
      // ---- phase 4: Q(1,1)  no reads
      if (kt + 2 < 16) ST(0, 1, kt + 2, buf);
      __builtin_amdgcn_s_barrier();
      __builtin_amdgcn_s_setprio(1);
#pragma unroll
      for (int m = 0; m < 4; ++m)
#pragma unroll
        for (int n = 0; n < 2; ++n)
#pragma unroll
          for (int ks = 0; ks < 2; ++ks)
            acc[4 + m][2 + n] = __builtin_amdgcn_mfma_f32_16x16x32_bf16(af1[m][ks], bfr[2 + n][ks], acc[4 + m][2 + n], 0, 0, 0);
      __builtin_amdgcn_s_setprio(0);
      if (kt < 14) {
        asm volatile("s_waitcnt vmcnt(6)" ::: "memory");  // kt+1 fully landed
      } else {
        asm volatile("s_waitcnt vmcnt(0)" ::: "memory");  // tail drain
      }
      __builtin_amdgcn_s_barrier();
    }

    // -------- epilogue (LDS untouched; all waves past final barrier) --------
    if (isMen) {
      float wov[4];
#pragma unroll
      for (int n = 0; n < 4; ++n) wov[n] = wo[bcolBase + n * 64 + wc * 16 + lm];
      float rsum[8][4];
#pragma unroll
      for (int m = 0; m < 8; ++m)
#pragma unroll
        for (int r = 0; r < 4; ++r) {
          float s = 0.f;
#pragma unroll
          for (int n = 0; n < 4; ++n) s += fast_tanh(acc[m][n][r]) * wov[n];
          rsum[m][r] = s;
        }
#pragma unroll
      for (int msk = 1; msk <= 8; msk <<= 1)
#pragma unroll
        for (int m = 0; m < 8; ++m)
#pragma unroll
          for (int r = 0; r < 4; ++r) rsum[m][r] += __shfl_xor(rsum[m][r], msk, 64);
      if (lm == 0) {
#pragma unroll
        for (int m = 0; m < 8; ++m)
#pragma unroll
          for (int r = 0; r < 4; ++r)
            atomicAdd(&score[rowBase + m * 32 + wr * 16 + lq * 4 + r], rsum[m][r]);
      }
    } else {
      const int cb0 = bcolBase + wc * 16 + lm;
#pragma unroll
      for (int m = 0; m < 8; ++m) {
        const int row = rowBase + m * 32 + wr * 16 + lq * 4;
#pragma unroll
        for (int n = 0; n < 4; ++n) {
          const int col = cb0 + n * 64;
#pragma unroll
          for (int r = 0; r < 4; ++r)
            Hc[(size_t)(row + r) * 1024 + col] = f2bf(acc[m][n][r]);
        }
      }
    }
    // -------- prologue for next assignment (stores drain first in vmcnt) ----
    if (t < 3) {
      setTile(t + 1);
      PRO();
    }
  }
}

// ---------------------------------------------------------------------------
// ctx score from deduped hidden (proven; tanh -> fast_tanh)
// ---------------------------------------------------------------------------
__global__ __launch_bounds__(256) void k_ctx_score(
    const unsigned short* __restrict__ Hc, const int* __restrict__ gathers,
    const float* __restrict__ cb, const float* __restrict__ wd,
    const float* __restrict__ wo, const float* __restrict__ dist,
    float* __restrict__ score) {
  const int b = blockIdx.x, tid = threadIdx.x, wave = tid >> 6, lane = tid & 63;
  const int n = gathers[b];
  __shared__ float cbl[1024], wdl[1024], wol[1024];
  for (int i = tid; i < 1024; i += 256) {
    cbl[i] = cb[b * 1024 + i];
    wdl[i] = wd[i];
    wol[i] = wo[i];
  }
  __syncthreads();
  for (int s = wave; s < 128; s += 4) {
    float d = dist[b * 128 + s];
    const unsigned short* hrow = &Hc[(size_t)(n * 128 + s) * 1024 + lane * 16];
    unsigned short hs[16];
    *(uint4*)hs = *(const uint4*)hrow;
    *(uint4*)(hs + 8) = *(const uint4*)(hrow + 8);
    float p = 0.f;
#pragma unroll
    for (int j = 0; j < 16; ++j) {
      int e = lane * 16 + j;
      p += fast_tanh(bf2f(hs[j]) + cbl[e] + d * wdl[e]) * wol[e];
    }
#pragma unroll
    for (int msk = 1; msk <= 32; msk <<= 1) p += __shfl_xor(p, msk, 64);
    if (lane == 0) score[b * 128 + s] = p;
  }
}

// ---------------------------------------------------------------------------
// softmax over S=128 + weighted sum from bf16 X -> bf16 final_repr half.
// ---------------------------------------------------------------------------
__global__ __launch_bounds__(256) void k_softb(
    const float* __restrict__ score_src, const float* __restrict__ mask,
    const unsigned short* __restrict__ Xb, const int* __restrict__ gathers,
    unsigned short* __restrict__ finalrb, int isCtx) {
  const int b = blockIdx.x, tid = threadIdx.x;
  const int n = gathers[b];
  __shared__ float attn[128];
  __shared__ float red[128 * 8];
  __shared__ float smax, ssum;
  if (tid < 128) {
    int srow = isCtx ? b : n;
    attn[tid] = score_src[srow * 128 + tid] + (1.0f - mask[b * 128 + tid]) * (-10000.0f);
  }
  __syncthreads();
  if (tid == 0) {
    float m = attn[0];
    for (int i = 1; i < 128; ++i) m = fmaxf(m, attn[i]);
    smax = m;
  }
  __syncthreads();
  if (tid < 128) attn[tid] = expf(attn[tid] - smax);
  __syncthreads();
  if (tid == 0) {
    float s = 0.f;
    for (int i = 0; i < 128; ++i) s += attn[i];
    ssum = 1.0f / s;
  }
  __syncthreads();
  if (tid < 128) attn[tid] *= ssum;
  __syncthreads();
  const unsigned short* xb = Xb + (size_t)n * 128 * 1024;
  const int c = tid & 127, h = tid >> 7;
  float acc[8] = {};
  for (int s = h; s < 128; s += 2) {
    float w = attn[s];
    u16x8 v = *(const u16x8*)&xb[(size_t)s * 1024 + c * 8];
#pragma unroll
    for (int j = 0; j < 8; ++j) acc[j] += w * bf2f(v[j]);
  }
  if (h == 1) {
#pragma unroll
    for (int j = 0; j < 8; ++j) red[c * 8 + j] = acc[j];
  }
  __syncthreads();
  if (h == 0) {
    unsigned short o[8];
#pragma unroll
    for (int j = 0; j < 8; ++j) o[j] = f2bf(acc[j] + red[c * 8 + j]);
    *(uint4*)&finalrb[(size_t)b * 2048 + (isCtx ? 1024 : 0) + c * 8] = *(uint4*)o;
  }
}

// ---------------------------------------------------------------------------
// cb GEMM (bf16 in): cb[b,e] = men_repr[b,:1024] . Wcm[e,:]; grid 128
// ---------------------------------------------------------------------------
__global__ __launch_bounds__(256) void k_cb_gemm_b(
    const unsigned short* __restrict__ finalrb, const unsigned short* __restrict__ Wcmb,
    float* __restrict__ cb) {
  __shared__ __align__(16) unsigned short As[64 * 32];
  __shared__ __align__(16) unsigned short Bs[64 * 32];
  const int bid = blockIdx.x;
  const int rowBase = (bid >> 4) * 64, colBase = (bid & 15) * 64;
  const int tid = threadIdx.x, wave = tid >> 6, lane = tid & 63;
  const int lm = lane & 15, lq = lane >> 4;
  const int sr = tid >> 2, sc = (tid & 3) * 8;
  f32x4 acc[4] = {};
  for (int k0 = 0; k0 < 1024; k0 += 32) {
    __syncthreads();
    *(uint4*)&As[sr * 32 + sc] = *(const uint4*)&finalrb[(size_t)(rowBase + sr) * 2048 + k0 + sc];
    *(uint4*)&Bs[sr * 32 + sc] = *(const uint4*)&Wcmb[(size_t)(colBase + sr) * 1024 + k0 + sc];
    __syncthreads();
    bf16x8 af = *(const bf16x8*)&As[(wave * 16 + lm) * 32 + lq * 8];
#pragma unroll
    for (int j = 0; j < 4; ++j) {
      bf16x8 bfr = *(const bf16x8*)&Bs[(j * 16 + lm) * 32 + lq * 8];
      acc[j] = __builtin_amdgcn_mfma_f32_16x16x32_bf16(af, bfr, acc[j], 0, 0, 0);
    }
  }
#pragma unroll
  for (int j = 0; j < 4; ++j) {
    int col = colBase + j * 16 + lm;
#pragma unroll
    for (int r = 0; r < 4; ++r) {
      int row = rowBase + wave * 16 + lq * 4 + r;
      cb[row * 1024 + col] = acc[j][r];
    }
  }
}

// ---------------------------------------------------------------------------
// latent GEMM (bf16): latb[b,0:128] = finalrb . Wf2lb^T; grid dim3(2,8)
// ---------------------------------------------------------------------------
__global__ __launch_bounds__(256) void k_lat_gemm_b(
    const unsigned short* __restrict__ finalrb, const unsigned short* __restrict__ Wf2lb,
    unsigned short* __restrict__ latb) {
  __shared__ __align__(16) unsigned short As[64 * 32];
  __shared__ __align__(16) unsigned short Bs[64 * 32];
  const int rowBase = blockIdx.y * 64, colBase = blockIdx.x * 64;
  const int tid = threadIdx.x, wave = tid >> 6, lane = tid & 63;
  const int lm = lane & 15, lq = lane >> 4;
  const int sr = tid >> 2, sc = (tid & 3) * 8;
  f32x4 acc[4] = {};
  for (int k0 = 0; k0 < 2048; k0 += 32) {
    __syncthreads();
    *(uint4*)&As[sr * 32 + sc] = *(const uint4*)&finalrb[(size_t)(rowBase + sr) * 2048 + k0 + sc];
    *(uint4*)&Bs[sr * 32 + sc] = *(const uint4*)&Wf2lb[(size_t)(colBase + sr) * 2048 + k0 + sc];
    __syncthreads();
    bf16x8 af = *(const bf16x8*)&As[(wave * 16 + lm) * 32 + lq * 8];
#pragma unroll
    for (int j = 0; j < 4; ++j) {
      bf16x8 bfr = *(const bf16x8*)&Bs[(j * 16 + lm) * 32 + lq * 8];
      acc[j] = __builtin_amdgcn_mfma_f32_16x16x32_bf16(af, bfr, acc[j], 0, 0, 0);
    }
  }
#pragma unroll
  for (int j = 0; j < 4; ++j) {
    int col = colBase + j * 16 + lm;
#pragma unroll
    for (int r = 0; r < 4; ++r) {
      int row = rowBase + wave * 16 + lq * 4 + r;
      latb[row * LATPAD + col] = f2bf(acc[j][r]);
    }
  }
}

// ---------------------------------------------------------------------------
// output GEMM, 128x128 async BK=64 structure:
//   acc  = finalrb[128,2048] . Woutb[128cols,2048]^T
//   acc2 = latb[128,128] . Wl2lb[128cols,128]^T
//   out = acc + scal*acc2 ; outLat = acc2. grid dim3(81, 4) - all co-resident
// ---------------------------------------------------------------------------
__global__ __launch_bounds__(256) void k_out_gemm_b(
    const unsigned short* __restrict__ finalrb, const unsigned short* __restrict__ Woutb,
    const unsigned short* __restrict__ latb, const unsigned short* __restrict__ Wl2lb,
    const float* __restrict__ lscale, float* __restrict__ out,
    float* __restrict__ outLat) {
  __shared__ __align__(16) unsigned short As[2 * 128 * 32];
  __shared__ __align__(16) unsigned short Bs[2 * 128 * 32];
  const int colBase = blockIdx.x * 128;
  const int rowBase = blockIdx.y * 128;
  const int tid = threadIdx.x, wave = tid >> 6, lane = tid & 63;
  const int lm = lane & 15, lq = lane >> 4;
  const int wr = (wave & 1) * 64, wc = (wave >> 1) * 64;
  const int srow = wave * 32 + (lane >> 2);
  const int scol = (lane & 3) * 8;
  const float scal = lscale[0];
  const unsigned short* aPtr = finalrb + (size_t)(rowBase + srow) * 2048 + scol;
  const unsigned short* bPtr = Woutb + (size_t)(colBase + srow) * 2048 + scol;
  f32x4 acc[4][4] = {};
  for (int k0 = 0; k0 < 2048; k0 += 64) {
    __syncthreads();
#pragma unroll
    for (int h = 0; h < 2; ++h) {
      gl_lds16(aPtr + k0 + h * 32, As + h * 4096 + wave * 1024);
      gl_lds16(aPtr + k0 + h * 32 + 16 * 2048, As + h * 4096 + wave * 1024 + 512);
      gl_lds16(bPtr + k0 + h * 32, Bs + h * 4096 + wave * 1024);
      gl_lds16(bPtr + k0 + h * 32 + 16 * 2048, Bs + h * 4096 + wave * 1024 + 512);
    }
    __syncthreads();
#pragma unroll
    for (int h = 0; h < 2; ++h) {
      bf16x8 af[4], bfr[4];
#pragma unroll
      for (int m = 0; m < 4; ++m)
        af[m] = *(const bf16x8*)&As[h * 4096 + (wr + m * 16 + lm) * 32 + lq * 8];
#pragma unroll
      for (int n = 0; n < 4; ++n)
        bfr[n] = *(const bf16x8*)&Bs[h * 4096 + (wc + n * 16 + lm) * 32 + lq * 8];
#pragma unroll
      for (int m = 0; m < 4; ++m)
#pragma unroll
        for (int n = 0; n < 4; ++n)
          acc[m][n] = __builtin_amdgcn_mfma_f32_16x16x32_bf16(af[m], bfr[n], acc[m][n], 0, 0, 0);
    }
  }
  // latent phase: K=128 (2 iters), separate accumulator
  const unsigned short* aPtr2 = latb + (size_t)(rowBase + srow) * LATPAD + scol;
  const unsigned short* bPtr2 = Wl2lb + (size_t)(colBase + srow) * LATPAD + scol;
  f32x4 acc2[4][4] = {};
  for (int k0 = 0; k0 < 128; k0 += 64) {
    __syncthreads();
#pragma unroll
    for (int h = 0; h < 2; ++h) {
      gl_lds16(aPtr2 + k0 + h * 32, As + h * 4096 + wave * 1024);
      gl_lds16(aPtr2 + k0 + h * 32 + 16 * LATPAD, As + h * 4096 + wave * 1024 + 512);
      gl_lds16(bPtr2 + k0 + h * 32, Bs + h * 4096 + wave * 1024);
      gl_lds16(bPtr2 + k0 + h * 32 + 16 * LATPAD, Bs + h * 4096 + wave * 1024 + 512);
    }
    __syncthreads();
#pragma unroll
    for (int h = 0; h < 2; ++h) {
      bf16x8 af[4], bfr[4];
#pragma unroll
      for (int m = 0; m < 4; ++m)
        af[m] = *(const bf16x8*)&As[h * 4096 + (wr + m * 16 + lm) * 32 + lq * 8];
#pragma unroll
      for (int n = 0; n < 4; ++n)
        bfr[n] = *(const bf16x8*)&Bs[h * 4096 + (wc + n * 16 + lm) * 32 + lq * 8];
#pragma unroll
      for (int m = 0; m < 4; ++m)
#pragma unroll
        for (int n = 0; n < 4; ++n)
          acc2[m][n] = __builtin_amdgcn_mfma_f32_16x16x32_bf16(af[m], bfr[n], acc2[m][n], 0, 0, 0);
    }
  }
#pragma unroll
  for (int m = 0; m < 4; ++m)
#pragma unroll
    for (int n = 0; n < 4; ++n) {
      int col = colBase + wc + n * 16 + lm;
      if (col < LL) {
#pragma unroll
        for (int r = 0; r < 4; ++r) {
          int row = rowBase + wr + m * 16 + lq * 4 + r;
          float lv = acc2[m][n][r];
          out[(size_t)row * LL + col] = acc[m][n][r] + scal * lv;
          outLat[(size_t)row * LL + col] = lv;
        }
      }
    }
}

// ======================= legacy fallback (round-3, proven) ==================
__global__ __launch_bounds__(256) void k_men_gemm(
    const float* __restrict__ X, const float* __restrict__ Wm,
    const float* __restrict__ wo, float* __restrict__ score) {
  __shared__ __align__(16) unsigned short As[64 * 32];
  __shared__ __align__(16) unsigned short Bs[64 * 32];
  const int bid = blockIdx.x;
  const int rowBase = (bid >> 4) * 64, colBase = (bid & 15) * 64;
  const int tid = threadIdx.x, wave = tid >> 6, lane = tid & 63;
  const int lm = lane & 15, lq = lane >> 4;
  const int sr = tid >> 2, sc = (tid & 3) * 8;
  f32x4 acc[4] = {};
  for (int k0 = 0; k0 < 1024; k0 += 32) {
    __syncthreads();
    stage8(&As[sr * 32 + sc], &X[(size_t)(rowBase + sr) * 1024 + k0 + sc]);
    stage8(&Bs[sr * 32 + sc], &Wm[(size_t)(colBase + sr) * 1024 + k0 + sc]);
    __syncthreads();
    bf16x8 af = *(const bf16x8*)&As[(wave * 16 + lm) * 32 + lq * 8];
#pragma unroll
    for (int j = 0; j < 4; ++j) {
      bf16x8 bfr = *(const bf16x8*)&Bs[(j * 16 + lm) * 32 + lq * 8];
      acc[j] = __builtin_amdgcn_mfma_f32_16x16x32_bf16(af, bfr, acc[j], 0, 0, 0);
    }
  }
  float rsum[4] = {0.f, 0.f, 0.f, 0.f};
#pragma unroll
  for (int j = 0; j < 4; ++j) {
    float w = wo[colBase + j * 16 + lm];
#pragma unroll
    for (int r = 0; r < 4; ++r) rsum[r] += tanhf(acc[j][r]) * w;
  }
#pragma unroll
  for (int m = 1; m <= 8; m <<= 1)
#pragma unroll
    for (int r = 0; r < 4; ++r) rsum[r] += __shfl_xor(rsum[r], m, 64);
  if (lm == 0) {
    int row0 = rowBase + wave * 16 + lq * 4;
#pragma unroll
    for (int r = 0; r < 4; ++r) atomicAdd(&score[row0 + r], rsum[r]);
  }
}

__global__ __launch_bounds__(256) void k_ctx_gemm(
    const float* __restrict__ X, const int* __restrict__ gathers,
    const float* __restrict__ Wc, const float* __restrict__ wd,
    const float* __restrict__ wo, const float* __restrict__ dist,
    const float* __restrict__ cb, float* __restrict__ score) {
  __shared__ __align__(16) unsigned short As[64 * 32];
  __shared__ __align__(16) unsigned short Bs[64 * 32];
  const int bid = blockIdx.x;
  const int rowBase = (bid >> 4) * 64, colBase = (bid & 15) * 64;
  const int tid = threadIdx.x, wave = tid >> 6, lane = tid & 63;
  const int lm = lane & 15, lq = lane >> 4;
  const int sr = tid >> 2, sc = (tid & 3) * 8;
  const int row_g = rowBase + sr;
  const int srcRow = (gathers[row_g >> 7] << 7) + (row_g & 127);
  f32x4 acc[4] = {};
  for (int k0 = 0; k0 < 1024; k0 += 32) {
    __syncthreads();
    stage8(&As[sr * 32 + sc], &X[(size_t)srcRow * 1024 + k0 + sc]);
    stage8(&Bs[sr * 32 + sc], &Wc[(size_t)(colBase + sr) * 1024 + k0 + sc]);
    __syncthreads();
    bf16x8 af = *(const bf16x8*)&As[(wave * 16 + lm) * 32 + lq * 8];
#pragma unroll
    for (int j = 0; j < 4; ++j) {
      bf16x8 bfr = *(const bf16x8*)&Bs[(j * 16 + lm) * 32 + lq * 8];
      acc[j] = __builtin_amdgcn_mfma_f32_16x16x32_bf16(af, bfr, acc[j], 0, 0, 0);
    }
  }
  float rsum[4] = {0.f, 0.f, 0.f, 0.f};
#pragma unroll
  for (int j = 0; j < 4; ++j) {
    int col = colBase + j * 16 + lm;
    float w = wo[col];
    float wdv = wd[col];
#pragma unroll
    for (int r = 0; r < 4; ++r) {
      int rg = rowBase + wave * 16 + lq * 4 + r;
      int b = rg >> 7, s = rg & 127;
      float v = acc[j][r] + cb[b * 1024 + col] + dist[b * 128 + s] * wdv;
      rsum[r] += tanhf(v) * w;
    }
  }
#pragma unroll
  for (int m = 1; m <= 8; m <<= 1)
#pragma unroll
    for (int r = 0; r < 4; ++r) rsum[r] += __shfl_xor(rsum[r], m, 64);
  if (lm == 0) {
    int row0 = rowBase + wave * 16 + lq * 4;
#pragma unroll
    for (int r = 0; r < 4; ++r) atomicAdd(&score[row0 + r], rsum[r]);
  }
}

__global__ __launch_bounds__(256) void k_soft(
    const float* __restrict__ score_src, const float* __restrict__ mask,
    const float* __restrict__ X, const int* __restrict__ gathers,
    float* __restrict__ finalr, int isCtx) {
  const int b = blockIdx.x, tid = threadIdx.x;
  const int n = gathers[b];
  __shared__ float attn[128];
  __shared__ float smax, ssum;
  if (tid < 128) {
    int srow = isCtx ? b : n;
    attn[tid] = score_src[srow * 128 + tid] + (1.0f - mask[b * 128 + tid]) * (-10000.0f);
  }
  __syncthreads();
  if (tid == 0) {
    float m = attn[0];
    for (int i = 1; i < 128; ++i) m = fmaxf(m, attn[i]);
    smax = m;
  }
  __syncthreads();
  if (tid < 128) attn[tid] = expf(attn[tid] - smax);
  __syncthreads();
  if (tid == 0) {
    float s = 0.f;
    for (int i = 0; i < 128; ++i) s += attn[i];
    ssum = 1.0f / s;
  }
  __syncthreads();
  if (tid < 128) attn[tid] *= ssum;
  __syncthreads();
  const float* xb = &X[(size_t)(n << 7) * 1024];
  const int off = isCtx ? 1024 : 0;
  for (int d = tid; d < 1024; d += 256) {
    float a = 0.f;
#pragma unroll 8
    for (int s = 0; s < 128; ++s) a += attn[s] * xb[s * 1024 + d];
    finalr[b * 2048 + off + d] = a;
  }
}

__global__ __launch_bounds__(256) void k_cb_gemm(
    const float* __restrict__ finalr, const float* __restrict__ Wcm,
    float* __restrict__ cb) {
  __shared__ __align__(16) unsigned short As[64 * 32];
  __shared__ __align__(16) unsigned short Bs[64 * 32];
  const int bid = blockIdx.x;
  const int rowBase = (bid >> 4) * 64, colBase = (bid & 15) * 64;
  const int tid = threadIdx.x, wave = tid >> 6, lane = tid & 63;
  const int lm = lane & 15, lq = lane >> 4;
  const int sr = tid >> 2, sc = (tid & 3) * 8;
  f32x4 acc[4] = {};
  for (int k0 = 0; k0 < 1024; k0 += 32) {
    __syncthreads();
    stage8(&As[sr * 32 + sc], &finalr[(size_t)(rowBase + sr) * 2048 + k0 + sc]);
    stage8(&Bs[sr * 32 + sc], &Wcm[(size_t)(colBase + sr) * 1024 + k0 + sc]);
    __syncthreads();
    bf16x8 af = *(const bf16x8*)&As[(wave * 16 + lm) * 32 + lq * 8];
#pragma unroll
    for (int j = 0; j < 4; ++j) {
      bf16x8 bfr = *(const bf16x8*)&Bs[(j * 16 + lm) * 32 + lq * 8];
      acc[j] = __builtin_amdgcn_mfma_f32_16x16x32_bf16(af, bfr, acc[j], 0, 0, 0);
    }
  }
#pragma unroll
  for (int j = 0; j < 4; ++j) {
    int col = colBase + j * 16 + lm;
#pragma unroll
    for (int r = 0; r < 4; ++r) {
      int row = rowBase + wave * 16 + lq * 4 + r;
      cb[row * 1024 + col] = acc[j][r];
    }
  }
}

__global__ __launch_bounds__(256) void k_lat_gemm(
    const float* __restrict__ finalr, const float* __restrict__ Wf2l,
    float* __restrict__ lat) {
  __shared__ __align__(16) unsigned short As[64 * 32];
  __shared__ __align__(16) unsigned short Bs[64 * 32];
  const int rowBase = blockIdx.y * 64, colBase = blockIdx.x * 64;
  const int tid = threadIdx.x, wave = tid >> 6, lane = tid & 63;
  const int lm = lane & 15, lq = lane >> 4;
  const int sr = tid >> 2, sc = (tid & 3) * 8;
  f32x4 acc[4] = {};
  for (int k0 = 0; k0 < 2048; k0 += 32) {
    __syncthreads();
    stage8(&As[sr * 32 + sc], &finalr[(size_t)(rowBase + sr) * 2048 + k0 + sc]);
    int l = colBase + sr;
    if (l < LATENT) {
      stage8(&Bs[sr * 32 + sc], &Wf2l[(size_t)l * 2048 + k0 + sc]);
    } else {
      uint4 z = {0, 0, 0, 0};
      *(uint4*)&Bs[sr * 32 + sc] = z;
    }
    __syncthreads();
    bf16x8 af = *(const bf16x8*)&As[(wave * 16 + lm) * 32 + lq * 8];
#pragma unroll
    for (int j = 0; j < 4; ++j) {
      bf16x8 bfr = *(const bf16x8*)&Bs[(j * 16 + lm) * 32 + lq * 8];
      acc[j] = __builtin_amdgcn_mfma_f32_16x16x32_bf16(af, bfr, acc[j], 0, 0, 0);
    }
  }
#pragma unroll
  for (int j = 0; j < 4; ++j) {
    int col = colBase + j * 16 + lm;
    if (col < LATENT) {
#pragma unroll
      for (int r = 0; r < 4; ++r) {
        int row = rowBase + wave * 16 + lq * 4 + r;
        lat[row * LATENT + col] = acc[j][r];
      }
    }
  }
}

__global__ __launch_bounds__(256) void k_out_gemm(
    const float* __restrict__ finalr, const float* __restrict__ Wout,
    const float* __restrict__ lat, const float* __restrict__ Wl2l,
    const float* __restrict__ lscale, float* __restrict__ out,
    float* __restrict__ outLat) {
  __shared__ __align__(16) unsigned short As[64 * 32];
  __shared__ __align__(16) unsigned short Bs[64 * 32];
  const int rowBase = blockIdx.y * 64, colBase = blockIdx.x * 64;
  const int tid = threadIdx.x, wave = tid >> 6, lane = tid & 63;
  const int lm = lane & 15, lq = lane >> 4;
  const int sr = tid >> 2, sc = (tid & 3) * 8;
  const float scal = lscale[0];
  const int lrow = colBase + sr;
  const bool lvalid = (lrow < LL);
  f32x4 acc[4] = {};
  for (int k0 = 0; k0 < 2048; k0 += 32) {
    __syncthreads();
    stage8(&As[sr * 32 + sc], &finalr[(size_t)(rowBase + sr) * 2048 + k0 + sc]);
    if (lvalid) {
      stage8(&Bs[sr * 32 + sc], &Wout[(size_t)lrow * 2048 + k0 + sc]);
    } else {
      uint4 z = {0, 0, 0, 0};
      *(uint4*)&Bs[sr * 32 + sc] = z;
    }
    __syncthreads();
    bf16x8 af = *(const bf16x8*)&As[(wave * 16 + lm) * 32 + lq * 8];
#pragma unroll
    for (int j = 0; j < 4; ++j) {
      bf16x8 bfr = *(const bf16x8*)&Bs[(j * 16 + lm) * 32 + lq * 8];
      acc[j] = __builtin_amdgcn_mfma_f32_16x16x32_bf16(af, bfr, acc[j], 0, 0, 0);
    }
  }
  f32x4 acc2[4] = {};
  for (int k2 = 0; k2 < 128; k2 += 32) {
    __syncthreads();
    const int brow = rowBase + sr;
#pragma unroll
    for (int jj = 0; jj < 8; ++jj) {
      int idx = k2 + sc + jj;
      As[sr * 32 + sc + jj] = (idx < LATENT) ? f2bf(lat[brow * LATENT + idx]) : (unsigned short)0;
      Bs[sr * 32 + sc + jj] = (lvalid && idx < LATENT) ? f2bf(Wl2l[lrow * LATENT + idx]) : (unsigned short)0;
    }
    __syncthreads();
    bf16x8 af = *(const bf16x8*)&As[(wave * 16 + lm) * 32 + lq * 8];
#pragma unroll
    for (int j = 0; j < 4; ++j) {
      bf16x8 bfr = *(const bf16x8*)&Bs[(j * 16 + lm) * 32 + lq * 8];
      acc2[j] = __builtin_amdgcn_mfma_f32_16x16x32_bf16(af, bfr, acc2[j], 0, 0, 0);
    }
  }
#pragma unroll
  for (int j = 0; j < 4; ++j) {
    int col = colBase + j * 16 + lm;
    if (col < LL) {
#pragma unroll
      for (int r = 0; r < 4; ++r) {
        int row = rowBase + wave * 16 + lq * 4 + r;
        float lv = acc2[j][r];
        out[(size_t)row * LL + col] = acc[j][r] + scal * lv;
        outLat[(size_t)row * LL + col] = lv;
      }
    }
  }
}

extern "C" void kernel_launch(void* const* d_in, const int* in_sizes, int n_in,
                              void* d_out, int out_size, void* d_ws, size_t ws_size,
                              hipStream_t stream) {
  const float* X = (const float*)d_in[0];
  const float* men_mask = (const float*)d_in[1];
  const float* ctx_mask = (const float*)d_in[2];
  const float* dist = (const float*)d_in[3];
  const int* gathers = (const int*)d_in[4];
  const float* W_men_m = (const float*)d_in[5];
  const float* W_men_o = (const float*)d_in[6];
  const float* W_ctx_c = (const float*)d_in[7];
  const float* W_ctx_m = (const float*)d_in[8];
  const float* w_ctx_d = (const float*)d_in[9];
  const float* W_ctx_o = (const float*)d_in[10];
  const float* W_out = (const float*)d_in[11];
  const float* W_f2l = (const float*)d_in[12];
  const float* W_l2l = (const float*)d_in[13];
  const float* lscale = (const float*)d_in[14];
  float* out = (float*)d_out;
  float* outLat = out + (size_t)BB * LL;

  size_t off = 0;
  auto carve = [&](size_t bytes) {
    void* p = (char*)d_ws + off;
    off = (off + bytes + 255) & ~(size_t)255;
    return p;
  };
  float* sent_score = (float*)carve(32768 * 4);
  float* ctx_score = (float*)carve(65536 * 4);
  float* finalr = (float*)carve((size_t)512 * 2048 * 4);        // legacy only
  float* cb = (float*)carve((size_t)512 * 1024 * 4);
  float* lat = (float*)carve((size_t)512 * LATENT * 4);         // legacy only
  unsigned short* Xb = (unsigned short*)carve((size_t)32768 * 1024 * 2);
  unsigned short* Wmb = (unsigned short*)carve((size_t)1024 * 1024 * 2);
  unsigned short* Wcb = (unsigned short*)carve((size_t)1024 * 1024 * 2);
  unsigned short* Wcmb = (unsigned short*)carve((size_t)1024 * 1024 * 2);
  unsigned short* Hc = (unsigned short*)carve((size_t)32768 * 1024 * 2);
  unsigned short* Wf2lb = (unsigned short*)carve((size_t)LATPAD * 2048 * 2);
  unsigned short* Wl2lb = (unsigned short*)carve((size_t)LPAD * LATPAD * 2);
  unsigned short* finalrb = (unsigned short*)carve((size_t)512 * 2048 * 2);
  unsigned short* latb = (unsigned short*)carve((size_t)512 * LATPAD * 2);
  const bool fits = off <= ws_size;
  // Woutb aliases Xb (Xb dead after ctx softmax; LPAD*2048*2 = 42.5 MB <= 67 MB)
  unsigned short* Woutb = Xb;

  if (fits) {
    hipMemsetAsync(sent_score, 0, 32768 * sizeof(float), stream);
    k_cvt<<<8192, 256, 0, stream>>>(X, Xb, 32768 * 1024 / 4);
    k_cvt<<<1024, 256, 0, stream>>>(W_men_m, Wmb, 1024 * 1024 / 4);
    k_cvt<<<1024, 256, 0, stream>>>(W_ctx_c, Wcb, 1024 * 1024 / 4);
    k_cvt<<<1024, 256, 0, stream>>>(W_ctx_m, Wcmb, 1024 * 1024 / 4);
    k_cvt_pad<<<512, 256, 0, stream>>>(W_f2l, Wf2lb, LATENT, 2048, 2048, LATPAD * 2048);
    k_cvt_pad<<<1024, 256, 0, stream>>>(W_l2l, Wl2lb, LL, LATENT, LATPAD, LPAD * LATPAD);
    k_mc_gemm8<<<256, 512, 0, stream>>>(Xb, Wmb, Wcb, W_men_o, sent_score, Hc);
    k_softb<<<512, 256, 0, stream>>>(sent_score, men_mask, Xb, gathers, finalrb, 0);
    k_cb_gemm_b<<<128, 256, 0, stream>>>(finalrb, Wcmb, cb);
    k_ctx_score<<<512, 256, 0, stream>>>(Hc, gathers, cb, w_ctx_d, W_ctx_o, dist, ctx_score);
    k_softb<<<512, 256, 0, stream>>>(ctx_score, ctx_mask, Xb, gathers, finalrb, 1);
    k_lat_gemm_b<<<dim3(2, 8), 256, 0, stream>>>(finalrb, Wf2lb, latb);
    // Xb dead; convert W_out (zero-padded rows) into its space
    k_cvt_pad<<<8192, 256, 0, stream>>>(W_out, Woutb, LL, 2048, 2048, LPAD * 2048);
    k_out_gemm_b<<<dim3(81, 4), 256, 0, stream>>>(finalrb, Woutb, latb, Wl2lb,
                                                  lscale, out, outLat);
  } else {
    hipMemsetAsync(d_ws, 0, (32768 + 65536) * sizeof(float), stream);
    k_men_gemm<<<8192, 256, 0, stream>>>(X, W_men_m, W_men_o, sent_score);
    k_soft<<<512, 256, 0, stream>>>(sent_score, men_mask, X, gathers, finalr, 0);
    k_cb_gemm<<<128, 256, 0, stream>>>(finalr, W_ctx_m, cb);
    k_ctx_gemm<<<16384, 256, 0, stream>>>(X, gathers, W_ctx_c, w_ctx_d, W_ctx_o, dist, cb, ctx_score);
    k_soft<<<512, 256, 0, stream>>>(ctx_score, ctx_mask, X, gathers, finalr, 1);
    k_lat_gemm<<<dim3(2, 8), 256, 0, stream>>>(finalr, W_f2l, lat);
    k_out_gemm<<<dim3(162, 8), 256, 0, stream>>>(finalr, W_out, lat, W_l2l, lscale, out, outLat);
  }
}

// Round 3
// 657.421 us; speedup vs baseline: 1.1269x; 1.0078x over previous
//
#include <hip/hip_runtime.h>
#include <hip/hip_bf16.h>

typedef __bf16 bf16x8 __attribute__((ext_vector_type(8)));
typedef float f32x4 __attribute__((ext_vector_type(4)));
typedef unsigned short u16x8 __attribute__((ext_vector_type(8)));

#define DEV __device__ __forceinline__

static constexpr int N_SENTC = 256, BB = 512, SS = 128, DD = 1024;
static constexpr int LL = 10331, LATENT = 101;
static constexpr int LPAD = 10368;  // 162*64 = 81*128, row-padded L
static constexpr int LATPAD = 128;  // padded latent

DEV float bf2f(unsigned short u) {
  unsigned v = (unsigned)u << 16;
  return __builtin_bit_cast(float, v);
}
DEV unsigned short f2bf(float f) {
  unsigned u = __builtin_bit_cast(unsigned, f);
  unsigned lsb = (u >> 16) & 1u;
  u += 0x7fffu + lsb;
  return (unsigned short)(u >> 16);
}

// fast tanh: 1 - 2/(e^2x + 1); |err| ~1e-7 rel, saturates correctly at +-inf
DEV float fast_tanh(float x) {
  float e = __expf(2.0f * x);
  return 1.0f - 2.0f / (e + 1.0f);
}

DEV void stage8(unsigned short* dst, const float* src) {
  float4 a = *(const float4*)src;
  float4 b = *(const float4*)(src + 4);
  unsigned short t[8];
  t[0] = f2bf(a.x); t[1] = f2bf(a.y); t[2] = f2bf(a.z); t[3] = f2bf(a.w);
  t[4] = f2bf(b.x); t[5] = f2bf(b.y); t[6] = f2bf(b.z); t[7] = f2bf(b.w);
  *(uint4*)dst = *(uint4*)t;
}

// async global->LDS, 16B per lane; lds base wave-uniform (HW adds lane*16)
DEV void gl_lds16(const unsigned short* g, unsigned short* l) {
  __builtin_amdgcn_global_load_lds(
      (const __attribute__((address_space(1))) unsigned int*)g,
      (__attribute__((address_space(3))) unsigned int*)l, 16, 0, 0);
}

// ---------------------------------------------------------------------------
// f32 -> bf16 bulk convert (n4 = count/4)
// ---------------------------------------------------------------------------
__global__ __launch_bounds__(256) void k_cvt(
    const float* __restrict__ src, unsigned short* __restrict__ dst, int n4) {
  for (int i = blockIdx.x * 256 + threadIdx.x; i < n4; i += gridDim.x * 256) {
    float4 v = ((const float4*)src)[i];
    unsigned short t[4] = {f2bf(v.x), f2bf(v.y), f2bf(v.z), f2bf(v.w)};
    ((uint2*)dst)[i] = *(const uint2*)t;
  }
}

// f32 [srcR,srcC] -> bf16 [dstR,dstC] zero-padded
__global__ __launch_bounds__(256) void k_cvt_pad(
    const float* __restrict__ src, unsigned short* __restrict__ dst,
    int srcR, int srcC, int dstC, int total) {
  for (int i = blockIdx.x * 256 + threadIdx.x; i < total; i += gridDim.x * 256) {
    int r = i / dstC, c = i - r * dstC;
    dst[i] = (r < srcR && c < srcC) ? f2bf(src[(size_t)r * srcC + c]) : (unsigned short)0;
  }
}

// ---------------------------------------------------------------------------
// Fused men-score + ctx-hidden GEMM, 256x256-tile 8-phase schedule,
// PERSISTENT blocks (grid 256, 4 tiles each; colTile constant per block so
// the 512KB B-slice stays L2-hot) + fragment-register double-buffering
// (af0 phases 1-2, af1 phases 3-4). Proven at 167us / 822 TF.
// ---------------------------------------------------------------------------
__global__ __launch_bounds__(512) void k_mc_gemm8(
    const unsigned short* __restrict__ Xb, const unsigned short* __restrict__ Wmb,
    const unsigned short* __restrict__ Wcb, const float* __restrict__ wo,
    float* __restrict__ score, unsigned short* __restrict__ Hc) {
  __shared__ __align__(16) unsigned short lds[2][2][2][8192];
  const int p = blockIdx.x;  // 256 persistent blocks
  const int tid = threadIdx.x, w = tid >> 6, lane = tid & 63;
  const int lm = lane & 15, lq = lane >> 4;
  const int wr = w >> 2, wc = w & 3;
  // staging coords: wave w stages rows [w*16, w*16+16) of each half-tile;
  // source column pre-swapped for lanes>=32 (inverse of LDS read swizzle).
  const int stRow = w * 16 + (lane >> 2);
  const int stCol = ((lane & 3) * 8) ^ ((lane >> 5) << 4);
  // read coords: byte col within 64B row, bit5 XOR'd with row-bit-3 (= lane&8)
  const int rdCol = (lq * 16) ^ ((lane & 8) ? 32 : 0);
  const int aoff = (wr * 16 + lm) * 64 + rdCol;
  const int boff = (wc * 16 + lm) * 64 + rdCol;

  // per-assignment tile state
  const unsigned short* aSrc;
  const unsigned short* bSrc;
  int rowBase, bcolBase;
  bool isMen;
  auto setTile = [&](int t) {
    const int vbid = p + 256 * t;
    const int lbid = (vbid & 7) * 128 + (vbid >> 3);  // bijective XCD swizzle
    const int colTile = lbid & 7, rowTile = lbid >> 3;
    rowBase = rowTile * 256;
    isMen = colTile < 4;
    bcolBase = (colTile & 3) * 256;
    aSrc = Xb + (size_t)(rowBase + stRow) * 1024 + stCol;
    bSrc = (isMen ? Wmb : Wcb) + (size_t)(bcolBase + stRow) * 1024 + stCol;
  };

  auto ST = [&](int op, int h, int kt, int buf) {
    const unsigned short* s = (op ? bSrc : aSrc) + (size_t)h * 131072 + kt * 64;
    unsigned short* d = &lds[buf][op][h][w * 512];
    gl_lds16(s, d);             // ks=0 block of this half
    gl_lds16(s + 32, d + 4096); // ks=1 block
  };
  auto PRO = [&]() {
    // kt0 complete (4 halves) + kt1 A-h0,B-h0,A-h1 (B-h1 comes in ph1 of kt0)
    ST(0, 0, 0, 0); ST(1, 0, 0, 0); ST(0, 1, 0, 0); ST(1, 1, 0, 0);
    ST(0, 0, 1, 1); ST(1, 0, 1, 1); ST(0, 1, 1, 1);
  };

  setTile(0);
  PRO();

  for (int t = 0; t < 4; ++t) {
    asm volatile("s_waitcnt vmcnt(6)" ::: "memory");  // kt0's 8 loads landed
    __builtin_amdgcn_s_barrier();

    f32x4 acc[8][4] = {};
    bf16x8 af0[4][2], af1[4][2], bfr[4][2];
    for (int kt = 0; kt < 16; ++kt) {
      const int buf = kt & 1;
      const char* A0 = (const char*)&lds[buf][0][0][0];
      const char* A1 = (const char*)&lds[buf][0][1][0];
      const char* B0 = (const char*)&lds[buf][1][0][0];
      const char* B1 = (const char*)&lds[buf][1][1][0];
      // ---- phase 1: Q(0,0)  reads A-h0 -> af0, B-h0 -> bfr[0..1]
#pragma unroll
      for (int m = 0; m < 4; ++m)
#pragma unroll
        for (int ks = 0; ks < 2; ++ks)
          af0[m][ks] = *(const bf16x8*)(A0 + aoff + m * 2048 + ks * 8192);
#pragma unroll
      for (int n = 0; n < 2; ++n)
#pragma unroll
        for (int ks = 0; ks < 2; ++ks)
          bfr[n][ks] = *(const bf16x8*)(B0 + boff + n * 4096 + ks * 8192);
      if (kt + 1 < 16) ST(1, 1, kt + 1, buf ^ 1);
      __builtin_amdgcn_s_barrier();
      __builtin_amdgcn_s_setprio(1);
#pragma unroll
      for (int m = 0; m < 4; ++m)
#pragma unroll
        for (int n = 0; n < 2; ++n)
#pragma unroll
          for (int ks = 0; ks < 2; ++ks)
            acc[m][n] = __builtin_amdgcn_mfma_f32_16x16x32_bf16(af0[m][ks], bfr[n][ks], acc[m][n], 0, 0, 0);
      __builtin_amdgcn_s_setprio(0);
      __builtin_amdgcn_s_barrier();
      // ---- phase 2: Q(0,1)  reads B-h1 -> bfr[2..3]
#pragma unroll
      for (int n = 0; n < 2; ++n)
#pragma unroll
        for (int ks = 0; ks < 2; ++ks)
          bfr[2 + n][ks] = *(const bf16x8*)(B1 + boff + n * 4096 + ks * 8192);
      if (kt + 2 < 16) ST(0, 0, kt + 2, buf);
      __builtin_amdgcn_s_barrier();
      __builtin_amdgcn_s_setprio(1);
#pragma unroll
      for (int m = 0; m < 4; ++m)
#pragma unroll
        for (int n = 0; n < 2; ++n)
#pragma unroll
          for (int ks = 0; ks < 2; ++ks)
            acc[m][2 + n] = __builtin_amdgcn_mfma_f32_16x16x32_bf16(af0[m][ks], bfr[2 + n][ks], acc[m][2 + n], 0, 0, 0);
      __builtin_amdgcn_s_setprio(0);
      __builtin_amdgcn_s_barrier();
      // ---- phase 3: Q(1,0)  reads A-h1 -> af1 (distinct regs: no WAR vs ph2)
#pragma unroll
      for (int m = 0; m < 4; ++m)
#pragma unroll
        for (int ks = 0; ks < 2; ++ks)
          af1[m][ks] = *(const bf16x8*)(A1 + aoff + m * 2048 + ks * 8192);
      if (kt + 2 < 16) ST(1, 0, kt + 2, buf);
      __builtin_amdgcn_s_barrier();
      __builtin_amdgcn_s_setprio(1);
#pragma unroll
      for (int m = 0; m < 4; ++m)
#pragma unroll
        for (int n = 0; n < 2; ++n)
#pragma unroll
          for (int ks = 0; ks < 2; ++ks)
            acc[4 + m][n] = __builtin_amdgcn_mfma_f32_16x16x32_bf16(af1[m][ks], bfr[n][ks], acc[4 + m][n], 0, 0, 0);
      __builtin_amdgcn_s_setprio(0);
      __builtin_amdgcn_s_barrier();
      // ---- phase 4: Q(1,1)  no reads
      if (kt + 2 < 16) ST(0, 1, kt + 2, buf);
      __builtin_amdgcn_s_barrier();
      __builtin_amdgcn_s_setprio(1);
#pragma unroll
      for (int m = 0; m < 4; ++m)
#pragma unroll
        for (int n = 0; n < 2; ++n)
#pragma unroll
          for (int ks = 0; ks < 2; ++ks)
            acc[4 + m][2 + n] = __builtin_amdgcn_mfma_f32_16x16x32_bf16(af1[m][ks], bfr[2 + n][ks], acc[4 + m][2 + n], 0, 0, 0);
      __builtin_amdgcn_s_setprio(0);
      if (kt < 14) {
        asm volatile("s_waitcnt vmcnt(6)" ::: "memory");  // kt+1 fully landed
      } else {
        asm volatile("s_waitcnt vmcnt(0)" ::: "memory");  // tail drain
      }
      __builtin_amdgcn_s_barrier();
    }

    // -------- epilogue (LDS untouched; all waves past final barrier) --------
    if (isMen) {
      float wov[4];
#pragma unroll
      for (int n = 0; n < 4; ++n) wov[n] = wo[bcolBase + n * 64 + wc * 16 + lm];
      float rsum[8][4];
#pragma unroll
      for (int m = 0; m < 8; ++m)
#pragma unroll
        for (int r = 0; r < 4; ++r) {
          float s = 0.f;
#pragma unroll
          for (int n = 0; n < 4; ++n) s += fast_tanh(acc[m][n][r]) * wov[n];
          rsum[m][r] = s;
        }
#pragma unroll
      for (int msk = 1; msk <= 8; msk <<= 1)
#pragma unroll
        for (int m = 0; m < 8; ++m)
#pragma unroll
          for (int r = 0; r < 4; ++r) rsum[m][r] += __shfl_xor(rsum[m][r], msk, 64);
      if (lm == 0) {
#pragma unroll
        for (int m = 0; m < 8; ++m)
#pragma unroll
          for (int r = 0; r < 4; ++r)
            atomicAdd(&score[rowBase + m * 32 + wr * 16 + lq * 4 + r], rsum[m][r]);
      }
    } else {
      const int cb0 = bcolBase + wc * 16 + lm;
#pragma unroll
      for (int m = 0; m < 8; ++m) {
        const int row = rowBase + m * 32 + wr * 16 + lq * 4;
#pragma unroll
        for (int n = 0; n < 4; ++n) {
          const int col = cb0 + n * 64;
#pragma unroll
          for (int r = 0; r < 4; ++r)
            Hc[(size_t)(row + r) * 1024 + col] = f2bf(acc[m][n][r]);
        }
      }
    }
    // -------- prologue for next assignment (stores drain first in vmcnt) ----
    if (t < 3) {
      setTile(t + 1);
      PRO();
    }
  }
}

// ---------------------------------------------------------------------------
// ctx score from deduped hidden (proven; fast_tanh)
// ---------------------------------------------------------------------------
__global__ __launch_bounds__(256) void k_ctx_score(
    const unsigned short* __restrict__ Hc, const int* __restrict__ gathers,
    const float* __restrict__ cb, const float* __restrict__ wd,
    const float* __restrict__ wo, const float* __restrict__ dist,
    float* __restrict__ score) {
  const int b = blockIdx.x, tid = threadIdx.x, wave = tid >> 6, lane = tid & 63;
  const int n = gathers[b];
  __shared__ float cbl[1024], wdl[1024], wol[1024];
  for (int i = tid; i < 1024; i += 256) {
    cbl[i] = cb[b * 1024 + i];
    wdl[i] = wd[i];
    wol[i] = wo[i];
  }
  __syncthreads();
  for (int s = wave; s < 128; s += 4) {
    float d = dist[b * 128 + s];
    const unsigned short* hrow = &Hc[(size_t)(n * 128 + s) * 1024 + lane * 16];
    unsigned short hs[16];
    *(uint4*)hs = *(const uint4*)hrow;
    *(uint4*)(hs + 8) = *(const uint4*)(hrow + 8);
    float p = 0.f;
#pragma unroll
    for (int j = 0; j < 16; ++j) {
      int e = lane * 16 + j;
      p += fast_tanh(bf2f(hs[j]) + cbl[e] + d * wdl[e]) * wol[e];
    }
#pragma unroll
    for (int msk = 1; msk <= 32; msk <<= 1) p += __shfl_xor(p, msk, 64);
    if (lane == 0) score[b * 128 + s] = p;
  }
}

// ---------------------------------------------------------------------------
// softmax over S=128 (wave-parallel reduce) + weighted sum -> bf16 repr half
// ---------------------------------------------------------------------------
__global__ __launch_bounds__(256) void k_softb(
    const float* __restrict__ score_src, const float* __restrict__ mask,
    const unsigned short* __restrict__ Xb, const int* __restrict__ gathers,
    unsigned short* __restrict__ finalrb, int isCtx) {
  const int b = blockIdx.x, tid = threadIdx.x;
  const int n = gathers[b];
  __shared__ float attn[128];
  __shared__ float red[128 * 8];
  __shared__ float smax, ssum;
  if (tid < 128) {
    int srow = isCtx ? b : n;
    attn[tid] = score_src[srow * 128 + tid] + (1.0f - mask[b * 128 + tid]) * (-10000.0f);
  }
  __syncthreads();
  if (tid < 64) {
    float m = fmaxf(attn[tid], attn[tid + 64]);
#pragma unroll
    for (int msk = 1; msk <= 32; msk <<= 1) m = fmaxf(m, __shfl_xor(m, msk, 64));
    if (tid == 0) smax = m;
  }
  __syncthreads();
  if (tid < 128) attn[tid] = __expf(attn[tid] - smax);
  __syncthreads();
  if (tid < 64) {
    float s = attn[tid] + attn[tid + 64];
#pragma unroll
    for (int msk = 1; msk <= 32; msk <<= 1) s += __shfl_xor(s, msk, 64);
    if (tid == 0) ssum = 1.0f / s;
  }
  __syncthreads();
  if (tid < 128) attn[tid] *= ssum;
  __syncthreads();
  const unsigned short* xb = Xb + (size_t)n * 128 * 1024;
  const int c = tid & 127, h = tid >> 7;
  float acc[8] = {};
  for (int s = h; s < 128; s += 2) {
    float w = attn[s];
    u16x8 v = *(const u16x8*)&xb[(size_t)s * 1024 + c * 8];
#pragma unroll
    for (int j = 0; j < 8; ++j) acc[j] += w * bf2f(v[j]);
  }
  if (h == 1) {
#pragma unroll
    for (int j = 0; j < 8; ++j) red[c * 8 + j] = acc[j];
  }
  __syncthreads();
  if (h == 0) {
    unsigned short o[8];
#pragma unroll
    for (int j = 0; j < 8; ++j) o[j] = f2bf(acc[j] + red[c * 8 + j]);
    *(uint4*)&finalrb[(size_t)b * 2048 + (isCtx ? 1024 : 0) + c * 8] = *(uint4*)o;
  }
}

// ---------------------------------------------------------------------------
// cb GEMM (bf16 in): cb[b,e] = men_repr[b,:1024] . Wcm[e,:]; grid 128
// ---------------------------------------------------------------------------
__global__ __launch_bounds__(256) void k_cb_gemm_b(
    const unsigned short* __restrict__ finalrb, const unsigned short* __restrict__ Wcmb,
    float* __restrict__ cb) {
  __shared__ __align__(16) unsigned short As[64 * 32];
  __shared__ __align__(16) unsigned short Bs[64 * 32];
  const int bid = blockIdx.x;
  const int rowBase = (bid >> 4) * 64, colBase = (bid & 15) * 64;
  const int tid = threadIdx.x, wave = tid >> 6, lane = tid & 63;
  const int lm = lane & 15, lq = lane >> 4;
  const int sr = tid >> 2, sc = (tid & 3) * 8;
  f32x4 acc[4] = {};
  for (int k0 = 0; k0 < 1024; k0 += 32) {
    __syncthreads();
    *(uint4*)&As[sr * 32 + sc] = *(const uint4*)&finalrb[(size_t)(rowBase + sr) * 2048 + k0 + sc];
    *(uint4*)&Bs[sr * 32 + sc] = *(const uint4*)&Wcmb[(size_t)(colBase + sr) * 1024 + k0 + sc];
    __syncthreads();
    bf16x8 af = *(const bf16x8*)&As[(wave * 16 + lm) * 32 + lq * 8];
#pragma unroll
    for (int j = 0; j < 4; ++j) {
      bf16x8 bfr = *(const bf16x8*)&Bs[(j * 16 + lm) * 32 + lq * 8];
      acc[j] = __builtin_amdgcn_mfma_f32_16x16x32_bf16(af, bfr, acc[j], 0, 0, 0);
    }
  }
#pragma unroll
  for (int j = 0; j < 4; ++j) {
    int col = colBase + j * 16 + lm;
#pragma unroll
    for (int r = 0; r < 4; ++r) {
      int row = rowBase + wave * 16 + lq * 4 + r;
      cb[row * 1024 + col] = acc[j][r];
    }
  }
}

// ---------------------------------------------------------------------------
// latent GEMM split-K: latf[b, 0:128] += finalrb . Wf2lb^T over K-chunk.
// grid 128 = 2 colTiles x 8 rowTiles x 8 K-chunks (vs 16 blocks before:
// latency-bound, 94% of CUs idle). latf must be pre-zeroed.
// ---------------------------------------------------------------------------
__global__ __launch_bounds__(256) void k_lat_split(
    const unsigned short* __restrict__ finalrb, const unsigned short* __restrict__ Wf2lb,
    float* __restrict__ latf) {
  __shared__ __align__(16) unsigned short As[64 * 32];
  __shared__ __align__(16) unsigned short Bs[64 * 32];
  const int bid = blockIdx.x;
  const int ks = bid & 7;
  const int rowBase = ((bid >> 3) & 7) * 64;
  const int colBase = (bid >> 6) * 64;
  const int tid = threadIdx.x, wave = tid >> 6, lane = tid & 63;
  const int lm = lane & 15, lq = lane >> 4;
  const int sr = tid >> 2, sc = (tid & 3) * 8;
  f32x4 acc[4] = {};
  const int kEnd = ks * 256 + 256;
  for (int k0 = ks * 256; k0 < kEnd; k0 += 32) {
    __syncthreads();
    *(uint4*)&As[sr * 32 + sc] = *(const uint4*)&finalrb[(size_t)(rowBase + sr) * 2048 + k0 + sc];
    *(uint4*)&Bs[sr * 32 + sc] = *(const uint4*)&Wf2lb[(size_t)(colBase + sr) * 2048 + k0 + sc];
    __syncthreads();
    bf16x8 af = *(const bf16x8*)&As[(wave * 16 + lm) * 32 + lq * 8];
#pragma unroll
    for (int j = 0; j < 4; ++j) {
      bf16x8 bfr = *(const bf16x8*)&Bs[(j * 16 + lm) * 32 + lq * 8];
      acc[j] = __builtin_amdgcn_mfma_f32_16x16x32_bf16(af, bfr, acc[j], 0, 0, 0);
    }
  }
#pragma unroll
  for (int j = 0; j < 4; ++j) {
    int col = colBase + j * 16 + lm;
#pragma unroll
    for (int r = 0; r < 4; ++r) {
      int row = rowBase + wave * 16 + lq * 4 + r;
      atomicAdd(&latf[row * LATPAD + col], acc[j][r]);
    }
  }
}

// ---------------------------------------------------------------------------
// output GEMM, fused W_out f32->bf16 staging (no pre-convert pass):
//   acc  = finalrb[128,2048] . W_out[128cols,2048]^T   (B stage8'd in-kernel)
//   acc2 = latb[128,128] . Wl2lb[128cols,128]^T
// XCD-grouped block map: xcd = bid&7; the 4 row-blocks sharing a B-panel run
// on the SAME XCD -> W_out panel read ~once into that L2 (vs 4x cross-XCD).
// grid 352 (8 xcd x 44); blocks with colTile>=81 exit early.
// ---------------------------------------------------------------------------
__global__ __launch_bounds__(256) void k_out_gemm_f(
    const unsigned short* __restrict__ finalrb, const float* __restrict__ Wout,
    const unsigned short* __restrict__ latb, const unsigned short* __restrict__ Wl2lb,
    const float* __restrict__ lscale, float* __restrict__ out,
    float* __restrict__ outLat) {
  __shared__ __align__(16) unsigned short As[2 * 128 * 32];
  __shared__ __align__(16) unsigned short Bs[2 * 128 * 32];
  const int bid = blockIdx.x;
  const int xcd = bid & 7, idx = bid >> 3;
  const int rowTile = idx & 3, colTile = xcd + 8 * (idx >> 2);
  if (colTile >= 81) return;
  const int colBase = colTile * 128;
  const int rowBase = rowTile * 128;
  const int tid = threadIdx.x, wave = tid >> 6, lane = tid & 63;
  const int lm = lane & 15, lq = lane >> 4;
  const int wr = (wave & 1) * 64, wc = (wave >> 1) * 64;
  const int srow = wave * 32 + (lane >> 2);
  const int scol = (lane & 3) * 8;
  const float scal = lscale[0];
  const unsigned short* aPtr = finalrb + (size_t)(rowBase + srow) * 2048 + scol;
  // B staging: thread covers W_out row (colBase + tid/2), k-half (tid&1)
  const int br = tid >> 1, bh = tid & 1;
  const int bRow = colBase + br;
  const bool bv = bRow < LL;
  const float* bsrc = Wout + (size_t)bRow * 2048 + bh * 32;
  unsigned short* bdst = &Bs[bh * 4096 + br * 32];
  f32x4 acc[4][4] = {};
  for (int k0 = 0; k0 < 2048; k0 += 64) {
    __syncthreads();
    // A: async DMA bf16 (layout [h][128][32], identical to proven kernel)
    gl_lds16(aPtr + k0, As + wave * 1024);
    gl_lds16(aPtr + k0 + 16 * 2048, As + wave * 1024 + 512);
    gl_lds16(aPtr + k0 + 32, As + 4096 + wave * 1024);
    gl_lds16(aPtr + k0 + 32 + 16 * 2048, As + 4096 + wave * 1024 + 512);
    // B: register-stage f32 -> bf16 (32 elems/thread)
    if (bv) {
      stage8(bdst, bsrc + k0);
      stage8(bdst + 8, bsrc + k0 + 8);
      stage8(bdst + 16, bsrc + k0 + 16);
      stage8(bdst + 24, bsrc + k0 + 24);
    } else {
      uint4 z = {0, 0, 0, 0};
      *(uint4*)bdst = z;
      *(uint4*)(bdst + 8) = z;
      *(uint4*)(bdst + 16) = z;
      *(uint4*)(bdst + 24) = z;
    }
    __syncthreads();
#pragma unroll
    for (int h = 0; h < 2; ++h) {
      bf16x8 af[4], bfr[4];
#pragma unroll
      for (int m = 0; m < 4; ++m)
        af[m] = *(const bf16x8*)&As[h * 4096 + (wr + m * 16 + lm) * 32 + lq * 8];
#pragma unroll
      for (int n = 0; n < 4; ++n)
        bfr[n] = *(const bf16x8*)&Bs[h * 4096 + (wc + n * 16 + lm) * 32 + lq * 8];
#pragma unroll
      for (int m = 0; m < 4; ++m)
#pragma unroll
        for (int n = 0; n < 4; ++n)
          acc[m][n] = __builtin_amdgcn_mfma_f32_16x16x32_bf16(af[m], bfr[n], acc[m][n], 0, 0, 0);
    }
  }
  // latent phase: K=128 (2 iters), separate accumulator; all-bf16 DMA
  const unsigned short* aPtr2 = latb + (size_t)(rowBase + srow) * LATPAD + scol;
  const unsigned short* bPtr2 = Wl2lb + (size_t)(colBase + srow) * LATPAD + scol;
  f32x4 acc2[4][4] = {};
  for (int k0 = 0; k0 < 128; k0 += 64) {
    __syncthreads();
#pragma unroll
    for (int h = 0; h < 2; ++h) {
      gl_lds16(aPtr2 + k0 + h * 32, As + h * 4096 + wave * 1024);
      gl_lds16(aPtr2 + k0 + h * 32 + 16 * LATPAD, As + h * 4096 + wave * 1024 + 512);
      gl_lds16(bPtr2 + k0 + h * 32, Bs + h * 4096 + wave * 1024);
      gl_lds16(bPtr2 + k0 + h * 32 + 16 * LATPAD, Bs + h * 4096 + wave * 1024 + 512);
    }
    __syncthreads();
#pragma unroll
    for (int h = 0; h < 2; ++h) {
      bf16x8 af[4], bfr[4];
#pragma unroll
      for (int m = 0; m < 4; ++m)
        af[m] = *(const bf16x8*)&As[h * 4096 + (wr + m * 16 + lm) * 32 + lq * 8];
#pragma unroll
      for (int n = 0; n < 4; ++n)
        bfr[n] = *(const bf16x8*)&Bs[h * 4096 + (wc + n * 16 + lm) * 32 + lq * 8];
#pragma unroll
      for (int m = 0; m < 4; ++m)
#pragma unroll
        for (int n = 0; n < 4; ++n)
          acc2[m][n] = __builtin_amdgcn_mfma_f32_16x16x32_bf16(af[m], bfr[n], acc2[m][n], 0, 0, 0);
    }
  }
#pragma unroll
  for (int m = 0; m < 4; ++m)
#pragma unroll
    for (int n = 0; n < 4; ++n) {
      int col = colBase + wc + n * 16 + lm;
      if (col < LL) {
#pragma unroll
        for (int r = 0; r < 4; ++r) {
          int row = rowBase + wr + m * 16 + lq * 4 + r;
          float lv = acc2[m][n][r];
          out[(size_t)row * LL + col] = acc[m][n][r] + scal * lv;
          outLat[(size_t)row * LL + col] = lv;
        }
      }
    }
}

// ======================= legacy fallback (round-3, proven) ==================
__global__ __launch_bounds__(256) void k_men_gemm(
    const float* __restrict__ X, const float* __restrict__ Wm,
    const float* __restrict__ wo, float* __restrict__ score) {
  __shared__ __align__(16) unsigned short As[64 * 32];
  __shared__ __align__(16) unsigned short Bs[64 * 32];
  const int bid = blockIdx.x;
  const int rowBase = (bid >> 4) * 64, colBase = (bid & 15) * 64;
  const int tid = threadIdx.x, wave = tid >> 6, lane = tid & 63;
  const int lm = lane & 15, lq = lane >> 4;
  const int sr = tid >> 2, sc = (tid & 3) * 8;
  f32x4 acc[4] = {};
  for (int k0 = 0; k0 < 1024; k0 += 32) {
    __syncthreads();
    stage8(&As[sr * 32 + sc], &X[(size_t)(rowBase + sr) * 1024 + k0 + sc]);
    stage8(&Bs[sr * 32 + sc], &Wm[(size_t)(colBase + sr) * 1024 + k0 + sc]);
    __syncthreads();
    bf16x8 af = *(const bf16x8*)&As[(wave * 16 + lm) * 32 + lq * 8];
#pragma unroll
    for (int j = 0; j < 4; ++j) {
      bf16x8 bfr = *(const bf16x8*)&Bs[(j * 16 + lm) * 32 + lq * 8];
      acc[j] = __builtin_amdgcn_mfma_f32_16x16x32_bf16(af, bfr, acc[j], 0, 0, 0);
    }
  }
  float rsum[4] = {0.f, 0.f, 0.f, 0.f};
#pragma unroll
  for (int j = 0; j < 4; ++j) {
    float w = wo[colBase + j * 16 + lm];
#pragma unroll
    for (int r = 0; r < 4; ++r) rsum[r] += tanhf(acc[j][r]) * w;
  }
#pragma unroll
  for (int m = 1; m <= 8; m <<= 1)
#pragma unroll
    for (int r = 0; r < 4; ++r) rsum[r] += __shfl_xor(rsum[r], m, 64);
  if (lm == 0) {
    int row0 = rowBase + wave * 16 + lq * 4;
#pragma unroll
    for (int r = 0; r < 4; ++r) atomicAdd(&score[row0 + r], rsum[r]);
  }
}

__global__ __launch_bounds__(256) void k_ctx_gemm(
    const float* __restrict__ X, const int* __restrict__ gathers,
    const float* __restrict__ Wc, const float* __restrict__ wd,
    const float* __restrict__ wo, const float* __restrict__ dist,
    const float* __restrict__ cb, float* __restrict__ score) {
  __shared__ __align__(16) unsigned short As[64 * 32];
  __shared__ __align__(16) unsigned short Bs[64 * 32];
  const int bid = blockIdx.x;
  const int rowBase = (bid >> 4) * 64, colBase = (bid & 15) * 64;
  const int tid = threadIdx.x, wave = tid >> 6, lane = tid & 63;
  const int lm = lane & 15, lq = lane >> 4;
  const int sr = tid >> 2, sc = (tid & 3) * 8;
  const int row_g = rowBase + sr;
  const int srcRow = (gathers[row_g >> 7] << 7) + (row_g & 127);
  f32x4 acc[4] = {};
  for (int k0 = 0; k0 < 1024; k0 += 32) {
    __syncthreads();
    stage8(&As[sr * 32 + sc], &X[(size_t)srcRow * 1024 + k0 + sc]);
    stage8(&Bs[sr * 32 + sc], &Wc[(size_t)(colBase + sr) * 1024 + k0 + sc]);
    __syncthreads();
    bf16x8 af = *(const bf16x8*)&As[(wave * 16 + lm) * 32 + lq * 8];
#pragma unroll
    for (int j = 0; j < 4; ++j) {
      bf16x8 bfr = *(const bf16x8*)&Bs[(j * 16 + lm) * 32 + lq * 8];
      acc[j] = __builtin_amdgcn_mfma_f32_16x16x32_bf16(af, bfr, acc[j], 0, 0, 0);
    }
  }
  float rsum[4] = {0.f, 0.f, 0.f, 0.f};
#pragma unroll
  for (int j = 0; j < 4; ++j) {
    int col = colBase + j * 16 + lm;
    float w = wo[col];
    float wdv = wd[col];
#pragma unroll
    for (int r = 0; r < 4; ++r) {
      int rg = rowBase + wave * 16 + lq * 4 + r;
      int b = rg >> 7, s = rg & 127;
      float v = acc[j][r] + cb[b * 1024 + col] + dist[b * 128 + s] * wdv;
      rsum[r] += tanhf(v) * w;
    }
  }
#pragma unroll
  for (int m = 1; m <= 8; m <<= 1)
#pragma unroll
    for (int r = 0; r < 4; ++r) rsum[r] += __shfl_xor(rsum[r], m, 64);
  if (lm == 0) {
    int row0 = rowBase + wave * 16 + lq * 4;
#pragma unroll
    for (int r = 0; r < 4; ++r) atomicAdd(&score[row0 + r], rsum[r]);
  }
}

__global__ __launch_bounds__(256) void k_soft(
    const float* __restrict__ score_src, const float* __restrict__ mask,
    const float* __restrict__ X, const int* __restrict__ gathers,
    float* __restrict__ finalr, int isCtx) {
  const int b = blockIdx.x, tid = threadIdx.x;
  const int n = gathers[b];
  __shared__ float attn[128];
  __shared__ float smax, ssum;
  if (tid < 128) {
    int srow = isCtx ? b : n;
    attn[tid] = score_src[srow * 128 + tid] + (1.0f - mask[b * 128 + tid]) * (-10000.0f);
  }
  __syncthreads();
  if (tid == 0) {
    float m = attn[0];
    for (int i = 1; i < 128; ++i) m = fmaxf(m, attn[i]);
    smax = m;
  }
  __syncthreads();
  if (tid < 128) attn[tid] = expf(attn[tid] - smax);
  __syncthreads();
  if (tid == 0) {
    float s = 0.f;
    for (int i = 0; i < 128; ++i) s += attn[i];
    ssum = 1.0f / s;
  }
  __syncthreads();
  if (tid < 128) attn[tid] *= ssum;
  __syncthreads();
  const float* xb = &X[(size_t)(n << 7) * 1024];
  const int off = isCtx ? 1024 : 0;
  for (int d = tid; d < 1024; d += 256) {
    float a = 0.f;
#pragma unroll 8
    for (int s = 0; s < 128; ++s) a += attn[s] * xb[s * 1024 + d];
    finalr[b * 2048 + off + d] = a;
  }
}

__global__ __launch_bounds__(256) void k_cb_gemm(
    const float* __restrict__ finalr, const float* __restrict__ Wcm,
    float* __restrict__ cb) {
  __shared__ __align__(16) unsigned short As[64 * 32];
  __shared__ __align__(16) unsigned short Bs[64 * 32];
  const int bid = blockIdx.x;
  const int rowBase = (bid >> 4) * 64, colBase = (bid & 15) * 64;
  const int tid = threadIdx.x, wave = tid >> 6, lane = tid & 63;
  const int lm = lane & 15, lq = lane >> 4;
  const int sr = tid >> 2, sc = (tid & 3) * 8;
  f32x4 acc[4] = {};
  for (int k0 = 0; k0 < 1024; k0 += 32) {
    __syncthreads();
    stage8(&As[sr * 32 + sc], &finalr[(size_t)(rowBase + sr) * 2048 + k0 + sc]);
    stage8(&Bs[sr * 32 + sc], &Wcm[(size_t)(colBase + sr) * 1024 + k0 + sc]);
    __syncthreads();
    bf16x8 af = *(const bf16x8*)&As[(wave * 16 + lm) * 32 + lq * 8];
#pragma unroll
    for (int j = 0; j < 4; ++j) {
      bf16x8 bfr = *(const bf16x8*)&Bs[(j * 16 + lm) * 32 + lq * 8];
      acc[j] = __builtin_amdgcn_mfma_f32_16x16x32_bf16(af, bfr, acc[j], 0, 0, 0);
    }
  }
#pragma unroll
  for (int j = 0; j < 4; ++j) {
    int col = colBase + j * 16 + lm;
#pragma unroll
    for (int r = 0; r < 4; ++r) {
      int row = rowBase + wave * 16 + lq * 4 + r;
      cb[row * 1024 + col] = acc[j][r];
    }
  }
}

__global__ __launch_bounds__(256) void k_lat_gemm(
    const float* __restrict__ finalr, const float* __restrict__ Wf2l,
    float* __restrict__ lat) {
  __shared__ __align__(16) unsigned short As[64 * 32];
  __shared__ __align__(16) unsigned short Bs[64 * 32];
  const int rowBase = blockIdx.y * 64, colBase = blockIdx.x * 64;
  const int tid = threadIdx.x, wave = tid >> 6, lane = tid & 63;
  const int lm = lane & 15, lq = lane >> 4;
  const int sr = tid >> 2, sc = (tid & 3) * 8;
  f32x4 acc[4] = {};
  for (int k0 = 0; k0 < 2048; k0 += 32) {
    __syncthreads();
    stage8(&As[sr * 32 + sc], &finalr[(size_t)(rowBase + sr) * 2048 + k0 + sc]);
    int l = colBase + sr;
    if (l < LATENT) {
      stage8(&Bs[sr * 32 + sc], &Wf2l[(size_t)l * 2048 + k0 + sc]);
    } else {
      uint4 z = {0, 0, 0, 0};
      *(uint4*)&Bs[sr * 32 + sc] = z;
    }
    __syncthreads();
    bf16x8 af = *(const bf16x8*)&As[(wave * 16 + lm) * 32 + lq * 8];
#pragma unroll
    for (int j = 0; j < 4; ++j) {
      bf16x8 bfr = *(const bf16x8*)&Bs[(j * 16 + lm) * 32 + lq * 8];
      acc[j] = __builtin_amdgcn_mfma_f32_16x16x32_bf16(af, bfr, acc[j], 0, 0, 0);
    }
  }
#pragma unroll
  for (int j = 0; j < 4; ++j) {
    int col = colBase + j * 16 + lm;
    if (col < LATENT) {
#pragma unroll
      for (int r = 0; r < 4; ++r) {
        int row = rowBase + wave * 16 + lq * 4 + r;
        lat[row * LATENT + col] = acc[j][r];
      }
    }
  }
}

__global__ __launch_bounds__(256) void k_out_gemm(
    const float* __restrict__ finalr, const float* __restrict__ Wout,
    const float* __restrict__ lat, const float* __restrict__ Wl2l,
    const float* __restrict__ lscale, float* __restrict__ out,
    float* __restrict__ outLat) {
  __shared__ __align__(16) unsigned short As[64 * 32];
  __shared__ __align__(16) unsigned short Bs[64 * 32];
  const int rowBase = blockIdx.y * 64, colBase = blockIdx.x * 64;
  const int tid = threadIdx.x, wave = tid >> 6, lane = tid & 63;
  const int lm = lane & 15, lq = lane >> 4;
  const int sr = tid >> 2, sc = (tid & 3) * 8;
  const float scal = lscale[0];
  const int lrow = colBase + sr;
  const bool lvalid = (lrow < LL);
  f32x4 acc[4] = {};
  for (int k0 = 0; k0 < 2048; k0 += 32) {
    __syncthreads();
    stage8(&As[sr * 32 + sc], &finalr[(size_t)(rowBase + sr) * 2048 + k0 + sc]);
    if (lvalid) {
      stage8(&Bs[sr * 32 + sc], &Wout[(size_t)lrow * 2048 + k0 + sc]);
    } else {
      uint4 z = {0, 0, 0, 0};
      *(uint4*)&Bs[sr * 32 + sc] = z;
    }
    __syncthreads();
    bf16x8 af = *(const bf16x8*)&As[(wave * 16 + lm) * 32 + lq * 8];
#pragma unroll
    for (int j = 0; j < 4; ++j) {
      bf16x8 bfr = *(const bf16x8*)&Bs[(j * 16 + lm) * 32 + lq * 8];
      acc[j] = __builtin_amdgcn_mfma_f32_16x16x32_bf16(af, bfr, acc[j], 0, 0, 0);
    }
  }
  f32x4 acc2[4] = {};
  for (int k2 = 0; k2 < 128; k2 += 32) {
    __syncthreads();
    const int brow = rowBase + sr;
#pragma unroll
    for (int jj = 0; jj < 8; ++jj) {
      int idx = k2 + sc + jj;
      As[sr * 32 + sc + jj] = (idx < LATENT) ? f2bf(lat[brow * LATENT + idx]) : (unsigned short)0;
      Bs[sr * 32 + sc + jj] = (lvalid && idx < LATENT) ? f2bf(Wl2l[lrow * LATENT + idx]) : (unsigned short)0;
    }
    __syncthreads();
    bf16x8 af = *(const bf16x8*)&As[(wave * 16 + lm) * 32 + lq * 8];
#pragma unroll
    for (int j = 0; j < 4; ++j) {
      bf16x8 bfr = *(const bf16x8*)&Bs[(j * 16 + lm) * 32 + lq * 8];
      acc2[j] = __builtin_amdgcn_mfma_f32_16x16x32_bf16(af, bfr, acc2[j], 0, 0, 0);
    }
  }
#pragma unroll
  for (int j = 0; j < 4; ++j) {
    int col = colBase + j * 16 + lm;
    if (col < LL) {
#pragma unroll
      for (int r = 0; r < 4; ++r) {
        int row = rowBase + wave * 16 + lq * 4 + r;
        float lv = acc2[j][r];
        out[(size_t)row * LL + col] = acc[j][r] + scal * lv;
        outLat[(size_t)row * LL + col] = lv;
      }
    }
  }
}

extern "C" void kernel_launch(void* const* d_in, const int* in_sizes, int n_in,
                              void* d_out, int out_size, void* d_ws, size_t ws_size,
                              hipStream_t stream) {
  const float* X = (const float*)d_in[0];
  const float* men_mask = (const float*)d_in[1];
  const float* ctx_mask = (const float*)d_in[2];
  const float* dist = (const float*)d_in[3];
  const int* gathers = (const int*)d_in[4];
  const float* W_men_m = (const float*)d_in[5];
  const float* W_men_o = (const float*)d_in[6];
  const float* W_ctx_c = (const float*)d_in[7];
  const float* W_ctx_m = (const float*)d_in[8];
  const float* w_ctx_d = (const float*)d_in[9];
  const float* W_ctx_o = (const float*)d_in[10];
  const float* W_out = (const float*)d_in[11];
  const float* W_f2l = (const float*)d_in[12];
  const float* W_l2l = (const float*)d_in[13];
  const float* lscale = (const float*)d_in[14];
  float* out = (float*)d_out;
  float* outLat = out + (size_t)BB * LL;

  size_t off = 0;
  auto carve = [&](size_t bytes) {
    void* p = (char*)d_ws + off;
    off = (off + bytes + 255) & ~(size_t)255;
    return p;
  };
  float* sent_score = (float*)carve(32768 * 4);
  float* ctx_score = (float*)carve(65536 * 4);
  float* finalr = (float*)carve((size_t)512 * 2048 * 4);        // legacy only
  float* cb = (float*)carve((size_t)512 * 1024 * 4);
  float* lat = (float*)carve((size_t)512 * LATENT * 4);         // legacy only
  unsigned short* Xb = (unsigned short*)carve((size_t)32768 * 1024 * 2);
  unsigned short* Wmb = (unsigned short*)carve((size_t)1024 * 1024 * 2);
  unsigned short* Wcb = (unsigned short*)carve((size_t)1024 * 1024 * 2);
  unsigned short* Wcmb = (unsigned short*)carve((size_t)1024 * 1024 * 2);
  unsigned short* Hc = (unsigned short*)carve((size_t)32768 * 1024 * 2);
  unsigned short* Wf2lb = (unsigned short*)carve((size_t)LATPAD * 2048 * 2);
  unsigned short* Wl2lb = (unsigned short*)carve((size_t)LPAD * LATPAD * 2);
  unsigned short* finalrb = (unsigned short*)carve((size_t)512 * 2048 * 2);
  unsigned short* latb = (unsigned short*)carve((size_t)512 * LATPAD * 2);
  float* latf = (float*)carve((size_t)512 * LATPAD * 4);
  const bool fits = off <= ws_size;

  if (fits) {
    hipMemsetAsync(sent_score, 0, 32768 * sizeof(float), stream);
    hipMemsetAsync(latf, 0, (size_t)512 * LATPAD * sizeof(float), stream);
    k_cvt<<<8192, 256, 0, stream>>>(X, Xb, 32768 * 1024 / 4);
    k_cvt<<<1024, 256, 0, stream>>>(W_men_m, Wmb, 1024 * 1024 / 4);
    k_cvt<<<1024, 256, 0, stream>>>(W_ctx_c, Wcb, 1024 * 1024 / 4);
    k_cvt<<<1024, 256, 0, stream>>>(W_ctx_m, Wcmb, 1024 * 1024 / 4);
    k_cvt_pad<<<512, 256, 0, stream>>>(W_f2l, Wf2lb, LATENT, 2048, 2048, LATPAD * 2048);
    k_cvt_pad<<<1024, 256, 0, stream>>>(W_l2l, Wl2lb, LL, LATENT, LATPAD, LPAD * LATPAD);
    k_mc_gemm8<<<256, 512, 0, stream>>>(Xb, Wmb, Wcb, W_men_o, sent_score, Hc);
    k_softb<<<512, 256, 0, stream>>>(sent_score, men_mask, Xb, gathers, finalrb, 0);
    k_cb_gemm_b<<<128, 256, 0, stream>>>(finalrb, Wcmb, cb);
    k_ctx_score<<<512, 256, 0, stream>>>(Hc, gathers, cb, w_ctx_d, W_ctx_o, dist, ctx_score);
    k_softb<<<512, 256, 0, stream>>>(ctx_score, ctx_mask, Xb, gathers, finalrb, 1);
    k_lat_split<<<128, 256, 0, stream>>>(finalrb, Wf2lb, latf);
    k_cvt<<<64, 256, 0, stream>>>(latf, latb, 512 * LATPAD / 4);
    k_out_gemm_f<<<352, 256, 0, stream>>>(finalrb, W_out, latb, Wl2lb,
                                          lscale, out, outLat);
  } else {
    hipMemsetAsync(d_ws, 0, (32768 + 65536) * sizeof(float), stream);
    k_men_gemm<<<8192, 256, 0, stream>>>(X, W_men_m, W_men_o, sent_score);
    k_soft<<<512, 256, 0, stream>>>(sent_score, men_mask, X, gathers, finalr, 0);
    k_cb_gemm<<<128, 256, 0, stream>>>(finalr, W_ctx_m, cb);
    k_ctx_gemm<<<16384, 256, 0, stream>>>(X, gathers, W_ctx_c, w_ctx_d, W_ctx_o, dist, cb, ctx_score);
    k_soft<<<512, 256, 0, stream>>>(ctx_score, ctx_mask, X, gathers, finalr, 1);
    k_lat_gemm<<<dim3(2, 8), 256, 0, stream>>>(finalr, W_f2l, lat);
    k_out_gemm<<<dim3(162, 8), 256, 0, stream>>>(finalr, W_out, lat, W_l2l, lscale, out, outLat);
  }
}

// Round 4
// 652.356 us; speedup vs baseline: 1.1357x; 1.0078x over previous
//
#include <hip/hip_runtime.h>
#include <hip/hip_bf16.h>

typedef __bf16 bf16x8 __attribute__((ext_vector_type(8)));
typedef float f32x4 __attribute__((ext_vector_type(4)));
typedef unsigned short u16x8 __attribute__((ext_vector_type(8)));

#define DEV __device__ __forceinline__

static constexpr int N_SENTC = 256, BB = 512, SS = 128, DD = 1024;
static constexpr int LL = 10331, LATENT = 101;
static constexpr int LPAD = 10368;  // 162*64 = 81*128, row-padded L
static constexpr int LATPAD = 128;  // padded latent

DEV float bf2f(unsigned short u) {
  unsigned v = (unsigned)u << 16;
  return __builtin_bit_cast(float, v);
}
DEV unsigned short f2bf(float f) {
  unsigned u = __builtin_bit_cast(unsigned, f);
  unsigned lsb = (u >> 16) & 1u;
  u += 0x7fffu + lsb;
  return (unsigned short)(u >> 16);
}

// fast tanh: 1 - 2/(e^2x + 1); |err| ~1e-7 rel, saturates correctly at +-inf
DEV float fast_tanh(float x) {
  float e = __expf(2.0f * x);
  return 1.0f - 2.0f / (e + 1.0f);
}

DEV void stage8(unsigned short* dst, const float* src) {
  float4 a = *(const float4*)src;
  float4 b = *(const float4*)(src + 4);
  unsigned short t[8];
  t[0] = f2bf(a.x); t[1] = f2bf(a.y); t[2] = f2bf(a.z); t[3] = f2bf(a.w);
  t[4] = f2bf(b.x); t[5] = f2bf(b.y); t[6] = f2bf(b.z); t[7] = f2bf(b.w);
  *(uint4*)dst = *(uint4*)t;
}

// async global->LDS, 16B per lane; lds base wave-uniform (HW adds lane*16)
DEV void gl_lds16(const unsigned short* g, unsigned short* l) {
  __builtin_amdgcn_global_load_lds(
      (const __attribute__((address_space(1))) unsigned int*)g,
      (__attribute__((address_space(3))) unsigned int*)l, 16, 0, 0);
}

// ---------------------------------------------------------------------------
// f32 -> bf16 bulk convert (n4 = count/4)
// ---------------------------------------------------------------------------
__global__ __launch_bounds__(256) void k_cvt(
    const float* __restrict__ src, unsigned short* __restrict__ dst, int n4) {
  for (int i = blockIdx.x * 256 + threadIdx.x; i < n4; i += gridDim.x * 256) {
    float4 v = ((const float4*)src)[i];
    unsigned short t[4] = {f2bf(v.x), f2bf(v.y), f2bf(v.z), f2bf(v.w)};
    ((uint2*)dst)[i] = *(const uint2*)t;
  }
}

// ---------------------------------------------------------------------------
// All weight conversions in ONE launch (was 5 launches):
//   seg A: Wm/Wc/Wcm 1024x1024 elementwise (vec4)
//   seg B: Wf2l [101,2048] -> [128,2048] zero-pad (vec4, row-uniform)
//   seg C: Wl2l [10331,101] -> [10368,128] zero-pad (vec4, per-elem guard)
// ---------------------------------------------------------------------------
__global__ __launch_bounds__(256) void k_cvt_all(
    const float* __restrict__ Wm, const float* __restrict__ Wc,
    const float* __restrict__ Wcm, const float* __restrict__ Wf2l,
    const float* __restrict__ Wl2l,
    unsigned short* __restrict__ Wmb, unsigned short* __restrict__ Wcb,
    unsigned short* __restrict__ Wcmb, unsigned short* __restrict__ Wf2lb,
    unsigned short* __restrict__ Wl2lb) {
  const int NA = 3 * 262144;   // vec4 units, 3 square mats
  const int NB = 65536;        // vec4 units, [128][2048]
  const int NC = 331776;       // vec4 units, [10368][128]
  for (int u = blockIdx.x * 256 + threadIdx.x; u < NA + NB + NC; u += gridDim.x * 256) {
    if (u < NA) {
      int which = u >> 18, off = u & 262143;
      const float* s = which == 0 ? Wm : (which == 1 ? Wc : Wcm);
      unsigned short* d = which == 0 ? Wmb : (which == 1 ? Wcb : Wcmb);
      float4 v = ((const float4*)s)[off];
      unsigned short t[4] = {f2bf(v.x), f2bf(v.y), f2bf(v.z), f2bf(v.w)};
      ((uint2*)d)[off] = *(const uint2*)t;
    } else if (u < NA + NB) {
      int off = u - NA;
      int r = off >> 9;  // (off*4)/2048
      if (r < LATENT) {
        float4 v = ((const float4*)Wf2l)[off];
        unsigned short t[4] = {f2bf(v.x), f2bf(v.y), f2bf(v.z), f2bf(v.w)};
        ((uint2*)Wf2lb)[off] = *(const uint2*)t;
      } else {
        ((uint2*)Wf2lb)[off] = make_uint2(0, 0);
      }
    } else {
      int off = u - NA - NB;
      int idx = off * 4;
      int r = idx >> 7, c0 = idx & 127;
      unsigned short t[4];
#pragma unroll
      for (int j = 0; j < 4; ++j) {
        int c = c0 + j;
        t[j] = (r < LL && c < LATENT) ? f2bf(Wl2l[(size_t)r * LATENT + c])
                                      : (unsigned short)0;
      }
      ((uint2*)Wl2lb)[off] = *(const uint2*)t;
    }
  }
}

// ---------------------------------------------------------------------------
// Fused men-score + ctx-hidden GEMM, 256x256-tile 8-phase schedule,
// PERSISTENT blocks (grid 256, 4 tiles each; colTile constant per block so
// the 512KB B-slice stays L2-hot) + fragment-register double-buffering
// (af0 phases 1-2, af1 phases 3-4). Proven correct; 167-198us run-to-run.
// FROZEN this round (r3 regression was codegen/clock variance, not source).
// ---------------------------------------------------------------------------
__global__ __launch_bounds__(512) void k_mc_gemm8(
    const unsigned short* __restrict__ Xb, const unsigned short* __restrict__ Wmb,
    const unsigned short* __restrict__ Wcb, const float* __restrict__ wo,
    float* __restrict__ score, unsigned short* __restrict__ Hc) {
  __shared__ __align__(16) unsigned short lds[2][2][2][8192];
  const int p = blockIdx.x;  // 256 persistent blocks
  const int tid = threadIdx.x, w = tid >> 6, lane = tid & 63;
  const int lm = lane & 15, lq = lane >> 4;
  const int wr = w >> 2, wc = w & 3;
  const int stRow = w * 16 + (lane >> 2);
  const int stCol = ((lane & 3) * 8) ^ ((lane >> 5) << 4);
  const int rdCol = (lq * 16) ^ ((lane & 8) ? 32 : 0);
  const int aoff = (wr * 16 + lm) * 64 + rdCol;
  const int boff = (wc * 16 + lm) * 64 + rdCol;

  const unsigned short* aSrc;
  const unsigned short* bSrc;
  int rowBase, bcolBase;
  bool isMen;
  auto setTile = [&](int t) {
    const int vbid = p + 256 * t;
    const int lbid = (vbid & 7) * 128 + (vbid >> 3);  // bijective XCD swizzle
    const int colTile = lbid & 7, rowTile = lbid >> 3;
    rowBase = rowTile * 256;
    isMen = colTile < 4;
    bcolBase = (colTile & 3) * 256;
    aSrc = Xb + (size_t)(rowBase + stRow) * 1024 + stCol;
    bSrc = (isMen ? Wmb : Wcb) + (size_t)(bcolBase + stRow) * 1024 + stCol;
  };

  auto ST = [&](int op, int h, int kt, int buf) {
    const unsigned short* s = (op ? bSrc : aSrc) + (size_t)h * 131072 + kt * 64;
    unsigned short* d = &lds[buf][op][h][w * 512];
    gl_lds16(s, d);
    gl_lds16(s + 32, d + 4096);
  };
  auto PRO = [&]() {
    ST(0, 0, 0, 0); ST(1, 0, 0, 0); ST(0, 1, 0, 0); ST(1, 1, 0, 0);
    ST(0, 0, 1, 1); ST(1, 0, 1, 1); ST(0, 1, 1, 1);
  };

  setTile(0);
  PRO();

  for (int t = 0; t < 4; ++t) {
    asm volatile("s_waitcnt vmcnt(6)" ::: "memory");
    __builtin_amdgcn_s_barrier();

    f32x4 acc[8][4] = {};
    bf16x8 af0[4][2], af1[4][2], bfr[4][2];
    for (int kt = 0; kt < 16; ++kt) {
      const int buf = kt & 1;
      const char* A0 = (const char*)&lds[buf][0][0][0];
      const char* A1 = (const char*)&lds[buf][0][1][0];
      const char* B0 = (const char*)&lds[buf][1][0][0];
      const char* B1 = (const char*)&lds[buf][1][1][0];
      // ---- phase 1: Q(0,0)
#pragma unroll
      for (int m = 0; m < 4; ++m)
#pragma unroll
        for (int ks = 0; ks < 2; ++ks)
          af0[m][ks] = *(const bf16x8*)(A0 + aoff + m * 2048 + ks * 8192);
#pragma unroll
      for (int n = 0; n < 2; ++n)
#pragma unroll
        for (int ks = 0; ks < 2; ++ks)
          bfr[n][ks] = *(const bf16x8*)(B0 + boff + n * 4096 + ks * 8192);
      if (kt + 1 < 16) ST(1, 1, kt + 1, buf ^ 1);
      __builtin_amdgcn_s_barrier();
      __builtin_amdgcn_s_setprio(1);
#pragma unroll
      for (int m = 0; m < 4; ++m)
#pragma unroll
        for (int n = 0; n < 2; ++n)
#pragma unroll
          for (int ks = 0; ks < 2; ++ks)
            acc[m][n] = __builtin_amdgcn_mfma_f32_16x16x32_bf16(af0[m][ks], bfr[n][ks], acc[m][n], 0, 0, 0);
      __builtin_amdgcn_s_setprio(0);
      __builtin_amdgcn_s_barrier();
      // ---- phase 2: Q(0,1)
#pragma unroll
      for (int n = 0; n < 2; ++n)
#pragma unroll
        for (int ks = 0; ks < 2; ++ks)
          bfr[2 + n][ks] = *(const bf16x8*)(B1 + boff + n * 4096 + ks * 8192);
      if (kt + 2 < 16) ST(0, 0, kt + 2, buf);
      __builtin_amdgcn_s_barrier();
      __builtin_amdgcn_s_setprio(1);
#pragma unroll
      for (int m = 0; m < 4; ++m)
#pragma unroll
        for (int n = 0; n < 2; ++n)
#pragma unroll
          for (int ks = 0; ks < 2; ++ks)
            acc[m][2 + n] = __builtin_amdgcn_mfma_f32_16x16x32_bf16(af0[m][ks], bfr[2 + n][ks], acc[m][2 + n], 0, 0, 0);
      __builtin_amdgcn_s_setprio(0);
      __builtin_amdgcn_s_barrier();
      // ---- phase 3: Q(1,0)
#pragma unroll
      for (int m = 0; m < 4; ++m)
#pragma unroll
        for (int ks = 0; ks < 2; ++ks)
          af1[m][ks] = *(const bf16x8*)(A1 + aoff + m * 2048 + ks * 8192);
      if (kt + 2 < 16) ST(1, 0, kt + 2, buf);
      __builtin_amdgcn_s_barrier();
      __builtin_amdgcn_s_setprio(1);
#pragma unroll
      for (int m = 0; m < 4; ++m)
#pragma unroll
        for (int n = 0; n < 2; ++n)
#pragma unroll
          for (int ks = 0; ks < 2; ++ks)
            acc[4 + m][n] = __builtin_amdgcn_mfma_f32_16x16x32_bf16(af1[m][ks], bfr[n][ks], acc[4 + m][n], 0, 0, 0);
      __builtin_amdgcn_s_setprio(0);
      __builtin_amdgcn_s_barrier();
      // ---- phase 4: Q(1,1)
      if (kt + 2 < 16) ST(0, 1, kt + 2, buf);
      __builtin_amdgcn_s_barrier();
      __builtin_amdgcn_s_setprio(1);
#pragma unroll
      for (int m = 0; m < 4; ++m)
#pragma unroll
        for (int n = 0; n < 2; ++n)
#pragma unroll
          for (int ks = 0; ks < 2; ++ks)
            acc[4 + m][2 + n] = __builtin_amdgcn_mfma_f32_16x16x32_bf16(af1[m][ks], bfr[2 + n][ks], acc[4 + m][2 + n], 0, 0, 0);
      __builtin_amdgcn_s_setprio(0);
      if (kt < 14) {
        asm volatile("s_waitcnt vmcnt(6)" ::: "memory");
      } else {
        asm volatile("s_waitcnt vmcnt(0)" ::: "memory");
      }
      __builtin_amdgcn_s_barrier();
    }

    // -------- epilogue --------
    if (isMen) {
      float wov[4];
#pragma unroll
      for (int n = 0; n < 4; ++n) wov[n] = wo[bcolBase + n * 64 + wc * 16 + lm];
      float rsum[8][4];
#pragma unroll
      for (int m = 0; m < 8; ++m)
#pragma unroll
        for (int r = 0; r < 4; ++r) {
          float s = 0.f;
#pragma unroll
          for (int n = 0; n < 4; ++n) s += fast_tanh(acc[m][n][r]) * wov[n];
          rsum[m][r] = s;
        }
#pragma unroll
      for (int msk = 1; msk <= 8; msk <<= 1)
#pragma unroll
        for (int m = 0; m < 8; ++m)
#pragma unroll
          for (int r = 0; r < 4; ++r) rsum[m][r] += __shfl_xor(rsum[m][r], msk, 64);
      if (lm == 0) {
#pragma unroll
        for (int m = 0; m < 8; ++m)
#pragma unroll
          for (int r = 0; r < 4; ++r)
            atomicAdd(&score[rowBase + m * 32 + wr * 16 + lq * 4 + r], rsum[m][r]);
      }
    } else {
      const int cb0 = bcolBase + wc * 16 + lm;
#pragma unroll
      for (int m = 0; m < 8; ++m) {
        const int row = rowBase + m * 32 + wr * 16 + lq * 4;
#pragma unroll
        for (int n = 0; n < 4; ++n) {
          const int col = cb0 + n * 64;
#pragma unroll
          for (int r = 0; r < 4; ++r)
            Hc[(size_t)(row + r) * 1024 + col] = f2bf(acc[m][n][r]);
        }
      }
    }
    if (t < 3) {
      setTile(t + 1);
      PRO();
    }
  }
}

// ---------------------------------------------------------------------------
// FUSED ctx score + softmax + weighted sum (was k_ctx_score + k_softb(1)):
// block b: scores from Hc[n] (wave per s), masked softmax in LDS, then
// attn-weighted sum over Xb[n] -> ctx half of finalrb. grid 512.
// ---------------------------------------------------------------------------
__global__ __launch_bounds__(256) void k_ctx_fused(
    const unsigned short* __restrict__ Hc, const int* __restrict__ gathers,
    const float* __restrict__ cb, const float* __restrict__ wd,
    const float* __restrict__ wo, const float* __restrict__ dist,
    const float* __restrict__ mask, const unsigned short* __restrict__ Xb,
    unsigned short* __restrict__ finalrb) {
  const int b = blockIdx.x, tid = threadIdx.x, wave = tid >> 6, lane = tid & 63;
  const int n = gathers[b];
  __shared__ float cbl[1024], wdl[1024], wol[1024];
  __shared__ float attn[128];
  __shared__ float red[128 * 8];
  __shared__ float smax, ssum;
  for (int i = tid; i < 1024; i += 256) {
    cbl[i] = cb[b * 1024 + i];
    wdl[i] = wd[i];
    wol[i] = wo[i];
  }
  __syncthreads();
  for (int s = wave; s < 128; s += 4) {
    float d = dist[b * 128 + s];
    const unsigned short* hrow = &Hc[(size_t)(n * 128 + s) * 1024 + lane * 16];
    unsigned short hs[16];
    *(uint4*)hs = *(const uint4*)hrow;
    *(uint4*)(hs + 8) = *(const uint4*)(hrow + 8);
    float p = 0.f;
#pragma unroll
    for (int j = 0; j < 16; ++j) {
      int e = lane * 16 + j;
      p += fast_tanh(bf2f(hs[j]) + cbl[e] + d * wdl[e]) * wol[e];
    }
#pragma unroll
    for (int msk = 1; msk <= 32; msk <<= 1) p += __shfl_xor(p, msk, 64);
    if (lane == 0) attn[s] = p + (1.0f - mask[b * 128 + s]) * (-10000.0f);
  }
  __syncthreads();
  if (tid < 64) {
    float m = fmaxf(attn[tid], attn[tid + 64]);
#pragma unroll
    for (int msk = 1; msk <= 32; msk <<= 1) m = fmaxf(m, __shfl_xor(m, msk, 64));
    if (tid == 0) smax = m;
  }
  __syncthreads();
  if (tid < 128) attn[tid] = __expf(attn[tid] - smax);
  __syncthreads();
  if (tid < 64) {
    float s = attn[tid] + attn[tid + 64];
#pragma unroll
    for (int msk = 1; msk <= 32; msk <<= 1) s += __shfl_xor(s, msk, 64);
    if (tid == 0) ssum = 1.0f / s;
  }
  __syncthreads();
  if (tid < 128) attn[tid] *= ssum;
  __syncthreads();
  const unsigned short* xb = Xb + (size_t)n * 128 * 1024;
  const int c = tid & 127, h = tid >> 7;
  float acc[8] = {};
  for (int s = h; s < 128; s += 2) {
    float w = attn[s];
    u16x8 v = *(const u16x8*)&xb[(size_t)s * 1024 + c * 8];
#pragma unroll
    for (int j = 0; j < 8; ++j) acc[j] += w * bf2f(v[j]);
  }
  if (h == 1) {
#pragma unroll
    for (int j = 0; j < 8; ++j) red[c * 8 + j] = acc[j];
  }
  __syncthreads();
  if (h == 0) {
    unsigned short o[8];
#pragma unroll
    for (int j = 0; j < 8; ++j) o[j] = f2bf(acc[j] + red[c * 8 + j]);
    *(uint4*)&finalrb[(size_t)b * 2048 + 1024 + c * 8] = *(uint4*)o;
  }
}

// ---------------------------------------------------------------------------
// softmax over S=128 (wave-parallel reduce) + weighted sum -> bf16 repr half
// (men path only now)
// ---------------------------------------------------------------------------
__global__ __launch_bounds__(256) void k_softb(
    const float* __restrict__ score_src, const float* __restrict__ mask,
    const unsigned short* __restrict__ Xb, const int* __restrict__ gathers,
    unsigned short* __restrict__ finalrb, int isCtx) {
  const int b = blockIdx.x, tid = threadIdx.x;
  const int n = gathers[b];
  __shared__ float attn[128];
  __shared__ float red[128 * 8];
  __shared__ float smax, ssum;
  if (tid < 128) {
    int srow = isCtx ? b : n;
    attn[tid] = score_src[srow * 128 + tid] + (1.0f - mask[b * 128 + tid]) * (-10000.0f);
  }
  __syncthreads();
  if (tid < 64) {
    float m = fmaxf(attn[tid], attn[tid + 64]);
#pragma unroll
    for (int msk = 1; msk <= 32; msk <<= 1) m = fmaxf(m, __shfl_xor(m, msk, 64));
    if (tid == 0) smax = m;
  }
  __syncthreads();
  if (tid < 128) attn[tid] = __expf(attn[tid] - smax);
  __syncthreads();
  if (tid < 64) {
    float s = attn[tid] + attn[tid + 64];
#pragma unroll
    for (int msk = 1; msk <= 32; msk <<= 1) s += __shfl_xor(s, msk, 64);
    if (tid == 0) ssum = 1.0f / s;
  }
  __syncthreads();
  if (tid < 128) attn[tid] *= ssum;
  __syncthreads();
  const unsigned short* xb = Xb + (size_t)n * 128 * 1024;
  const int c = tid & 127, h = tid >> 7;
  float acc[8] = {};
  for (int s = h; s < 128; s += 2) {
    float w = attn[s];
    u16x8 v = *(const u16x8*)&xb[(size_t)s * 1024 + c * 8];
#pragma unroll
    for (int j = 0; j < 8; ++j) acc[j] += w * bf2f(v[j]);
  }
  if (h == 1) {
#pragma unroll
    for (int j = 0; j < 8; ++j) red[c * 8 + j] = acc[j];
  }
  __syncthreads();
  if (h == 0) {
    unsigned short o[8];
#pragma unroll
    for (int j = 0; j < 8; ++j) o[j] = f2bf(acc[j] + red[c * 8 + j]);
    *(uint4*)&finalrb[(size_t)b * 2048 + (isCtx ? 1024 : 0) + c * 8] = *(uint4*)o;
  }
}

// ---------------------------------------------------------------------------
// cb GEMM (bf16 in): cb[b,e] = men_repr[b,:1024] . Wcm[e,:]; grid 128
// ---------------------------------------------------------------------------
__global__ __launch_bounds__(256) void k_cb_gemm_b(
    const unsigned short* __restrict__ finalrb, const unsigned short* __restrict__ Wcmb,
    float* __restrict__ cb) {
  __shared__ __align__(16) unsigned short As[64 * 32];
  __shared__ __align__(16) unsigned short Bs[64 * 32];
  const int bid = blockIdx.x;
  const int rowBase = (bid >> 4) * 64, colBase = (bid & 15) * 64;
  const int tid = threadIdx.x, wave = tid >> 6, lane = tid & 63;
  const int lm = lane & 15, lq = lane >> 4;
  const int sr = tid >> 2, sc = (tid & 3) * 8;
  f32x4 acc[4] = {};
  for (int k0 = 0; k0 < 1024; k0 += 32) {
    __syncthreads();
    *(uint4*)&As[sr * 32 + sc] = *(const uint4*)&finalrb[(size_t)(rowBase + sr) * 2048 + k0 + sc];
    *(uint4*)&Bs[sr * 32 + sc] = *(const uint4*)&Wcmb[(size_t)(colBase + sr) * 1024 + k0 + sc];
    __syncthreads();
    bf16x8 af = *(const bf16x8*)&As[(wave * 16 + lm) * 32 + lq * 8];
#pragma unroll
    for (int j = 0; j < 4; ++j) {
      bf16x8 bfr = *(const bf16x8*)&Bs[(j * 16 + lm) * 32 + lq * 8];
      acc[j] = __builtin_amdgcn_mfma_f32_16x16x32_bf16(af, bfr, acc[j], 0, 0, 0);
    }
  }
#pragma unroll
  for (int j = 0; j < 4; ++j) {
    int col = colBase + j * 16 + lm;
#pragma unroll
    for (int r = 0; r < 4; ++r) {
      int row = rowBase + wave * 16 + lq * 4 + r;
      cb[row * 1024 + col] = acc[j][r];
    }
  }
}

// ---------------------------------------------------------------------------
// latent GEMM split-K: latf[b, 0:128] += finalrb . Wf2lb^T over K-chunk.
// grid 128 = 2 colTiles x 8 rowTiles x 8 K-chunks. latf pre-zeroed.
// ---------------------------------------------------------------------------
__global__ __launch_bounds__(256) void k_lat_split(
    const unsigned short* __restrict__ finalrb, const unsigned short* __restrict__ Wf2lb,
    float* __restrict__ latf) {
  __shared__ __align__(16) unsigned short As[64 * 32];
  __shared__ __align__(16) unsigned short Bs[64 * 32];
  const int bid = blockIdx.x;
  const int ks = bid & 7;
  const int rowBase = ((bid >> 3) & 7) * 64;
  const int colBase = (bid >> 6) * 64;
  const int tid = threadIdx.x, wave = tid >> 6, lane = tid & 63;
  const int lm = lane & 15, lq = lane >> 4;
  const int sr = tid >> 2, sc = (tid & 3) * 8;
  f32x4 acc[4] = {};
  const int kEnd = ks * 256 + 256;
  for (int k0 = ks * 256; k0 < kEnd; k0 += 32) {
    __syncthreads();
    *(uint4*)&As[sr * 32 + sc] = *(const uint4*)&finalrb[(size_t)(rowBase + sr) * 2048 + k0 + sc];
    *(uint4*)&Bs[sr * 32 + sc] = *(const uint4*)&Wf2lb[(size_t)(colBase + sr) * 2048 + k0 + sc];
    __syncthreads();
    bf16x8 af = *(const bf16x8*)&As[(wave * 16 + lm) * 32 + lq * 8];
#pragma unroll
    for (int j = 0; j < 4; ++j) {
      bf16x8 bfr = *(const bf16x8*)&Bs[(j * 16 + lm) * 32 + lq * 8];
      acc[j] = __builtin_amdgcn_mfma_f32_16x16x32_bf16(af, bfr, acc[j], 0, 0, 0);
    }
  }
#pragma unroll
  for (int j = 0; j < 4; ++j) {
    int col = colBase + j * 16 + lm;
#pragma unroll
    for (int r = 0; r < 4; ++r) {
      int row = rowBase + wave * 16 + lq * 4 + r;
      atomicAdd(&latf[row * LATPAD + col], acc[j][r]);
    }
  }
}

// ---------------------------------------------------------------------------
// output GEMM with fused W_out f32->bf16 staging and T14 async B-prefetch:
// per K-step: raw barrier; DMA A; write PREFETCHED B regs->LDS (bf16);
// issue next-K B f32 loads; lgkmcnt(0)+vmcnt(8) (4 A-DMAs drained, 8
// prefetch loads stay in flight across the barrier); barrier; MFMA.
// sched_barrier(0) pins DMA-before-prefetch issue order so the count is
// exact (rule 18/21 discipline). B-row clamped so load issue is uniform.
// XCD-grouped mapping: 4 row-blocks sharing a B-panel on the same XCD.
// ---------------------------------------------------------------------------
__global__ __launch_bounds__(256) void k_out_gemm_f(
    const unsigned short* __restrict__ finalrb, const float* __restrict__ Wout,
    const unsigned short* __restrict__ latb, const unsigned short* __restrict__ Wl2lb,
    const float* __restrict__ lscale, float* __restrict__ out,
    float* __restrict__ outLat) {
  __shared__ __align__(16) unsigned short As[2 * 128 * 32];
  __shared__ __align__(16) unsigned short Bs[2 * 128 * 32];
  const int bid = blockIdx.x;
  const int xcd = bid & 7, idx = bid >> 3;
  const int rowTile = idx & 3, colTile = xcd + 8 * (idx >> 2);
  if (colTile >= 81) return;
  const int colBase = colTile * 128;
  const int rowBase = rowTile * 128;
  const int tid = threadIdx.x, wave = tid >> 6, lane = tid & 63;
  const int lm = lane & 15, lq = lane >> 4;
  const int wr = (wave & 1) * 64, wc = (wave >> 1) * 64;
  const int srow = wave * 32 + (lane >> 2);
  const int scol = (lane & 3) * 8;
  const float scal = lscale[0];
  const unsigned short* aPtr = finalrb + (size_t)(rowBase + srow) * 2048 + scol;
  // B staging: thread covers W_out row (colBase + tid/2), k-half (tid&1).
  // bv=false rows read row 0 (clamped) so vmem issue count is wave-uniform.
  const int br = tid >> 1, bh = tid & 1;
  const int bRow = colBase + br;
  const bool bv = bRow < LL;
  const float* bsrc = Wout + (size_t)(bv ? bRow : 0) * 2048 + bh * 32;
  unsigned short* bdst = &Bs[bh * 4096 + br * 32];
  float4 fa[8];
#pragma unroll
  for (int j = 0; j < 8; ++j) fa[j] = *(const float4*)(bsrc + j * 4);
  f32x4 acc[4][4] = {};
  for (int k0 = 0; k0 < 2048; k0 += 64) {
    __builtin_amdgcn_s_barrier();  // prev MFMA done reading LDS
    // A: async DMA bf16
    gl_lds16(aPtr + k0, As + wave * 1024);
    gl_lds16(aPtr + k0 + 16 * 2048, As + wave * 1024 + 512);
    gl_lds16(aPtr + k0 + 32, As + 4096 + wave * 1024);
    gl_lds16(aPtr + k0 + 32 + 16 * 2048, As + 4096 + wave * 1024 + 512);
    // B: convert prefetched regs -> LDS
    {
      unsigned short t[32];
#pragma unroll
      for (int j = 0; j < 8; ++j) {
        t[4 * j + 0] = f2bf(fa[j].x); t[4 * j + 1] = f2bf(fa[j].y);
        t[4 * j + 2] = f2bf(fa[j].z); t[4 * j + 3] = f2bf(fa[j].w);
      }
      if (bv) {
#pragma unroll
        for (int j = 0; j < 4; ++j) *(uint4*)(bdst + 8 * j) = *(uint4*)(t + 8 * j);
      } else {
        uint4 z = {0, 0, 0, 0};
#pragma unroll
        for (int j = 0; j < 4; ++j) *(uint4*)(bdst + 8 * j) = z;
      }
    }
    __builtin_amdgcn_sched_barrier(0);  // DMAs + ds_writes issue before prefetch
    if (k0 < 1984) {
#pragma unroll
      for (int j = 0; j < 8; ++j) fa[j] = *(const float4*)(bsrc + k0 + 64 + j * 4);
      asm volatile("s_waitcnt lgkmcnt(0)" ::: "memory");
      asm volatile("s_waitcnt vmcnt(8)" ::: "memory");  // A-DMAs done, prefetch in flight
    } else {
      asm volatile("s_waitcnt lgkmcnt(0)" ::: "memory");
      asm volatile("s_waitcnt vmcnt(0)" ::: "memory");  // tail drain
    }
    __builtin_amdgcn_sched_barrier(0);
    __builtin_amdgcn_s_barrier();
#pragma unroll
    for (int h = 0; h < 2; ++h) {
      bf16x8 af[4], bfr[4];
#pragma unroll
      for (int m = 0; m < 4; ++m)
        af[m] = *(const bf16x8*)&As[h * 4096 + (wr + m * 16 + lm) * 32 + lq * 8];
#pragma unroll
      for (int n = 0; n < 4; ++n)
        bfr[n] = *(const bf16x8*)&Bs[h * 4096 + (wc + n * 16 + lm) * 32 + lq * 8];
#pragma unroll
      for (int m = 0; m < 4; ++m)
#pragma unroll
        for (int n = 0; n < 4; ++n)
          acc[m][n] = __builtin_amdgcn_mfma_f32_16x16x32_bf16(af[m], bfr[n], acc[m][n], 0, 0, 0);
    }
  }
  // latent phase: K=128 (2 iters), separate accumulator; all-bf16 DMA
  const unsigned short* aPtr2 = latb + (size_t)(rowBase + srow) * LATPAD + scol;
  const unsigned short* bPtr2 = Wl2lb + (size_t)(colBase + srow) * LATPAD + scol;
  f32x4 acc2[4][4] = {};
  for (int k0 = 0; k0 < 128; k0 += 64) {
    __syncthreads();
#pragma unroll
    for (int h = 0; h < 2; ++h) {
      gl_lds16(aPtr2 + k0 + h * 32, As + h * 4096 + wave * 1024);
      gl_lds16(aPtr2 + k0 + h * 32 + 16 * LATPAD, As + h * 4096 + wave * 1024 + 512);
      gl_lds16(bPtr2 + k0 + h * 32, Bs + h * 4096 + wave * 1024);
      gl_lds16(bPtr2 + k0 + h * 32 + 16 * LATPAD, Bs + h * 4096 + wave * 1024 + 512);
    }
    __syncthreads();
#pragma unroll
    for (int h = 0; h < 2; ++h) {
      bf16x8 af[4], bfr[4];
#pragma unroll
      for (int m = 0; m < 4; ++m)
        af[m] = *(const bf16x8*)&As[h * 4096 + (wr + m * 16 + lm) * 32 + lq * 8];
#pragma unroll
      for (int n = 0; n < 4; ++n)
        bfr[n] = *(const bf16x8*)&Bs[h * 4096 + (wc + n * 16 + lm) * 32 + lq * 8];
#pragma unroll
      for (int m = 0; m < 4; ++m)
#pragma unroll
        for (int n = 0; n < 4; ++n)
          acc2[m][n] = __builtin_amdgcn_mfma_f32_16x16x32_bf16(af[m], bfr[n], acc2[m][n], 0, 0, 0);
    }
  }
#pragma unroll
  for (int m = 0; m < 4; ++m)
#pragma unroll
    for (int n = 0; n < 4; ++n) {
      int col = colBase + wc + n * 16 + lm;
      if (col < LL) {
#pragma unroll
        for (int r = 0; r < 4; ++r) {
          int row = rowBase + wr + m * 16 + lq * 4 + r;
          float lv = acc2[m][n][r];
          out[(size_t)row * LL + col] = acc[m][n][r] + scal * lv;
          outLat[(size_t)row * LL + col] = lv;
        }
      }
    }
}

// ======================= legacy fallback (round-3, proven) ==================
__global__ __launch_bounds__(256) void k_men_gemm(
    const float* __restrict__ X, const float* __restrict__ Wm,
    const float* __restrict__ wo, float* __restrict__ score) {
  __shared__ __align__(16) unsigned short As[64 * 32];
  __shared__ __align__(16) unsigned short Bs[64 * 32];
  const int bid = blockIdx.x;
  const int rowBase = (bid >> 4) * 64, colBase = (bid & 15) * 64;
  const int tid = threadIdx.x, wave = tid >> 6, lane = tid & 63;
  const int lm = lane & 15, lq = lane >> 4;
  const int sr = tid >> 2, sc = (tid & 3) * 8;
  f32x4 acc[4] = {};
  for (int k0 = 0; k0 < 1024; k0 += 32) {
    __syncthreads();
    stage8(&As[sr * 32 + sc], &X[(size_t)(rowBase + sr) * 1024 + k0 + sc]);
    stage8(&Bs[sr * 32 + sc], &Wm[(size_t)(colBase + sr) * 1024 + k0 + sc]);
    __syncthreads();
    bf16x8 af = *(const bf16x8*)&As[(wave * 16 + lm) * 32 + lq * 8];
#pragma unroll
    for (int j = 0; j < 4; ++j) {
      bf16x8 bfr = *(const bf16x8*)&Bs[(j * 16 + lm) * 32 + lq * 8];
      acc[j] = __builtin_amdgcn_mfma_f32_16x16x32_bf16(af, bfr, acc[j], 0, 0, 0);
    }
  }
  float rsum[4] = {0.f, 0.f, 0.f, 0.f};
#pragma unroll
  for (int j = 0; j < 4; ++j) {
    float w = wo[colBase + j * 16 + lm];
#pragma unroll
    for (int r = 0; r < 4; ++r) rsum[r] += tanhf(acc[j][r]) * w;
  }
#pragma unroll
  for (int m = 1; m <= 8; m <<= 1)
#pragma unroll
    for (int r = 0; r < 4; ++r) rsum[r] += __shfl_xor(rsum[r], m, 64);
  if (lm == 0) {
    int row0 = rowBase + wave * 16 + lq * 4;
#pragma unroll
    for (int r = 0; r < 4; ++r) atomicAdd(&score[row0 + r], rsum[r]);
  }
}

__global__ __launch_bounds__(256) void k_ctx_gemm(
    const float* __restrict__ X, const int* __restrict__ gathers,
    const float* __restrict__ Wc, const float* __restrict__ wd,
    const float* __restrict__ wo, const float* __restrict__ dist,
    const float* __restrict__ cb, float* __restrict__ score) {
  __shared__ __align__(16) unsigned short As[64 * 32];
  __shared__ __align__(16) unsigned short Bs[64 * 32];
  const int bid = blockIdx.x;
  const int rowBase = (bid >> 4) * 64, colBase = (bid & 15) * 64;
  const int tid = threadIdx.x, wave = tid >> 6, lane = tid & 63;
  const int lm = lane & 15, lq = lane >> 4;
  const int sr = tid >> 2, sc = (tid & 3) * 8;
  const int row_g = rowBase + sr;
  const int srcRow = (gathers[row_g >> 7] << 7) + (row_g & 127);
  f32x4 acc[4] = {};
  for (int k0 = 0; k0 < 1024; k0 += 32) {
    __syncthreads();
    stage8(&As[sr * 32 + sc], &X[(size_t)srcRow * 1024 + k0 + sc]);
    stage8(&Bs[sr * 32 + sc], &Wc[(size_t)(colBase + sr) * 1024 + k0 + sc]);
    __syncthreads();
    bf16x8 af = *(const bf16x8*)&As[(wave * 16 + lm) * 32 + lq * 8];
#pragma unroll
    for (int j = 0; j < 4; ++j) {
      bf16x8 bfr = *(const bf16x8*)&Bs[(j * 16 + lm) * 32 + lq * 8];
      acc[j] = __builtin_amdgcn_mfma_f32_16x16x32_bf16(af, bfr, acc[j], 0, 0, 0);
    }
  }
  float rsum[4] = {0.f, 0.f, 0.f, 0.f};
#pragma unroll
  for (int j = 0; j < 4; ++j) {
    int col = colBase + j * 16 + lm;
    float w = wo[col];
    float wdv = wd[col];
#pragma unroll
    for (int r = 0; r < 4; ++r) {
      int rg = rowBase + wave * 16 + lq * 4 + r;
      int b = rg >> 7, s = rg & 127;
      float v = acc[j][r] + cb[b * 1024 + col] + dist[b * 128 + s] * wdv;
      rsum[r] += tanhf(v) * w;
    }
  }
#pragma unroll
  for (int m = 1; m <= 8; m <<= 1)
#pragma unroll
    for (int r = 0; r < 4; ++r) rsum[r] += __shfl_xor(rsum[r], m, 64);
  if (lm == 0) {
    int row0 = rowBase + wave * 16 + lq * 4;
#pragma unroll
    for (int r = 0; r < 4; ++r) atomicAdd(&score[row0 + r], rsum[r]);
  }
}

__global__ __launch_bounds__(256) void k_soft(
    const float* __restrict__ score_src, const float* __restrict__ mask,
    const float* __restrict__ X, const int* __restrict__ gathers,
    float* __restrict__ finalr, int isCtx) {
  const int b = blockIdx.x, tid = threadIdx.x;
  const int n = gathers[b];
  __shared__ float attn[128];
  __shared__ float smax, ssum;
  if (tid < 128) {
    int srow = isCtx ? b : n;
    attn[tid] = score_src[srow * 128 + tid] + (1.0f - mask[b * 128 + tid]) * (-10000.0f);
  }
  __syncthreads();
  if (tid == 0) {
    float m = attn[0];
    for (int i = 1; i < 128; ++i) m = fmaxf(m, attn[i]);
    smax = m;
  }
  __syncthreads();
  if (tid < 128) attn[tid] = expf(attn[tid] - smax);
  __syncthreads();
  if (tid == 0) {
    float s = 0.f;
    for (int i = 0; i < 128; ++i) s += attn[i];
    ssum = 1.0f / s;
  }
  __syncthreads();
  if (tid < 128) attn[tid] *= ssum;
  __syncthreads();
  const float* xb = &X[(size_t)(n << 7) * 1024];
  const int off = isCtx ? 1024 : 0;
  for (int d = tid; d < 1024; d += 256) {
    float a = 0.f;
#pragma unroll 8
    for (int s = 0; s < 128; ++s) a += attn[s] * xb[s * 1024 + d];
    finalr[b * 2048 + off + d] = a;
  }
}

__global__ __launch_bounds__(256) void k_cb_gemm(
    const float* __restrict__ finalr, const float* __restrict__ Wcm,
    float* __restrict__ cb) {
  __shared__ __align__(16) unsigned short As[64 * 32];
  __shared__ __align__(16) unsigned short Bs[64 * 32];
  const int bid = blockIdx.x;
  const int rowBase = (bid >> 4) * 64, colBase = (bid & 15) * 64;
  const int tid = threadIdx.x, wave = tid >> 6, lane = tid & 63;
  const int lm = lane & 15, lq = lane >> 4;
  const int sr = tid >> 2, sc = (tid & 3) * 8;
  f32x4 acc[4] = {};
  for (int k0 = 0; k0 < 1024; k0 += 32) {
    __syncthreads();
    stage8(&As[sr * 32 + sc], &finalr[(size_t)(rowBase + sr) * 2048 + k0 + sc]);
    stage8(&Bs[sr * 32 + sc], &Wcm[(size_t)(colBase + sr) * 1024 + k0 + sc]);
    __syncthreads();
    bf16x8 af = *(const bf16x8*)&As[(wave * 16 + lm) * 32 + lq * 8];
#pragma unroll
    for (int j = 0; j < 4; ++j) {
      bf16x8 bfr = *(const bf16x8*)&Bs[(j * 16 + lm) * 32 + lq * 8];
      acc[j] = __builtin_amdgcn_mfma_f32_16x16x32_bf16(af, bfr, acc[j], 0, 0, 0);
    }
  }
#pragma unroll
  for (int j = 0; j < 4; ++j) {
    int col = colBase + j * 16 + lm;
#pragma unroll
    for (int r = 0; r < 4; ++r) {
      int row = rowBase + wave * 16 + lq * 4 + r;
      cb[row * 1024 + col] = acc[j][r];
    }
  }
}

__global__ __launch_bounds__(256) void k_lat_gemm(
    const float* __restrict__ finalr, const float* __restrict__ Wf2l,
    float* __restrict__ lat) {
  __shared__ __align__(16) unsigned short As[64 * 32];
  __shared__ __align__(16) unsigned short Bs[64 * 32];
  const int rowBase = blockIdx.y * 64, colBase = blockIdx.x * 64;
  const int tid = threadIdx.x, wave = tid >> 6, lane = tid & 63;
  const int lm = lane & 15, lq = lane >> 4;
  const int sr = tid >> 2, sc = (tid & 3) * 8;
  f32x4 acc[4] = {};
  for (int k0 = 0; k0 < 2048; k0 += 32) {
    __syncthreads();
    stage8(&As[sr * 32 + sc], &finalr[(size_t)(rowBase + sr) * 2048 + k0 + sc]);
    int l = colBase + sr;
    if (l < LATENT) {
      stage8(&Bs[sr * 32 + sc], &Wf2l[(size_t)l * 2048 + k0 + sc]);
    } else {
      uint4 z = {0, 0, 0, 0};
      *(uint4*)&Bs[sr * 32 + sc] = z;
    }
    __syncthreads();
    bf16x8 af = *(const bf16x8*)&As[(wave * 16 + lm) * 32 + lq * 8];
#pragma unroll
    for (int j = 0; j < 4; ++j) {
      bf16x8 bfr = *(const bf16x8*)&Bs[(j * 16 + lm) * 32 + lq * 8];
      acc[j] = __builtin_amdgcn_mfma_f32_16x16x32_bf16(af, bfr, acc[j], 0, 0, 0);
    }
  }
#pragma unroll
  for (int j = 0; j < 4; ++j) {
    int col = colBase + j * 16 + lm;
    if (col < LATENT) {
#pragma unroll
      for (int r = 0; r < 4; ++r) {
        int row = rowBase + wave * 16 + lq * 4 + r;
        lat[row * LATENT + col] = acc[j][r];
      }
    }
  }
}

__global__ __launch_bounds__(256) void k_out_gemm(
    const float* __restrict__ finalr, const float* __restrict__ Wout,
    const float* __restrict__ lat, const float* __restrict__ Wl2l,
    const float* __restrict__ lscale, float* __restrict__ out,
    float* __restrict__ outLat) {
  __shared__ __align__(16) unsigned short As[64 * 32];
  __shared__ __align__(16) unsigned short Bs[64 * 32];
  const int rowBase = blockIdx.y * 64, colBase = blockIdx.x * 64;
  const int tid = threadIdx.x, wave = tid >> 6, lane = tid & 63;
  const int lm = lane & 15, lq = lane >> 4;
  const int sr = tid >> 2, sc = (tid & 3) * 8;
  const float scal = lscale[0];
  const int lrow = colBase + sr;
  const bool lvalid = (lrow < LL);
  f32x4 acc[4] = {};
  for (int k0 = 0; k0 < 2048; k0 += 32) {
    __syncthreads();
    stage8(&As[sr * 32 + sc], &finalr[(size_t)(rowBase + sr) * 2048 + k0 + sc]);
    if (lvalid) {
      stage8(&Bs[sr * 32 + sc], &Wout[(size_t)lrow * 2048 + k0 + sc]);
    } else {
      uint4 z = {0, 0, 0, 0};
      *(uint4*)&Bs[sr * 32 + sc] = z;
    }
    __syncthreads();
    bf16x8 af = *(const bf16x8*)&As[(wave * 16 + lm) * 32 + lq * 8];
#pragma unroll
    for (int j = 0; j < 4; ++j) {
      bf16x8 bfr = *(const bf16x8*)&Bs[(j * 16 + lm) * 32 + lq * 8];
      acc[j] = __builtin_amdgcn_mfma_f32_16x16x32_bf16(af, bfr, acc[j], 0, 0, 0);
    }
  }
  f32x4 acc2[4] = {};
  for (int k2 = 0; k2 < 128; k2 += 32) {
    __syncthreads();
    const int brow = rowBase + sr;
#pragma unroll
    for (int jj = 0; jj < 8; ++jj) {
      int idx = k2 + sc + jj;
      As[sr * 32 + sc + jj] = (idx < LATENT) ? f2bf(lat[brow * LATENT + idx]) : (unsigned short)0;
      Bs[sr * 32 + sc + jj] = (lvalid && idx < LATENT) ? f2bf(Wl2l[lrow * LATENT + idx]) : (unsigned short)0;
    }
    __syncthreads();
    bf16x8 af = *(const bf16x8*)&As[(wave * 16 + lm) * 32 + lq * 8];
#pragma unroll
    for (int j = 0; j < 4; ++j) {
      bf16x8 bfr = *(const bf16x8*)&Bs[(j * 16 + lm) * 32 + lq * 8];
      acc2[j] = __builtin_amdgcn_mfma_f32_16x16x32_bf16(af, bfr, acc2[j], 0, 0, 0);
    }
  }
#pragma unroll
  for (int j = 0; j < 4; ++j) {
    int col = colBase + j * 16 + lm;
    if (col < LL) {
#pragma unroll
      for (int r = 0; r < 4; ++r) {
        int row = rowBase + wave * 16 + lq * 4 + r;
        float lv = acc2[j][r];
        out[(size_t)row * LL + col] = acc[j][r] + scal * lv;
        outLat[(size_t)row * LL + col] = lv;
      }
    }
  }
}

extern "C" void kernel_launch(void* const* d_in, const int* in_sizes, int n_in,
                              void* d_out, int out_size, void* d_ws, size_t ws_size,
                              hipStream_t stream) {
  const float* X = (const float*)d_in[0];
  const float* men_mask = (const float*)d_in[1];
  const float* ctx_mask = (const float*)d_in[2];
  const float* dist = (const float*)d_in[3];
  const int* gathers = (const int*)d_in[4];
  const float* W_men_m = (const float*)d_in[5];
  const float* W_men_o = (const float*)d_in[6];
  const float* W_ctx_c = (const float*)d_in[7];
  const float* W_ctx_m = (const float*)d_in[8];
  const float* w_ctx_d = (const float*)d_in[9];
  const float* W_ctx_o = (const float*)d_in[10];
  const float* W_out = (const float*)d_in[11];
  const float* W_f2l = (const float*)d_in[12];
  const float* W_l2l = (const float*)d_in[13];
  const float* lscale = (const float*)d_in[14];
  float* out = (float*)d_out;
  float* outLat = out + (size_t)BB * LL;

  size_t off = 0;
  auto carve = [&](size_t bytes) {
    void* p = (char*)d_ws + off;
    off = (off + bytes + 255) & ~(size_t)255;
    return p;
  };
  float* sent_score = (float*)carve(32768 * 4);
  float* ctx_score = (float*)carve(65536 * 4);
  float* finalr = (float*)carve((size_t)512 * 2048 * 4);        // legacy only
  float* cb = (float*)carve((size_t)512 * 1024 * 4);
  float* lat = (float*)carve((size_t)512 * LATENT * 4);         // legacy only
  unsigned short* Xb = (unsigned short*)carve((size_t)32768 * 1024 * 2);
  unsigned short* Wmb = (unsigned short*)carve((size_t)1024 * 1024 * 2);
  unsigned short* Wcb = (unsigned short*)carve((size_t)1024 * 1024 * 2);
  unsigned short* Wcmb = (unsigned short*)carve((size_t)1024 * 1024 * 2);
  unsigned short* Hc = (unsigned short*)carve((size_t)32768 * 1024 * 2);
  unsigned short* Wf2lb = (unsigned short*)carve((size_t)LATPAD * 2048 * 2);
  unsigned short* Wl2lb = (unsigned short*)carve((size_t)LPAD * LATPAD * 2);
  unsigned short* finalrb = (unsigned short*)carve((size_t)512 * 2048 * 2);
  unsigned short* latb = (unsigned short*)carve((size_t)512 * LATPAD * 2);
  float* latf = (float*)carve((size_t)512 * LATPAD * 4);
  const bool fits = off <= ws_size;

  if (fits) {
    hipMemsetAsync(sent_score, 0, 32768 * sizeof(float), stream);
    hipMemsetAsync(latf, 0, (size_t)512 * LATPAD * sizeof(float), stream);
    k_cvt<<<8192, 256, 0, stream>>>(X, Xb, 32768 * 1024 / 4);
    k_cvt_all<<<2048, 256, 0, stream>>>(W_men_m, W_ctx_c, W_ctx_m, W_f2l, W_l2l,
                                        Wmb, Wcb, Wcmb, Wf2lb, Wl2lb);
    k_mc_gemm8<<<256, 512, 0, stream>>>(Xb, Wmb, Wcb, W_men_o, sent_score, Hc);
    k_softb<<<512, 256, 0, stream>>>(sent_score, men_mask, Xb, gathers, finalrb, 0);
    k_cb_gemm_b<<<128, 256, 0, stream>>>(finalrb, Wcmb, cb);
    k_ctx_fused<<<512, 256, 0, stream>>>(Hc, gathers, cb, w_ctx_d, W_ctx_o, dist,
                                         ctx_mask, Xb, finalrb);
    k_lat_split<<<128, 256, 0, stream>>>(finalrb, Wf2lb, latf);
    k_cvt<<<64, 256, 0, stream>>>(latf, latb, 512 * LATPAD / 4);
    k_out_gemm_f<<<352, 256, 0, stream>>>(finalrb, W_out, latb, Wl2lb,
                                          lscale, out, outLat);
  } else {
    hipMemsetAsync(d_ws, 0, (32768 + 65536) * sizeof(float), stream);
    k_men_gemm<<<8192, 256, 0, stream>>>(X, W_men_m, W_men_o, sent_score);
    k_soft<<<512, 256, 0, stream>>>(sent_score, men_mask, X, gathers, finalr, 0);
    k_cb_gemm<<<128, 256, 0, stream>>>(finalr, W_ctx_m, cb);
    k_ctx_gemm<<<16384, 256, 0, stream>>>(X, gathers, W_ctx_c, w_ctx_d, W_ctx_o, dist, cb, ctx_score);
    k_soft<<<512, 256, 0, stream>>>(ctx_score, ctx_mask, X, gathers, finalr, 1);
    k_lat_gemm<<<dim3(2, 8), 256, 0, stream>>>(finalr, W_f2l, lat);
    k_out_gemm<<<dim3(162, 8), 256, 0, stream>>>(finalr, W_out, lat, W_l2l, lscale, out, outLat);
  }
}

// Round 5
// 644.973 us; speedup vs baseline: 1.1487x; 1.0114x over previous
//
#include <hip/hip_runtime.h>
#include <hip/hip_bf16.h>

typedef __bf16 bf16x8 __attribute__((ext_vector_type(8)));
typedef float f32x4 __attribute__((ext_vector_type(4)));
typedef unsigned short u16x8 __attribute__((ext_vector_type(8)));

#define DEV __device__ __forceinline__

static constexpr int N_SENTC = 256, BB = 512, SS = 128, DD = 1024;
static constexpr int LL = 10331, LATENT = 101;
static constexpr int LPAD = 10368;  // 162*64 = 81*128, row-padded L
static constexpr int LATPAD = 128;  // padded latent

DEV float bf2f(unsigned short u) {
  unsigned v = (unsigned)u << 16;
  return __builtin_bit_cast(float, v);
}
DEV unsigned short f2bf(float f) {
  unsigned u = __builtin_bit_cast(unsigned, f);
  unsigned lsb = (u >> 16) & 1u;
  u += 0x7fffu + lsb;
  return (unsigned short)(u >> 16);
}

// fast tanh: 1 - 2/(e^2x + 1); |err| ~1e-7 rel, saturates correctly at +-inf
DEV float fast_tanh(float x) {
  float e = __expf(2.0f * x);
  return 1.0f - 2.0f / (e + 1.0f);
}

DEV void stage8(unsigned short* dst, const float* src) {
  float4 a = *(const float4*)src;
  float4 b = *(const float4*)(src + 4);
  unsigned short t[8];
  t[0] = f2bf(a.x); t[1] = f2bf(a.y); t[2] = f2bf(a.z); t[3] = f2bf(a.w);
  t[4] = f2bf(b.x); t[5] = f2bf(b.y); t[6] = f2bf(b.z); t[7] = f2bf(b.w);
  *(uint4*)dst = *(uint4*)t;
}

// async global->LDS, 16B per lane; lds base wave-uniform (HW adds lane*16)
DEV void gl_lds16(const unsigned short* g, unsigned short* l) {
  __builtin_amdgcn_global_load_lds(
      (const __attribute__((address_space(1))) unsigned int*)g,
      (__attribute__((address_space(3))) unsigned int*)l, 16, 0, 0);
}

// ---------------------------------------------------------------------------
// f32 -> bf16 bulk convert (n4 = count/4)
// ---------------------------------------------------------------------------
__global__ __launch_bounds__(256) void k_cvt(
    const float* __restrict__ src, unsigned short* __restrict__ dst, int n4) {
  for (int i = blockIdx.x * 256 + threadIdx.x; i < n4; i += gridDim.x * 256) {
    float4 v = ((const float4*)src)[i];
    unsigned short t[4] = {f2bf(v.x), f2bf(v.y), f2bf(v.z), f2bf(v.w)};
    ((uint2*)dst)[i] = *(const uint2*)t;
  }
}

// ---------------------------------------------------------------------------
// All weight conversions in ONE launch (was 5 launches)
// ---------------------------------------------------------------------------
__global__ __launch_bounds__(256) void k_cvt_all(
    const float* __restrict__ Wm, const float* __restrict__ Wc,
    const float* __restrict__ Wcm, const float* __restrict__ Wf2l,
    const float* __restrict__ Wl2l,
    unsigned short* __restrict__ Wmb, unsigned short* __restrict__ Wcb,
    unsigned short* __restrict__ Wcmb, unsigned short* __restrict__ Wf2lb,
    unsigned short* __restrict__ Wl2lb) {
  const int NA = 3 * 262144;   // vec4 units, 3 square mats
  const int NB = 65536;        // vec4 units, [128][2048]
  const int NC = 331776;       // vec4 units, [10368][128]
  for (int u = blockIdx.x * 256 + threadIdx.x; u < NA + NB + NC; u += gridDim.x * 256) {
    if (u < NA) {
      int which = u >> 18, off = u & 262143;
      const float* s = which == 0 ? Wm : (which == 1 ? Wc : Wcm);
      unsigned short* d = which == 0 ? Wmb : (which == 1 ? Wcb : Wcmb);
      float4 v = ((const float4*)s)[off];
      unsigned short t[4] = {f2bf(v.x), f2bf(v.y), f2bf(v.z), f2bf(v.w)};
      ((uint2*)d)[off] = *(const uint2*)t;
    } else if (u < NA + NB) {
      int off = u - NA;
      int r = off >> 9;  // (off*4)/2048
      if (r < LATENT) {
        float4 v = ((const float4*)Wf2l)[off];
        unsigned short t[4] = {f2bf(v.x), f2bf(v.y), f2bf(v.z), f2bf(v.w)};
        ((uint2*)Wf2lb)[off] = *(const uint2*)t;
      } else {
        ((uint2*)Wf2lb)[off] = make_uint2(0, 0);
      }
    } else {
      int off = u - NA - NB;
      int idx = off * 4;
      int r = idx >> 7, c0 = idx & 127;
      unsigned short t[4];
#pragma unroll
      for (int j = 0; j < 4; ++j) {
        int c = c0 + j;
        t[j] = (r < LL && c < LATENT) ? f2bf(Wl2l[(size_t)r * LATENT + c])
                                      : (unsigned short)0;
      }
      ((uint2*)Wl2lb)[off] = *(const uint2*)t;
    }
  }
}

// ---------------------------------------------------------------------------
// Fused men-score + ctx-hidden GEMM, 256x256-tile 8-phase schedule,
// PERSISTENT blocks (grid 256, 4 tiles each; colTile constant per block).
// Round-5 changes:
//  * ds_read rebalance 4/4/8/8: af0 for kt+1 prefetched from buf^1 during
//    phase 4 (read-idle). vmcnt proof: 12 outstanding at ph4, oldest 2 =
//    A-h0(kt+1) -> vmcnt(10) (kt<14) / vmcnt(6) (kt==14) lands them.
//  * ctx epilogue: LDS-bounce (reuse 128KB staging LDS, dead after final
//    vmcnt(0)) -> coalesced uint4 stores instead of 128 scalar u16 stores.
//  * men epilogue: next assignment's PRO() issued BEFORE the tanh/shfl work
//    (men epilogue touches no LDS) so prologue HBM latency hides under VALU.
// ---------------------------------------------------------------------------
__global__ __launch_bounds__(512) void k_mc_gemm8(
    const unsigned short* __restrict__ Xb, const unsigned short* __restrict__ Wmb,
    const unsigned short* __restrict__ Wcb, const float* __restrict__ wo,
    float* __restrict__ score, unsigned short* __restrict__ Hc) {
  __shared__ __align__(16) unsigned short lds[2][2][2][8192];
  const int p = blockIdx.x;  // 256 persistent blocks
  const int tid = threadIdx.x, w = tid >> 6, lane = tid & 63;
  const int lm = lane & 15, lq = lane >> 4;
  const int wr = w >> 2, wc = w & 3;
  const int stRow = w * 16 + (lane >> 2);
  const int stCol = ((lane & 3) * 8) ^ ((lane >> 5) << 4);
  const int rdCol = (lq * 16) ^ ((lane & 8) ? 32 : 0);
  const int aoff = (wr * 16 + lm) * 64 + rdCol;
  const int boff = (wc * 16 + lm) * 64 + rdCol;

  const unsigned short* aSrc;
  const unsigned short* bSrc;
  int rowBase, bcolBase;
  bool isMen;
  auto setTile = [&](int t) {
    const int vbid = p + 256 * t;
    const int lbid = (vbid & 7) * 128 + (vbid >> 3);  // bijective XCD swizzle
    const int colTile = lbid & 7, rowTile = lbid >> 3;
    rowBase = rowTile * 256;
    isMen = colTile < 4;   // colTile = (p>>3)&7: constant per block
    bcolBase = (colTile & 3) * 256;
    aSrc = Xb + (size_t)(rowBase + stRow) * 1024 + stCol;
    bSrc = (isMen ? Wmb : Wcb) + (size_t)(bcolBase + stRow) * 1024 + stCol;
  };

  auto ST = [&](int op, int h, int kt, int buf) {
    const unsigned short* s = (op ? bSrc : aSrc) + (size_t)h * 131072 + kt * 64;
    unsigned short* d = &lds[buf][op][h][w * 512];
    gl_lds16(s, d);
    gl_lds16(s + 32, d + 4096);
  };
  auto PRO = [&]() {
    ST(0, 0, 0, 0); ST(1, 0, 0, 0); ST(0, 1, 0, 0); ST(1, 1, 0, 0);
    ST(0, 0, 1, 1); ST(1, 0, 1, 1); ST(0, 1, 1, 1);
  };

  setTile(0);
  PRO();

  for (int t = 0; t < 4; ++t) {
    asm volatile("s_waitcnt vmcnt(6)" ::: "memory");  // kt0's 8 loads landed
    __builtin_amdgcn_s_barrier();

    f32x4 acc[8][4] = {};
    bf16x8 af0[4][2], af1[4][2], bfr[4][2];
    // preload af0 for kt=0 (buf 0 fully resident)
    {
      const char* A0 = (const char*)&lds[0][0][0][0];
#pragma unroll
      for (int m = 0; m < 4; ++m)
#pragma unroll
        for (int ks = 0; ks < 2; ++ks)
          af0[m][ks] = *(const bf16x8*)(A0 + aoff + m * 2048 + ks * 8192);
    }
    for (int kt = 0; kt < 16; ++kt) {
      const int buf = kt & 1;
      const char* A1 = (const char*)&lds[buf][0][1][0];
      const char* B0 = (const char*)&lds[buf][1][0][0];
      const char* B1 = (const char*)&lds[buf][1][1][0];
      // ---- phase 1: Q(0,0)  reads B-h0 only (af0 preloaded in prev ph4)
#pragma unroll
      for (int n = 0; n < 2; ++n)
#pragma unroll
        for (int ks = 0; ks < 2; ++ks)
          bfr[n][ks] = *(const bf16x8*)(B0 + boff + n * 4096 + ks * 8192);
      if (kt + 1 < 16) ST(1, 1, kt + 1, buf ^ 1);
      __builtin_amdgcn_s_barrier();
      __builtin_amdgcn_s_setprio(1);
#pragma unroll
      for (int m = 0; m < 4; ++m)
#pragma unroll
        for (int n = 0; n < 2; ++n)
#pragma unroll
          for (int ks = 0; ks < 2; ++ks)
            acc[m][n] = __builtin_amdgcn_mfma_f32_16x16x32_bf16(af0[m][ks], bfr[n][ks], acc[m][n], 0, 0, 0);
      __builtin_amdgcn_s_setprio(0);
      __builtin_amdgcn_s_barrier();
      // ---- phase 2: Q(0,1)  reads B-h1
#pragma unroll
      for (int n = 0; n < 2; ++n)
#pragma unroll
        for (int ks = 0; ks < 2; ++ks)
          bfr[2 + n][ks] = *(const bf16x8*)(B1 + boff + n * 4096 + ks * 8192);
      if (kt + 2 < 16) ST(0, 0, kt + 2, buf);
      __builtin_amdgcn_s_barrier();
      __builtin_amdgcn_s_setprio(1);
#pragma unroll
      for (int m = 0; m < 4; ++m)
#pragma unroll
        for (int n = 0; n < 2; ++n)
#pragma unroll
          for (int ks = 0; ks < 2; ++ks)
            acc[m][2 + n] = __builtin_amdgcn_mfma_f32_16x16x32_bf16(af0[m][ks], bfr[2 + n][ks], acc[m][2 + n], 0, 0, 0);
      __builtin_amdgcn_s_setprio(0);
      __builtin_amdgcn_s_barrier();
      // ---- phase 3: Q(1,0)  reads A-h1 -> af1
#pragma unroll
      for (int m = 0; m < 4; ++m)
#pragma unroll
        for (int ks = 0; ks < 2; ++ks)
          af1[m][ks] = *(const bf16x8*)(A1 + aoff + m * 2048 + ks * 8192);
      if (kt + 2 < 16) ST(1, 0, kt + 2, buf);
      __builtin_amdgcn_s_barrier();
      __builtin_amdgcn_s_setprio(1);
#pragma unroll
      for (int m = 0; m < 4; ++m)
#pragma unroll
        for (int n = 0; n < 2; ++n)
#pragma unroll
          for (int ks = 0; ks < 2; ++ks)
            acc[4 + m][n] = __builtin_amdgcn_mfma_f32_16x16x32_bf16(af1[m][ks], bfr[n][ks], acc[4 + m][n], 0, 0, 0);
      __builtin_amdgcn_s_setprio(0);
      __builtin_amdgcn_s_barrier();
      // ---- phase 4: Q(1,1)  prefetch af0 for kt+1 from buf^1 (read-idle ph)
      if (kt + 1 < 16) {
        if (kt < 14) {
          asm volatile("s_waitcnt vmcnt(10)" ::: "memory");  // A-h0(kt+1) landed
        } else {
          asm volatile("s_waitcnt vmcnt(6)" ::: "memory");   // kt==14 tail case
        }
        const char* A0n = (const char*)&lds[buf ^ 1][0][0][0];
#pragma unroll
        for (int m = 0; m < 4; ++m)
#pragma unroll
          for (int ks = 0; ks < 2; ++ks)
            af0[m][ks] = *(const bf16x8*)(A0n + aoff + m * 2048 + ks * 8192);
      }
      if (kt + 2 < 16) ST(0, 1, kt + 2, buf);
      __builtin_amdgcn_s_barrier();
      __builtin_amdgcn_s_setprio(1);
#pragma unroll
      for (int m = 0; m < 4; ++m)
#pragma unroll
        for (int n = 0; n < 2; ++n)
#pragma unroll
          for (int ks = 0; ks < 2; ++ks)
            acc[4 + m][2 + n] = __builtin_amdgcn_mfma_f32_16x16x32_bf16(af1[m][ks], bfr[2 + n][ks], acc[4 + m][2 + n], 0, 0, 0);
      __builtin_amdgcn_s_setprio(0);
      if (kt < 14) {
        asm volatile("s_waitcnt vmcnt(6)" ::: "memory");
      } else {
        asm volatile("s_waitcnt vmcnt(0)" ::: "memory");
      }
      __builtin_amdgcn_s_barrier();
    }

    // -------- epilogue (all DMAs drained; LDS free) --------
    const int eRow = rowBase, eCol = bcolBase;
    if (isMen) {
      if (t < 3) { setTile(t + 1); PRO(); }  // loads overlap epilogue VALU
      float wov[4];
#pragma unroll
      for (int n = 0; n < 4; ++n) wov[n] = wo[eCol + n * 64 + wc * 16 + lm];
      float rsum[8][4];
#pragma unroll
      for (int m = 0; m < 8; ++m)
#pragma unroll
        for (int r = 0; r < 4; ++r) {
          float s = 0.f;
#pragma unroll
          for (int n = 0; n < 4; ++n) s += fast_tanh(acc[m][n][r]) * wov[n];
          rsum[m][r] = s;
        }
#pragma unroll
      for (int msk = 1; msk <= 8; msk <<= 1)
#pragma unroll
        for (int m = 0; m < 8; ++m)
#pragma unroll
          for (int r = 0; r < 4; ++r) rsum[m][r] += __shfl_xor(rsum[m][r], msk, 64);
      if (lm == 0) {
#pragma unroll
        for (int m = 0; m < 8; ++m)
#pragma unroll
          for (int r = 0; r < 4; ++r)
            atomicAdd(&score[eRow + m * 32 + wr * 16 + lq * 4 + r], rsum[m][r]);
      }
    } else {
      // LDS-bounce: acc -> S[256][256] bf16 (=128KB, exact lds reuse) ->
      // coalesced uint4 row stores (each inst: 2 rows x 512B)
      unsigned short (*S)[256] = (unsigned short (*)[256]) & lds[0][0][0][0];
#pragma unroll
      for (int m = 0; m < 8; ++m) {
        const int rl = m * 32 + wr * 16 + lq * 4;
#pragma unroll
        for (int n = 0; n < 4; ++n) {
          const int cl = wc * 16 + n * 64 + lm;
#pragma unroll
          for (int r = 0; r < 4; ++r) S[rl + r][cl] = f2bf(acc[m][n][r]);
        }
      }
      __syncthreads();
      const int srowl = lane >> 5;       // 0/1
      const int scoll = (lane & 31) * 8; // elems
#pragma unroll
      for (int i = 0; i < 16; ++i) {
        int row = w * 32 + i * 2 + srowl;
        uint4 v = *(const uint4*)&S[row][scoll];
        *(uint4*)&Hc[(size_t)(eRow + row) * 1024 + eCol + scoll] = v;
      }
      __syncthreads();  // all waves done reading S before next DMA lands
      if (t < 3) { setTile(t + 1); PRO(); }
    }
  }
}

// ---------------------------------------------------------------------------
// FUSED ctx score + softmax + weighted sum. grid 512.
// ---------------------------------------------------------------------------
__global__ __launch_bounds__(256) void k_ctx_fused(
    const unsigned short* __restrict__ Hc, const int* __restrict__ gathers,
    const float* __restrict__ cb, const float* __restrict__ wd,
    const float* __restrict__ wo, const float* __restrict__ dist,
    const float* __restrict__ mask, const unsigned short* __restrict__ Xb,
    unsigned short* __restrict__ finalrb) {
  const int b = blockIdx.x, tid = threadIdx.x, wave = tid >> 6, lane = tid & 63;
  const int n = gathers[b];
  __shared__ float cbl[1024], wdl[1024], wol[1024];
  __shared__ float attn[128];
  __shared__ float red[128 * 8];
  __shared__ float smax, ssum;
  for (int i = tid; i < 1024; i += 256) {
    cbl[i] = cb[b * 1024 + i];
    wdl[i] = wd[i];
    wol[i] = wo[i];
  }
  __syncthreads();
  for (int s = wave; s < 128; s += 4) {
    float d = dist[b * 128 + s];
    const unsigned short* hrow = &Hc[(size_t)(n * 128 + s) * 1024 + lane * 16];
    unsigned short hs[16];
    *(uint4*)hs = *(const uint4*)hrow;
    *(uint4*)(hs + 8) = *(const uint4*)(hrow + 8);
    float p = 0.f;
#pragma unroll
    for (int j = 0; j < 16; ++j) {
      int e = lane * 16 + j;
      p += fast_tanh(bf2f(hs[j]) + cbl[e] + d * wdl[e]) * wol[e];
    }
#pragma unroll
    for (int msk = 1; msk <= 32; msk <<= 1) p += __shfl_xor(p, msk, 64);
    if (lane == 0) attn[s] = p + (1.0f - mask[b * 128 + s]) * (-10000.0f);
  }
  __syncthreads();
  if (tid < 64) {
    float m = fmaxf(attn[tid], attn[tid + 64]);
#pragma unroll
    for (int msk = 1; msk <= 32; msk <<= 1) m = fmaxf(m, __shfl_xor(m, msk, 64));
    if (tid == 0) smax = m;
  }
  __syncthreads();
  if (tid < 128) attn[tid] = __expf(attn[tid] - smax);
  __syncthreads();
  if (tid < 64) {
    float s = attn[tid] + attn[tid + 64];
#pragma unroll
    for (int msk = 1; msk <= 32; msk <<= 1) s += __shfl_xor(s, msk, 64);
    if (tid == 0) ssum = 1.0f / s;
  }
  __syncthreads();
  if (tid < 128) attn[tid] *= ssum;
  __syncthreads();
  const unsigned short* xb = Xb + (size_t)n * 128 * 1024;
  const int c = tid & 127, h = tid >> 7;
  float acc[8] = {};
  for (int s = h; s < 128; s += 2) {
    float w = attn[s];
    u16x8 v = *(const u16x8*)&xb[(size_t)s * 1024 + c * 8];
#pragma unroll
    for (int j = 0; j < 8; ++j) acc[j] += w * bf2f(v[j]);
  }
  if (h == 1) {
#pragma unroll
    for (int j = 0; j < 8; ++j) red[c * 8 + j] = acc[j];
  }
  __syncthreads();
  if (h == 0) {
    unsigned short o[8];
#pragma unroll
    for (int j = 0; j < 8; ++j) o[j] = f2bf(acc[j] + red[c * 8 + j]);
    *(uint4*)&finalrb[(size_t)b * 2048 + 1024 + c * 8] = *(uint4*)o;
  }
}

// ---------------------------------------------------------------------------
// softmax over S=128 (wave-parallel) + weighted sum -> bf16 repr (men path)
// ---------------------------------------------------------------------------
__global__ __launch_bounds__(256) void k_softb(
    const float* __restrict__ score_src, const float* __restrict__ mask,
    const unsigned short* __restrict__ Xb, const int* __restrict__ gathers,
    unsigned short* __restrict__ finalrb, int isCtx) {
  const int b = blockIdx.x, tid = threadIdx.x;
  const int n = gathers[b];
  __shared__ float attn[128];
  __shared__ float red[128 * 8];
  __shared__ float smax, ssum;
  if (tid < 128) {
    int srow = isCtx ? b : n;
    attn[tid] = score_src[srow * 128 + tid] + (1.0f - mask[b * 128 + tid]) * (-10000.0f);
  }
  __syncthreads();
  if (tid < 64) {
    float m = fmaxf(attn[tid], attn[tid + 64]);
#pragma unroll
    for (int msk = 1; msk <= 32; msk <<= 1) m = fmaxf(m, __shfl_xor(m, msk, 64));
    if (tid == 0) smax = m;
  }
  __syncthreads();
  if (tid < 128) attn[tid] = __expf(attn[tid] - smax);
  __syncthreads();
  if (tid < 64) {
    float s = attn[tid] + attn[tid + 64];
#pragma unroll
    for (int msk = 1; msk <= 32; msk <<= 1) s += __shfl_xor(s, msk, 64);
    if (tid == 0) ssum = 1.0f / s;
  }
  __syncthreads();
  if (tid < 128) attn[tid] *= ssum;
  __syncthreads();
  const unsigned short* xb = Xb + (size_t)n * 128 * 1024;
  const int c = tid & 127, h = tid >> 7;
  float acc[8] = {};
  for (int s = h; s < 128; s += 2) {
    float w = attn[s];
    u16x8 v = *(const u16x8*)&xb[(size_t)s * 1024 + c * 8];
#pragma unroll
    for (int j = 0; j < 8; ++j) acc[j] += w * bf2f(v[j]);
  }
  if (h == 1) {
#pragma unroll
    for (int j = 0; j < 8; ++j) red[c * 8 + j] = acc[j];
  }
  __syncthreads();
  if (h == 0) {
    unsigned short o[8];
#pragma unroll
    for (int j = 0; j < 8; ++j) o[j] = f2bf(acc[j] + red[c * 8 + j]);
    *(uint4*)&finalrb[(size_t)b * 2048 + (isCtx ? 1024 : 0) + c * 8] = *(uint4*)o;
  }
}

// ---------------------------------------------------------------------------
// cb GEMM split-K x2: cb[b,e] += men_repr[b]. Wcm[e] over K-half.
// grid 256 = 16 colTiles x 8 rowTiles x 2 K-halves. cb pre-zeroed.
// ---------------------------------------------------------------------------
__global__ __launch_bounds__(256) void k_cb_split(
    const unsigned short* __restrict__ finalrb, const unsigned short* __restrict__ Wcmb,
    float* __restrict__ cb) {
  __shared__ __align__(16) unsigned short As[64 * 32];
  __shared__ __align__(16) unsigned short Bs[64 * 32];
  const int bid = blockIdx.x;
  const int ks = bid & 1;
  const int rowBase = ((bid >> 1) & 7) * 64;
  const int colBase = (bid >> 4) * 64;
  const int tid = threadIdx.x, wave = tid >> 6, lane = tid & 63;
  const int lm = lane & 15, lq = lane >> 4;
  const int sr = tid >> 2, sc = (tid & 3) * 8;
  f32x4 acc[4] = {};
  const int kEnd = ks * 512 + 512;
  for (int k0 = ks * 512; k0 < kEnd; k0 += 32) {
    __syncthreads();
    *(uint4*)&As[sr * 32 + sc] = *(const uint4*)&finalrb[(size_t)(rowBase + sr) * 2048 + k0 + sc];
    *(uint4*)&Bs[sr * 32 + sc] = *(const uint4*)&Wcmb[(size_t)(colBase + sr) * 1024 + k0 + sc];
    __syncthreads();
    bf16x8 af = *(const bf16x8*)&As[(wave * 16 + lm) * 32 + lq * 8];
#pragma unroll
    for (int j = 0; j < 4; ++j) {
      bf16x8 bfr = *(const bf16x8*)&Bs[(j * 16 + lm) * 32 + lq * 8];
      acc[j] = __builtin_amdgcn_mfma_f32_16x16x32_bf16(af, bfr, acc[j], 0, 0, 0);
    }
  }
#pragma unroll
  for (int j = 0; j < 4; ++j) {
    int col = colBase + j * 16 + lm;
#pragma unroll
    for (int r = 0; r < 4; ++r) {
      int row = rowBase + wave * 16 + lq * 4 + r;
      atomicAdd(&cb[row * 1024 + col], acc[j][r]);
    }
  }
}

// ---------------------------------------------------------------------------
// latent GEMM split-K: grid 128 = 2 colTiles x 8 rowTiles x 8 K-chunks.
// ---------------------------------------------------------------------------
__global__ __launch_bounds__(256) void k_lat_split(
    const unsigned short* __restrict__ finalrb, const unsigned short* __restrict__ Wf2lb,
    float* __restrict__ latf) {
  __shared__ __align__(16) unsigned short As[64 * 32];
  __shared__ __align__(16) unsigned short Bs[64 * 32];
  const int bid = blockIdx.x;
  const int ks = bid & 7;
  const int rowBase = ((bid >> 3) & 7) * 64;
  const int colBase = (bid >> 6) * 64;
  const int tid = threadIdx.x, wave = tid >> 6, lane = tid & 63;
  const int lm = lane & 15, lq = lane >> 4;
  const int sr = tid >> 2, sc = (tid & 3) * 8;
  f32x4 acc[4] = {};
  const int kEnd = ks * 256 + 256;
  for (int k0 = ks * 256; k0 < kEnd; k0 += 32) {
    __syncthreads();
    *(uint4*)&As[sr * 32 + sc] = *(const uint4*)&finalrb[(size_t)(rowBase + sr) * 2048 + k0 + sc];
    *(uint4*)&Bs[sr * 32 + sc] = *(const uint4*)&Wf2lb[(size_t)(colBase + sr) * 2048 + k0 + sc];
    __syncthreads();
    bf16x8 af = *(const bf16x8*)&As[(wave * 16 + lm) * 32 + lq * 8];
#pragma unroll
    for (int j = 0; j < 4; ++j) {
      bf16x8 bfr = *(const bf16x8*)&Bs[(j * 16 + lm) * 32 + lq * 8];
      acc[j] = __builtin_amdgcn_mfma_f32_16x16x32_bf16(af, bfr, acc[j], 0, 0, 0);
    }
  }
#pragma unroll
  for (int j = 0; j < 4; ++j) {
    int col = colBase + j * 16 + lm;
#pragma unroll
    for (int r = 0; r < 4; ++r) {
      int row = rowBase + wave * 16 + lq * 4 + r;
      atomicAdd(&latf[row * LATPAD + col], acc[j][r]);
    }
  }
}

// ---------------------------------------------------------------------------
// output GEMM with fused W_out f32->bf16 staging + reg-prefetch (T14).
// Counted waits kept (required: raw barriers + gl_lds16 need manual vmcnt);
// sched_barrier(0) pins REMOVED (m141: order-pinning defeats the scheduler).
// ---------------------------------------------------------------------------
__global__ __launch_bounds__(256) void k_out_gemm_f(
    const unsigned short* __restrict__ finalrb, const float* __restrict__ Wout,
    const unsigned short* __restrict__ latb, const unsigned short* __restrict__ Wl2lb,
    const float* __restrict__ lscale, float* __restrict__ out,
    float* __restrict__ outLat) {
  __shared__ __align__(16) unsigned short As[2 * 128 * 32];
  __shared__ __align__(16) unsigned short Bs[2 * 128 * 32];
  const int bid = blockIdx.x;
  const int xcd = bid & 7, idx = bid >> 3;
  const int rowTile = idx & 3, colTile = xcd + 8 * (idx >> 2);
  if (colTile >= 81) return;
  const int colBase = colTile * 128;
  const int rowBase = rowTile * 128;
  const int tid = threadIdx.x, wave = tid >> 6, lane = tid & 63;
  const int lm = lane & 15, lq = lane >> 4;
  const int wr = (wave & 1) * 64, wc = (wave >> 1) * 64;
  const int srow = wave * 32 + (lane >> 2);
  const int scol = (lane & 3) * 8;
  const float scal = lscale[0];
  const unsigned short* aPtr = finalrb + (size_t)(rowBase + srow) * 2048 + scol;
  const int br = tid >> 1, bh = tid & 1;
  const int bRow = colBase + br;
  const bool bv = bRow < LL;
  const float* bsrc = Wout + (size_t)(bv ? bRow : 0) * 2048 + bh * 32;
  unsigned short* bdst = &Bs[bh * 4096 + br * 32];
  float4 fa[8];
#pragma unroll
  for (int j = 0; j < 8; ++j) fa[j] = *(const float4*)(bsrc + j * 4);
  f32x4 acc[4][4] = {};
  for (int k0 = 0; k0 < 2048; k0 += 64) {
    __builtin_amdgcn_s_barrier();  // prev MFMA done reading LDS
    gl_lds16(aPtr + k0, As + wave * 1024);
    gl_lds16(aPtr + k0 + 16 * 2048, As + wave * 1024 + 512);
    gl_lds16(aPtr + k0 + 32, As + 4096 + wave * 1024);
    gl_lds16(aPtr + k0 + 32 + 16 * 2048, As + 4096 + wave * 1024 + 512);
    {
      unsigned short t[32];
#pragma unroll
      for (int j = 0; j < 8; ++j) {
        t[4 * j + 0] = f2bf(fa[j].x); t[4 * j + 1] = f2bf(fa[j].y);
        t[4 * j + 2] = f2bf(fa[j].z); t[4 * j + 3] = f2bf(fa[j].w);
      }
      if (bv) {
#pragma unroll
        for (int j = 0; j < 4; ++j) *(uint4*)(bdst + 8 * j) = *(uint4*)(t + 8 * j);
      } else {
        uint4 z = {0, 0, 0, 0};
#pragma unroll
        for (int j = 0; j < 4; ++j) *(uint4*)(bdst + 8 * j) = z;
      }
    }
    if (k0 < 1984) {
#pragma unroll
      for (int j = 0; j < 8; ++j) fa[j] = *(const float4*)(bsrc + k0 + 64 + j * 4);
      asm volatile("s_waitcnt lgkmcnt(0)" ::: "memory");
      asm volatile("s_waitcnt vmcnt(8)" ::: "memory");  // A-DMAs done, prefetch in flight
    } else {
      asm volatile("s_waitcnt lgkmcnt(0)" ::: "memory");
      asm volatile("s_waitcnt vmcnt(0)" ::: "memory");  // tail drain
    }
    __builtin_amdgcn_s_barrier();
#pragma unroll
    for (int h = 0; h < 2; ++h) {
      bf16x8 af[4], bfr[4];
#pragma unroll
      for (int m = 0; m < 4; ++m)
        af[m] = *(const bf16x8*)&As[h * 4096 + (wr + m * 16 + lm) * 32 + lq * 8];
#pragma unroll
      for (int n = 0; n < 4; ++n)
        bfr[n] = *(const bf16x8*)&Bs[h * 4096 + (wc + n * 16 + lm) * 32 + lq * 8];
#pragma unroll
      for (int m = 0; m < 4; ++m)
#pragma unroll
        for (int n = 0; n < 4; ++n)
          acc[m][n] = __builtin_amdgcn_mfma_f32_16x16x32_bf16(af[m], bfr[n], acc[m][n], 0, 0, 0);
    }
  }
  // latent phase: K=128 (2 iters), separate accumulator; all-bf16 DMA
  const unsigned short* aPtr2 = latb + (size_t)(rowBase + srow) * LATPAD + scol;
  const unsigned short* bPtr2 = Wl2lb + (size_t)(colBase + srow) * LATPAD + scol;
  f32x4 acc2[4][4] = {};
  for (int k0 = 0; k0 < 128; k0 += 64) {
    __syncthreads();
#pragma unroll
    for (int h = 0; h < 2; ++h) {
      gl_lds16(aPtr2 + k0 + h * 32, As + h * 4096 + wave * 1024);
      gl_lds16(aPtr2 + k0 + h * 32 + 16 * LATPAD, As + h * 4096 + wave * 1024 + 512);
      gl_lds16(bPtr2 + k0 + h * 32, Bs + h * 4096 + wave * 1024);
      gl_lds16(bPtr2 + k0 + h * 32 + 16 * LATPAD, Bs + h * 4096 + wave * 1024 + 512);
    }
    __syncthreads();
#pragma unroll
    for (int h = 0; h < 2; ++h) {
      bf16x8 af[4], bfr[4];
#pragma unroll
      for (int m = 0; m < 4; ++m)
        af[m] = *(const bf16x8*)&As[h * 4096 + (wr + m * 16 + lm) * 32 + lq * 8];
#pragma unroll
      for (int n = 0; n < 4; ++n)
        bfr[n] = *(const bf16x8*)&Bs[h * 4096 + (wc + n * 16 + lm) * 32 + lq * 8];
#pragma unroll
      for (int m = 0; m < 4; ++m)
#pragma unroll
        for (int n = 0; n < 4; ++n)
          acc2[m][n] = __builtin_amdgcn_mfma_f32_16x16x32_bf16(af[m], bfr[n], acc2[m][n], 0, 0, 0);
    }
  }
#pragma unroll
  for (int m = 0; m < 4; ++m)
#pragma unroll
    for (int n = 0; n < 4; ++n) {
      int col = colBase + wc + n * 16 + lm;
      if (col < LL) {
#pragma unroll
        for (int r = 0; r < 4; ++r) {
          int row = rowBase + wr + m * 16 + lq * 4 + r;
          float lv = acc2[m][n][r];
          out[(size_t)row * LL + col] = acc[m][n][r] + scal * lv;
          outLat[(size_t)row * LL + col] = lv;
        }
      }
    }
}

// ======================= legacy fallback (round-3, proven) ==================
__global__ __launch_bounds__(256) void k_men_gemm(
    const float* __restrict__ X, const float* __restrict__ Wm,
    const float* __restrict__ wo, float* __restrict__ score) {
  __shared__ __align__(16) unsigned short As[64 * 32];
  __shared__ __align__(16) unsigned short Bs[64 * 32];
  const int bid = blockIdx.x;
  const int rowBase = (bid >> 4) * 64, colBase = (bid & 15) * 64;
  const int tid = threadIdx.x, wave = tid >> 6, lane = tid & 63;
  const int lm = lane & 15, lq = lane >> 4;
  const int sr = tid >> 2, sc = (tid & 3) * 8;
  f32x4 acc[4] = {};
  for (int k0 = 0; k0 < 1024; k0 += 32) {
    __syncthreads();
    stage8(&As[sr * 32 + sc], &X[(size_t)(rowBase + sr) * 1024 + k0 + sc]);
    stage8(&Bs[sr * 32 + sc], &Wm[(size_t)(colBase + sr) * 1024 + k0 + sc]);
    __syncthreads();
    bf16x8 af = *(const bf16x8*)&As[(wave * 16 + lm) * 32 + lq * 8];
#pragma unroll
    for (int j = 0; j < 4; ++j) {
      bf16x8 bfr = *(const bf16x8*)&Bs[(j * 16 + lm) * 32 + lq * 8];
      acc[j] = __builtin_amdgcn_mfma_f32_16x16x32_bf16(af, bfr, acc[j], 0, 0, 0);
    }
  }
  float rsum[4] = {0.f, 0.f, 0.f, 0.f};
#pragma unroll
  for (int j = 0; j < 4; ++j) {
    float w = wo[colBase + j * 16 + lm];
#pragma unroll
    for (int r = 0; r < 4; ++r) rsum[r] += tanhf(acc[j][r]) * w;
  }
#pragma unroll
  for (int m = 1; m <= 8; m <<= 1)
#pragma unroll
    for (int r = 0; r < 4; ++r) rsum[r] += __shfl_xor(rsum[r], m, 64);
  if (lm == 0) {
    int row0 = rowBase + wave * 16 + lq * 4;
#pragma unroll
    for (int r = 0; r < 4; ++r) atomicAdd(&score[row0 + r], rsum[r]);
  }
}

__global__ __launch_bounds__(256) void k_ctx_gemm(
    const float* __restrict__ X, const int* __restrict__ gathers,
    const float* __restrict__ Wc, const float* __restrict__ wd,
    const float* __restrict__ wo, const float* __restrict__ dist,
    const float* __restrict__ cb, float* __restrict__ score) {
  __shared__ __align__(16) unsigned short As[64 * 32];
  __shared__ __align__(16) unsigned short Bs[64 * 32];
  const int bid = blockIdx.x;
  const int rowBase = (bid >> 4) * 64, colBase = (bid & 15) * 64;
  const int tid = threadIdx.x, wave = tid >> 6, lane = tid & 63;
  const int lm = lane & 15, lq = lane >> 4;
  const int sr = tid >> 2, sc = (tid & 3) * 8;
  const int row_g = rowBase + sr;
  const int srcRow = (gathers[row_g >> 7] << 7) + (row_g & 127);
  f32x4 acc[4] = {};
  for (int k0 = 0; k0 < 1024; k0 += 32) {
    __syncthreads();
    stage8(&As[sr * 32 + sc], &X[(size_t)srcRow * 1024 + k0 + sc]);
    stage8(&Bs[sr * 32 + sc], &Wc[(size_t)(colBase + sr) * 1024 + k0 + sc]);
    __syncthreads();
    bf16x8 af = *(const bf16x8*)&As[(wave * 16 + lm) * 32 + lq * 8];
#pragma unroll
    for (int j = 0; j < 4; ++j) {
      bf16x8 bfr = *(const bf16x8*)&Bs[(j * 16 + lm) * 32 + lq * 8];
      acc[j] = __builtin_amdgcn_mfma_f32_16x16x32_bf16(af, bfr, acc[j], 0, 0, 0);
    }
  }
  float rsum[4] = {0.f, 0.f, 0.f, 0.f};
#pragma unroll
  for (int j = 0; j < 4; ++j) {
    int col = colBase + j * 16 + lm;
    float w = wo[col];
    float wdv = wd[col];
#pragma unroll
    for (int r = 0; r < 4; ++r) {
      int rg = rowBase + wave * 16 + lq * 4 + r;
      int b = rg >> 7, s = rg & 127;
      float v = acc[j][r] + cb[b * 1024 + col] + dist[b * 128 + s] * wdv;
      rsum[r] += tanhf(v) * w;
    }
  }
#pragma unroll
  for (int m = 1; m <= 8; m <<= 1)
#pragma unroll
    for (int r = 0; r < 4; ++r) rsum[r] += __shfl_xor(rsum[r], m, 64);
  if (lm == 0) {
    int row0 = rowBase + wave * 16 + lq * 4;
#pragma unroll
    for (int r = 0; r < 4; ++r) atomicAdd(&score[row0 + r], rsum[r]);
  }
}

__global__ __launch_bounds__(256) void k_soft(
    const float* __restrict__ score_src, const float* __restrict__ mask,
    const float* __restrict__ X, const int* __restrict__ gathers,
    float* __restrict__ finalr, int isCtx) {
  const int b = blockIdx.x, tid = threadIdx.x;
  const int n = gathers[b];
  __shared__ float attn[128];
  __shared__ float smax, ssum;
  if (tid < 128) {
    int srow = isCtx ? b : n;
    attn[tid] = score_src[srow * 128 + tid] + (1.0f - mask[b * 128 + tid]) * (-10000.0f);
  }
  __syncthreads();
  if (tid == 0) {
    float m = attn[0];
    for (int i = 1; i < 128; ++i) m = fmaxf(m, attn[i]);
    smax = m;
  }
  __syncthreads();
  if (tid < 128) attn[tid] = expf(attn[tid] - smax);
  __syncthreads();
  if (tid == 0) {
    float s = 0.f;
    for (int i = 0; i < 128; ++i) s += attn[i];
    ssum = 1.0f / s;
  }
  __syncthreads();
  if (tid < 128) attn[tid] *= ssum;
  __syncthreads();
  const float* xb = &X[(size_t)(n << 7) * 1024];
  const int off = isCtx ? 1024 : 0;
  for (int d = tid; d < 1024; d += 256) {
    float a = 0.f;
#pragma unroll 8
    for (int s = 0; s < 128; ++s) a += attn[s] * xb[s * 1024 + d];
    finalr[b * 2048 + off + d] = a;
  }
}

__global__ __launch_bounds__(256) void k_cb_gemm(
    const float* __restrict__ finalr, const float* __restrict__ Wcm,
    float* __restrict__ cb) {
  __shared__ __align__(16) unsigned short As[64 * 32];
  __shared__ __align__(16) unsigned short Bs[64 * 32];
  const int bid = blockIdx.x;
  const int rowBase = (bid >> 4) * 64, colBase = (bid & 15) * 64;
  const int tid = threadIdx.x, wave = tid >> 6, lane = tid & 63;
  const int lm = lane & 15, lq = lane >> 4;
  const int sr = tid >> 2, sc = (tid & 3) * 8;
  f32x4 acc[4] = {};
  for (int k0 = 0; k0 < 1024; k0 += 32) {
    __syncthreads();
    stage8(&As[sr * 32 + sc], &finalr[(size_t)(rowBase + sr) * 2048 + k0 + sc]);
    stage8(&Bs[sr * 32 + sc], &Wcm[(size_t)(colBase + sr) * 1024 + k0 + sc]);
    __syncthreads();
    bf16x8 af = *(const bf16x8*)&As[(wave * 16 + lm) * 32 + lq * 8];
#pragma unroll
    for (int j = 0; j < 4; ++j) {
      bf16x8 bfr = *(const bf16x8*)&Bs[(j * 16 + lm) * 32 + lq * 8];
      acc[j] = __builtin_amdgcn_mfma_f32_16x16x32_bf16(af, bfr, acc[j], 0, 0, 0);
    }
  }
#pragma unroll
  for (int j = 0; j < 4; ++j) {
    int col = colBase + j * 16 + lm;
#pragma unroll
    for (int r = 0; r < 4; ++r) {
      int row = rowBase + wave * 16 + lq * 4 + r;
      cb[row * 1024 + col] = acc[j][r];
    }
  }
}

__global__ __launch_bounds__(256) void k_lat_gemm(
    const float* __restrict__ finalr, const float* __restrict__ Wf2l,
    float* __restrict__ lat) {
  __shared__ __align__(16) unsigned short As[64 * 32];
  __shared__ __align__(16) unsigned short Bs[64 * 32];
  const int rowBase = blockIdx.y * 64, colBase = blockIdx.x * 64;
  const int tid = threadIdx.x, wave = tid >> 6, lane = tid & 63;
  const int lm = lane & 15, lq = lane >> 4;
  const int sr = tid >> 2, sc = (tid & 3) * 8;
  f32x4 acc[4] = {};
  for (int k0 = 0; k0 < 2048; k0 += 32) {
    __syncthreads();
    stage8(&As[sr * 32 + sc], &finalr[(size_t)(rowBase + sr) * 2048 + k0 + sc]);
    int l = colBase + sr;
    if (l < LATENT) {
      stage8(&Bs[sr * 32 + sc], &Wf2l[(size_t)l * 2048 + k0 + sc]);
    } else {
      uint4 z = {0, 0, 0, 0};
      *(uint4*)&Bs[sr * 32 + sc] = z;
    }
    __syncthreads();
    bf16x8 af = *(const bf16x8*)&As[(wave * 16 + lm) * 32 + lq * 8];
#pragma unroll
    for (int j = 0; j < 4; ++j) {
      bf16x8 bfr = *(const bf16x8*)&Bs[(j * 16 + lm) * 32 + lq * 8];
      acc[j] = __builtin_amdgcn_mfma_f32_16x16x32_bf16(af, bfr, acc[j], 0, 0, 0);
    }
  }
#pragma unroll
  for (int j = 0; j < 4; ++j) {
    int col = colBase + j * 16 + lm;
    if (col < LATENT) {
#pragma unroll
      for (int r = 0; r < 4; ++r) {
        int row = rowBase + wave * 16 + lq * 4 + r;
        lat[row * LATENT + col] = acc[j][r];
      }
    }
  }
}

__global__ __launch_bounds__(256) void k_out_gemm(
    const float* __restrict__ finalr, const float* __restrict__ Wout,
    const float* __restrict__ lat, const float* __restrict__ Wl2l,
    const float* __restrict__ lscale, float* __restrict__ out,
    float* __restrict__ outLat) {
  __shared__ __align__(16) unsigned short As[64 * 32];
  __shared__ __align__(16) unsigned short Bs[64 * 32];
  const int rowBase = blockIdx.y * 64, colBase = blockIdx.x * 64;
  const int tid = threadIdx.x, wave = tid >> 6, lane = tid & 63;
  const int lm = lane & 15, lq = lane >> 4;
  const int sr = tid >> 2, sc = (tid & 3) * 8;
  const float scal = lscale[0];
  const int lrow = colBase + sr;
  const bool lvalid = (lrow < LL);
  f32x4 acc[4] = {};
  for (int k0 = 0; k0 < 2048; k0 += 32) {
    __syncthreads();
    stage8(&As[sr * 32 + sc], &finalr[(size_t)(rowBase + sr) * 2048 + k0 + sc]);
    if (lvalid) {
      stage8(&Bs[sr * 32 + sc], &Wout[(size_t)lrow * 2048 + k0 + sc]);
    } else {
      uint4 z = {0, 0, 0, 0};
      *(uint4*)&Bs[sr * 32 + sc] = z;
    }
    __syncthreads();
    bf16x8 af = *(const bf16x8*)&As[(wave * 16 + lm) * 32 + lq * 8];
#pragma unroll
    for (int j = 0; j < 4; ++j) {
      bf16x8 bfr = *(const bf16x8*)&Bs[(j * 16 + lm) * 32 + lq * 8];
      acc[j] = __builtin_amdgcn_mfma_f32_16x16x32_bf16(af, bfr, acc[j], 0, 0, 0);
    }
  }
  f32x4 acc2[4] = {};
  for (int k2 = 0; k2 < 128; k2 += 32) {
    __syncthreads();
    const int brow = rowBase + sr;
#pragma unroll
    for (int jj = 0; jj < 8; ++jj) {
      int idx = k2 + sc + jj;
      As[sr * 32 + sc + jj] = (idx < LATENT) ? f2bf(lat[brow * LATENT + idx]) : (unsigned short)0;
      Bs[sr * 32 + sc + jj] = (lvalid && idx < LATENT) ? f2bf(Wl2l[lrow * LATENT + idx]) : (unsigned short)0;
    }
    __syncthreads();
    bf16x8 af = *(const bf16x8*)&As[(wave * 16 + lm) * 32 + lq * 8];
#pragma unroll
    for (int j = 0; j < 4; ++j) {
      bf16x8 bfr = *(const bf16x8*)&Bs[(j * 16 + lm) * 32 + lq * 8];
      acc2[j] = __builtin_amdgcn_mfma_f32_16x16x32_bf16(af, bfr, acc2[j], 0, 0, 0);
    }
  }
#pragma unroll
  for (int j = 0; j < 4; ++j) {
    int col = colBase + j * 16 + lm;
    if (col < LL) {
#pragma unroll
      for (int r = 0; r < 4; ++r) {
        int row = rowBase + wave * 16 + lq * 4 + r;
        float lv = acc2[j][r];
        out[(size_t)row * LL + col] = acc[j][r] + scal * lv;
        outLat[(size_t)row * LL + col] = lv;
      }
    }
  }
}

extern "C" void kernel_launch(void* const* d_in, const int* in_sizes, int n_in,
                              void* d_out, int out_size, void* d_ws, size_t ws_size,
                              hipStream_t stream) {
  const float* X = (const float*)d_in[0];
  const float* men_mask = (const float*)d_in[1];
  const float* ctx_mask = (const float*)d_in[2];
  const float* dist = (const float*)d_in[3];
  const int* gathers = (const int*)d_in[4];
  const float* W_men_m = (const float*)d_in[5];
  const float* W_men_o = (const float*)d_in[6];
  const float* W_ctx_c = (const float*)d_in[7];
  const float* W_ctx_m = (const float*)d_in[8];
  const float* w_ctx_d = (const float*)d_in[9];
  const float* W_ctx_o = (const float*)d_in[10];
  const float* W_out = (const float*)d_in[11];
  const float* W_f2l = (const float*)d_in[12];
  const float* W_l2l = (const float*)d_in[13];
  const float* lscale = (const float*)d_in[14];
  float* out = (float*)d_out;
  float* outLat = out + (size_t)BB * LL;

  size_t off = 0;
  auto carve = [&](size_t bytes) {
    void* p = (char*)d_ws + off;
    off = (off + bytes + 255) & ~(size_t)255;
    return p;
  };
  float* sent_score = (float*)carve(32768 * 4);
  float* ctx_score = (float*)carve(65536 * 4);
  float* finalr = (float*)carve((size_t)512 * 2048 * 4);        // legacy only
  float* cb = (float*)carve((size_t)512 * 1024 * 4);
  float* lat = (float*)carve((size_t)512 * LATENT * 4);         // legacy only
  unsigned short* Xb = (unsigned short*)carve((size_t)32768 * 1024 * 2);
  unsigned short* Wmb = (unsigned short*)carve((size_t)1024 * 1024 * 2);
  unsigned short* Wcb = (unsigned short*)carve((size_t)1024 * 1024 * 2);
  unsigned short* Wcmb = (unsigned short*)carve((size_t)1024 * 1024 * 2);
  unsigned short* Hc = (unsigned short*)carve((size_t)32768 * 1024 * 2);
  unsigned short* Wf2lb = (unsigned short*)carve((size_t)LATPAD * 2048 * 2);
  unsigned short* Wl2lb = (unsigned short*)carve((size_t)LPAD * LATPAD * 2);
  unsigned short* finalrb = (unsigned short*)carve((size_t)512 * 2048 * 2);
  unsigned short* latb = (unsigned short*)carve((size_t)512 * LATPAD * 2);
  float* latf = (float*)carve((size_t)512 * LATPAD * 4);
  const bool fits = off <= ws_size;

  if (fits) {
    hipMemsetAsync(sent_score, 0, 32768 * sizeof(float), stream);
    hipMemsetAsync(cb, 0, (size_t)512 * 1024 * sizeof(float), stream);
    hipMemsetAsync(latf, 0, (size_t)512 * LATPAD * sizeof(float), stream);
    k_cvt<<<8192, 256, 0, stream>>>(X, Xb, 32768 * 1024 / 4);
    k_cvt_all<<<2048, 256, 0, stream>>>(W_men_m, W_ctx_c, W_ctx_m, W_f2l, W_l2l,
                                        Wmb, Wcb, Wcmb, Wf2lb, Wl2lb);
    k_mc_gemm8<<<256, 512, 0, stream>>>(Xb, Wmb, Wcb, W_men_o, sent_score, Hc);
    k_softb<<<512, 256, 0, stream>>>(sent_score, men_mask, Xb, gathers, finalrb, 0);
    k_cb_split<<<256, 256, 0, stream>>>(finalrb, Wcmb, cb);
    k_ctx_fused<<<512, 256, 0, stream>>>(Hc, gathers, cb, w_ctx_d, W_ctx_o, dist,
                                         ctx_mask, Xb, finalrb);
    k_lat_split<<<128, 256, 0, stream>>>(finalrb, Wf2lb, latf);
    k_cvt<<<64, 256, 0, stream>>>(latf, latb, 512 * LATPAD / 4);
    k_out_gemm_f<<<352, 256, 0, stream>>>(finalrb, W_out, latb, Wl2lb,
                                          lscale, out, outLat);
  } else {
    hipMemsetAsync(d_ws, 0, (32768 + 65536) * sizeof(float), stream);
    k_men_gemm<<<8192, 256, 0, stream>>>(X, W_men_m, W_men_o, sent_score);
    k_soft<<<512, 256, 0, stream>>>(sent_score, men_mask, X, gathers, finalr, 0);
    k_cb_gemm<<<128, 256, 0, stream>>>(finalr, W_ctx_m, cb);
    k_ctx_gemm<<<16384, 256, 0, stream>>>(X, gathers, W_ctx_c, w_ctx_d, W_ctx_o, dist, cb, ctx_score);
    k_soft<<<512, 256, 0, stream>>>(ctx_score, ctx_mask, X, gathers, finalr, 1);
    k_lat_gemm<<<dim3(2, 8), 256, 0, stream>>>(finalr, W_f2l, lat);
    k_out_gemm<<<dim3(162, 8), 256, 0, stream>>>(finalr, W_out, lat, W_l2l, lscale, out, outLat);
  }
}